// Round 10
// baseline (813.231 us; speedup 1.0000x reference)
//
#include <hip/hip_runtime.h>
#include <hip/hip_bf16.h>
#include <math.h>

// CrystalGraphConvolution — MI355X round 10
// vs r9: apply v5 — prefetch rings deepened 4 -> 8 (latency-bound fix: double
// per-wave outstanding VMEM), (ssrc,sdst) packed into one int2 stream.
// Everything else identical to r9.

#define NN 50000
#define NE 800000
#define AD 128
#define ED 64
#define NSTEPS 3
#define NTILES (NE / 64)          // 12500
#define NSCAN  ((NN + 255) / 256) // 196
#define NROWB  ((NN + 63) / 64)   // 782

#define L2E 1.4426950408889634f
#define LN2 0.6931471805599453f

typedef __attribute__((ext_vector_type(8))) __bf16 bf16x8;
typedef __attribute__((ext_vector_type(4))) float  f32x4;
typedef __attribute__((ext_vector_type(2))) unsigned u32x2;

__device__ __forceinline__ float softplus_f(float x) {      // precise (output path)
    return fmaxf(x, 0.f) + log1pf(__expf(-fabsf(x)));
}
__device__ __forceinline__ float sigmoid_fast(float x) {    // Tier B
    float e = __expf(-fabsf(x));
    float r = __builtin_amdgcn_rcpf(1.f + e);
    return (x >= 0.f) ? r : 1.f - r;
}
__device__ __forceinline__ unsigned short bf16_rne(float f) {
    unsigned u = __float_as_uint(f);
    unsigned r = u + 0x7fffu + ((u >> 16) & 1u);
    return (unsigned short)(r >> 16);
}
__device__ __forceinline__ unsigned pack_bf2(float s, float g) {
    return (unsigned)bf16_rne(s) | ((unsigned)bf16_rne(g) << 16);
}
__device__ __forceinline__ float unp_lo(unsigned v) { return __uint_as_float(v << 16); }
__device__ __forceinline__ float unp_hi(unsigned v) { return __uint_as_float(v & 0xffff0000u); }

// raw transcendental helpers (v_exp_f32 = 2^x, v_log_f32 = log2)
__device__ __forceinline__ float nexp2_f(float x) {         // 2^(-x)
    float r; asm("v_exp_f32 %0, -%1" : "=v"(r) : "v"(x)); return r;
}
__device__ __forceinline__ float nexp2_abs_f(float x) {     // 2^(-|x|)
    float r; asm("v_exp_f32 %0, -abs(%1)" : "=v"(r) : "v"(x)); return r;
}
__device__ __forceinline__ float log2_f(float x) {
    float r; asm("v_log_f32 %0, %1" : "=v"(r) : "v"(x)); return r;
}

// ===== one-time B pre-pack for node GEMM =====
__global__ void __launch_bounds__(256) bn_prep(
    const float* __restrict__ Ks, const float* __restrict__ Kg,
    bf16x8* __restrict__ Bn)
{
    union U8 { short s[8]; bf16x8 v; };
    int idx = blockIdx.x * 256 + threadIdx.x;      // 64 blocks -> 16384
    int l4  = idx & 3;
    int col = (idx >> 2) & 127;
    int ki  = (idx >> 9) & 3;
    int hl  = (idx >> 11) & 1;
    int m   = (idx >> 12) & 1;
    int sel = (idx >> 13) & 1;
    const float* K = m ? Kg : Ks;
    U8 o;
#pragma unroll
    for (int j = 0; j < 8; ++j) {
        int k = sel * 128 + ki * 32 + l4 * 8 + j;
        float v = K[(size_t)k * AD + col];
        unsigned short h = bf16_rne(v);
        o.s[j] = (hl == 0) ? (short)h
                           : (short)bf16_rne(v - __uint_as_float((unsigned)h << 16));
    }
    Bn[idx] = o.v;
}

// ===== node projections via MFMA (hi/lo), + x maintenance; outputs xL2E-scaled =====
__global__ void __launch_bounds__(512, 1) node_mm_mfma(
    const float* __restrict__ xin, float* __restrict__ acc,
    const bf16x8* __restrict__ Bn, unsigned* __restrict__ PQ32, int mode)
{
    __shared__ short As_h[64 * 128];
    __shared__ short As_l[64 * 128];
    const int t = threadIdx.x;
    const int w = t >> 6, lane = t & 63;
    const int l4 = lane >> 4;
    const int row0 = blockIdx.x * 64;

#pragma unroll
    for (int ii = 0; ii < 4; ++ii) {
        int idx = t + 512 * ii;
        int row = idx >> 5, c4 = idx & 31;
        int node = row0 + row;
        f32x4 v = {};
        if (node < NN) {
            if (mode == 0) {
                v = *(const f32x4*)&xin[(size_t)node * AD + 4 * c4];
                *(f32x4*)&acc[(size_t)node * AD + 4 * c4] = v;
            } else {
                f32x4 a = *(const f32x4*)&acc[(size_t)node * AD + 4 * c4];
                v[0] = softplus_f(a[0]); v[1] = softplus_f(a[1]);
                v[2] = softplus_f(a[2]); v[3] = softplus_f(a[3]);
                *(f32x4*)&acc[(size_t)node * AD + 4 * c4] = v;
            }
        }
        unsigned short h0 = bf16_rne(v[0]), h1 = bf16_rne(v[1]),
                       h2 = bf16_rne(v[2]), h3 = bf16_rne(v[3]);
        unsigned short l0 = bf16_rne(v[0] - __uint_as_float((unsigned)h0 << 16));
        unsigned short l1 = bf16_rne(v[1] - __uint_as_float((unsigned)h1 << 16));
        unsigned short l2 = bf16_rne(v[2] - __uint_as_float((unsigned)h2 << 16));
        unsigned short l3 = bf16_rne(v[3] - __uint_as_float((unsigned)h3 << 16));
        int sidx = (row * 128 + c4 * 4) ^ ((row & 7) << 3);
        *(short4*)&As_h[sidx] = make_short4((short)h0, (short)h1, (short)h2, (short)h3);
        *(short4*)&As_l[sidx] = make_short4((short)l0, (short)l1, (short)l2, (short)l3);
    }
    __syncthreads();

    const int col = w * 16 + (lane & 15);
#pragma unroll
    for (int sel = 0; sel < 2; ++sel) {
        bf16x8 bS[4][2], bG[4][2];
#pragma unroll
        for (int ki = 0; ki < 4; ++ki) {
#pragma unroll
            for (int hl = 0; hl < 2; ++hl) {
                bS[ki][hl] = Bn[(((sel * 2 + 0) * 2 + hl) * 4 + ki) * 512 + col * 4 + l4];
                bG[ki][hl] = Bn[(((sel * 2 + 1) * 2 + hl) * 4 + ki) * 512 + col * 4 + l4];
            }
        }
        f32x4 aS[4] = {}, aG[4] = {};
#pragma unroll
        for (int mt = 0; mt < 4; ++mt) {
            int row = mt * 16 + (lane & 15);
#pragma unroll
            for (int ki = 0; ki < 4; ++ki) {
                int idx = (row * 128 + ki * 32 + l4 * 8) ^ ((row & 7) << 3);
                bf16x8 ah = *(const bf16x8*)&As_h[idx];
                bf16x8 al = *(const bf16x8*)&As_l[idx];
                aS[mt] = __builtin_amdgcn_mfma_f32_16x16x32_bf16(ah, bS[ki][0], aS[mt], 0, 0, 0);
                aS[mt] = __builtin_amdgcn_mfma_f32_16x16x32_bf16(al, bS[ki][0], aS[mt], 0, 0, 0);
                aS[mt] = __builtin_amdgcn_mfma_f32_16x16x32_bf16(ah, bS[ki][1], aS[mt], 0, 0, 0);
                aG[mt] = __builtin_amdgcn_mfma_f32_16x16x32_bf16(ah, bG[ki][0], aG[mt], 0, 0, 0);
                aG[mt] = __builtin_amdgcn_mfma_f32_16x16x32_bf16(al, bG[ki][0], aG[mt], 0, 0, 0);
                aG[mt] = __builtin_amdgcn_mfma_f32_16x16x32_bf16(ah, bG[ki][1], aG[mt], 0, 0, 0);
            }
        }
#pragma unroll
        for (int mt = 0; mt < 4; ++mt) {
#pragma unroll
            for (int reg = 0; reg < 4; ++reg) {
                int node = row0 + mt * 16 + l4 * 4 + reg;
                if (node < NN)
                    PQ32[(size_t)node * 256 + sel * 128 + col] =
                        pack_bf2(aS[mt][reg] * L2E, aG[mt][reg] * L2E);
            }
        }
    }
}

// ===== sort machinery =====
__global__ void __launch_bounds__(256) hist_k(const int* __restrict__ pidx,
                                              unsigned* __restrict__ cnt)
{
    int e = blockIdx.x * 256 + threadIdx.x;
    atomicAdd(&cnt[pidx[2 * e]], 1u);
}

__global__ void __launch_bounds__(256) scan1_k(const unsigned* __restrict__ cnt,
                                               unsigned* __restrict__ cur,
                                               unsigned* __restrict__ part)
{
    __shared__ unsigned tmp[256];
    const int t = threadIdx.x;
    const int bin = blockIdx.x * 256 + t;
    unsigned v = (bin < NN) ? cnt[bin] : 0u;
    tmp[t] = v;
    __syncthreads();
    for (int off = 1; off < 256; off <<= 1) {
        unsigned a = (t >= off) ? tmp[t - off] : 0u;
        __syncthreads();
        tmp[t] += a;
        __syncthreads();
    }
    if (bin < NN) cur[bin] = tmp[t] - v;
    if (t == 255) part[blockIdx.x] = tmp[255];
}

__global__ void __launch_bounds__(256) scan2_k(unsigned* __restrict__ part)
{
    __shared__ unsigned tmp[256];
    const int t = threadIdx.x;
    unsigned v = (t < NSCAN) ? part[t] : 0u;
    tmp[t] = v;
    __syncthreads();
    for (int off = 1; off < 256; off <<= 1) {
        unsigned a = (t >= off) ? tmp[t - off] : 0u;
        __syncthreads();
        tmp[t] += a;
        __syncthreads();
    }
    if (t < NSCAN) part[t] = tmp[t] - v;
}

__global__ void __launch_bounds__(256) scan3_k(unsigned* __restrict__ cur,
                                               const unsigned* __restrict__ part)
{
    const int bin = blockIdx.x * 256 + threadIdx.x;
    if (bin < NN) cur[bin] += part[blockIdx.x];
}

// scaled offsets packed: sdp[pos] = { src*1024, dst*1024+512 }
__global__ void __launch_bounds__(256) scatter_k(
    const int* __restrict__ pidx, unsigned* __restrict__ cur,
    int* __restrict__ sid, int2* __restrict__ sdp)
{
    int e = blockIdx.x * 256 + threadIdx.x;
    int s = pidx[2 * e], d = pidx[2 * e + 1];
    unsigned pos = atomicAdd(&cur[s], 1u);
    sid[pos] = e;
    sdp[pos] = make_int2(s << 10, (d << 10) + 512);
}

// ===== C = ef @ K_bot via MFMA (hi/lo), gather-read / linear-write; xL2E-scaled =====
__global__ void __launch_bounds__(512) edge_c_mfma(
    const float* __restrict__ ef, const float* __restrict__ Ks,
    const float* __restrict__ Kg, const int* __restrict__ sid,
    unsigned* __restrict__ C32)
{
    __shared__ short As_h[64 * 64];
    __shared__ short As_l[64 * 64];
    const int t = threadIdx.x;
    const int w = t >> 6, lane = t & 63;

    union U8 { short s[8]; bf16x8 v; };
    bf16x8 bS[2][2], bG[2][2];
    {
        const int col = w * 16 + (lane & 15);
#pragma unroll
        for (int ki = 0; ki < 2; ++ki) {
            U8 sh_, sl_, gh_, gl_;
            const int kbase = 2 * AD + ki * 32 + (lane >> 4) * 8;
#pragma unroll
            for (int j = 0; j < 8; ++j) {
                float vs = Ks[(size_t)(kbase + j) * AD + col];
                float vg = Kg[(size_t)(kbase + j) * AD + col];
                unsigned short h = bf16_rne(vs);
                sh_.s[j] = (short)h;
                sl_.s[j] = (short)bf16_rne(vs - __uint_as_float((unsigned)h << 16));
                h = bf16_rne(vg);
                gh_.s[j] = (short)h;
                gl_.s[j] = (short)bf16_rne(vg - __uint_as_float((unsigned)h << 16));
            }
            bS[ki][0] = sh_.v; bS[ki][1] = sl_.v;
            bG[ki][0] = gh_.v; bG[ki][1] = gl_.v;
        }
    }

    const int srow = t >> 4, sc4 = t & 15;
    f32x4 pf0, pf1;
    {
        int ea = sid[(size_t)blockIdx.x * 64 + srow];
        int eb = sid[(size_t)blockIdx.x * 64 + srow + 32];
        pf0 = __builtin_nontemporal_load((const f32x4*)&ef[(size_t)ea * 64 + 4 * sc4]);
        pf1 = __builtin_nontemporal_load((const f32x4*)&ef[(size_t)eb * 64 + 4 * sc4]);
    }

    for (int tile = blockIdx.x; tile < NTILES; tile += gridDim.x) {
        __syncthreads();
        {
            f32x4 v[2] = {pf0, pf1};
#pragma unroll
            for (int ii = 0; ii < 2; ++ii) {
                int row = srow + 32 * ii;
                float a0 = v[ii][0], a1 = v[ii][1], a2 = v[ii][2], a3 = v[ii][3];
                unsigned short h0 = bf16_rne(a0), h1 = bf16_rne(a1),
                               h2 = bf16_rne(a2), h3 = bf16_rne(a3);
                unsigned short l0 = bf16_rne(a0 - __uint_as_float((unsigned)h0 << 16));
                unsigned short l1 = bf16_rne(a1 - __uint_as_float((unsigned)h1 << 16));
                unsigned short l2 = bf16_rne(a2 - __uint_as_float((unsigned)h2 << 16));
                unsigned short l3 = bf16_rne(a3 - __uint_as_float((unsigned)h3 << 16));
                int sidx = (row * 64 + sc4 * 4) ^ ((row & 7) << 3);
                *(short4*)&As_h[sidx] = make_short4((short)h0, (short)h1, (short)h2, (short)h3);
                *(short4*)&As_l[sidx] = make_short4((short)l0, (short)l1, (short)l2, (short)l3);
            }
        }
        {
            int nxt = tile + gridDim.x;
            if (nxt < NTILES) {
                int ea = sid[(size_t)nxt * 64 + srow];
                int eb = sid[(size_t)nxt * 64 + srow + 32];
                pf0 = __builtin_nontemporal_load((const f32x4*)&ef[(size_t)ea * 64 + 4 * sc4]);
                pf1 = __builtin_nontemporal_load((const f32x4*)&ef[(size_t)eb * 64 + 4 * sc4]);
            }
        }
        __syncthreads();

        f32x4 accS[4] = {}, accG[4] = {};
#pragma unroll
        for (int mt = 0; mt < 4; ++mt) {
#pragma unroll
            for (int ki = 0; ki < 2; ++ki) {
                int row = mt * 16 + (lane & 15);
                int idx = (row * 64 + ki * 32 + (lane >> 4) * 8) ^ ((row & 7) << 3);
                bf16x8 ah = *(const bf16x8*)&As_h[idx];
                bf16x8 al = *(const bf16x8*)&As_l[idx];
                accS[mt] = __builtin_amdgcn_mfma_f32_16x16x32_bf16(ah, bS[ki][0], accS[mt], 0, 0, 0);
                accS[mt] = __builtin_amdgcn_mfma_f32_16x16x32_bf16(al, bS[ki][0], accS[mt], 0, 0, 0);
                accS[mt] = __builtin_amdgcn_mfma_f32_16x16x32_bf16(ah, bS[ki][1], accS[mt], 0, 0, 0);
                accG[mt] = __builtin_amdgcn_mfma_f32_16x16x32_bf16(ah, bG[ki][0], accG[mt], 0, 0, 0);
                accG[mt] = __builtin_amdgcn_mfma_f32_16x16x32_bf16(al, bG[ki][0], accG[mt], 0, 0, 0);
                accG[mt] = __builtin_amdgcn_mfma_f32_16x16x32_bf16(ah, bG[ki][1], accG[mt], 0, 0, 0);
            }
        }
        const size_t p0 = (size_t)tile * 64;
#pragma unroll
        for (int mt = 0; mt < 4; ++mt) {
#pragma unroll
            for (int reg = 0; reg < 4; ++reg) {
                int row = mt * 16 + (lane >> 4) * 4 + reg;
                unsigned val = pack_bf2(accS[mt][reg] * L2E, accG[mt][reg] * L2E);
                __builtin_nontemporal_store(val,
                    &C32[(p0 + row) * 128 + w * 16 + (lane & 15)]);
            }
        }
    }
}

// ===== sorted apply v5: log2-domain, readlane-scalarized, depth-8 rings =====
__global__ void __launch_bounds__(256) edge_apply_sorted(
    const char* __restrict__ C8, const char* __restrict__ PQ8,
    const int2* __restrict__ sdp,
    const float* __restrict__ bs, const float* __restrict__ bg,
    float* __restrict__ acc)
{
    const int t = threadIdx.x & 63;
    const int w = threadIdx.x >> 6;
    const size_t p0 = ((size_t)blockIdx.x * 4 + w) * 64;
    const int2 sd = sdp[p0 + t];        // lane i holds offsets of edge p0+i
    const int srcv = sd.x, dstv = sd.y;

    const float2 bsv = *(const float2*)&bs[2 * t];
    const float2 bgv = *(const float2*)&bg[2 * t];
    const float bsA = bsv.x * L2E, bsB = bsv.y * L2E;
    const float bgA = bgv.x * L2E, bgB = bgv.y * L2E;

    const char* PQl = PQ8 + 8 * t;
    char* accl = (char*)acc + 8 * t;
    const char* Cl = C8 + p0 * 512 + 8 * t;

#define RL(v, i) __builtin_amdgcn_readlane((v), (i))
#define LOADC(i) __builtin_nontemporal_load((const u32x2*)(Cl + (i) * 512))
#define LOADQ(i) (*(const u32x2*)(PQl + RL(dstv, (i))))
#define LOADP(s_) (*(const u32x2*)(PQl + (s_)))

    int cur = RL(srcv, 0);
    u32x2 pv = LOADP(cur);
    float psA = unp_lo(pv.x) + bsA, pgA = unp_hi(pv.x) + bgA;
    float psB = unp_lo(pv.y) + bsB, pgB = unp_hi(pv.y) + bgB;

    u32x2 c0 = LOADC(0), c1 = LOADC(1), c2 = LOADC(2), c3 = LOADC(3),
          c4 = LOADC(4), c5 = LOADC(5), c6 = LOADC(6), c7 = LOADC(7);
    u32x2 q0 = LOADQ(0), q1 = LOADQ(1), q2 = LOADQ(2), q3 = LOADQ(3),
          q4 = LOADQ(4), q5 = LOADQ(5), q6 = LOADQ(6), q7 = LOADQ(7);
    u32x2 r0 = pv, r1 = pv, r2 = pv, r3 = pv, r4 = pv, r5 = pv, r6 = pv, r7 = pv;
    if (RL(srcv, 1) != RL(srcv, 0)) r1 = LOADP(RL(srcv, 1));
    if (RL(srcv, 2) != RL(srcv, 1)) r2 = LOADP(RL(srcv, 2));
    if (RL(srcv, 3) != RL(srcv, 2)) r3 = LOADP(RL(srcv, 3));
    if (RL(srcv, 4) != RL(srcv, 3)) r4 = LOADP(RL(srcv, 4));
    if (RL(srcv, 5) != RL(srcv, 4)) r5 = LOADP(RL(srcv, 5));
    if (RL(srcv, 6) != RL(srcv, 5)) r6 = LOADP(RL(srcv, 6));
    if (RL(srcv, 7) != RL(srcv, 6)) r7 = LOADP(RL(srcv, 7));
    float accA = 0.f, accB = 0.f;

#define FLUSH                                                              \
    atomicAdd((float*)(accl + ((unsigned)cur >> 1)),     LN2 * accA);      \
    atomicAdd((float*)(accl + ((unsigned)cur >> 1) + 4), LN2 * accB);

#define CORE(i, cc, qq, rr)                                                \
    {                                                                      \
        int src_ = RL(srcv, (i));                                          \
        if (src_ != cur) {                                                 \
            FLUSH;                                                         \
            accA = 0.f; accB = 0.f; cur = src_;                            \
            psA = unp_lo(rr.x) + bsA; pgA = unp_hi(rr.x) + bgA;            \
            psB = unp_lo(rr.y) + bsB; pgB = unp_hi(rr.y) + bgB;            \
        }                                                                  \
        float sA = unp_lo(cc.x) + unp_lo(qq.x) + psA;                      \
        float gA = unp_hi(cc.x) + unp_hi(qq.x) + pgA;                      \
        float sB = unp_lo(cc.y) + unp_lo(qq.y) + psB;                      \
        float gB = unp_hi(cc.y) + unp_hi(qq.y) + pgB;                      \
        float spA = fmaxf(gA, 0.f) + log2_f(1.f + nexp2_abs_f(gA));        \
        float spB = fmaxf(gB, 0.f) + log2_f(1.f + nexp2_abs_f(gB));       \
        accA = fmaf(__builtin_amdgcn_rcpf(1.f + nexp2_f(sA)), spA, accA);  \
        accB = fmaf(__builtin_amdgcn_rcpf(1.f + nexp2_f(sB)), spB, accB);  \
    }

#define STEP(i, cc, qq, rr)                                                \
    CORE(i, cc, qq, rr)                                                    \
    {                                                                      \
        cc = LOADC((i) + 8);                                               \
        qq = LOADQ((i) + 8);                                               \
        if (RL(srcv, (i) + 8) != RL(srcv, (i) + 7))                        \
            rr = LOADP(RL(srcv, (i) + 8));                                 \
    }

    for (int b = 0; b < 56; b += 8) {
        STEP(b + 0, c0, q0, r0)
        STEP(b + 1, c1, q1, r1)
        STEP(b + 2, c2, q2, r2)
        STEP(b + 3, c3, q3, r3)
        STEP(b + 4, c4, q4, r4)
        STEP(b + 5, c5, q5, r5)
        STEP(b + 6, c6, q6, r6)
        STEP(b + 7, c7, q7, r7)
    }
    CORE(56, c0, q0, r0)
    CORE(57, c1, q1, r1)
    CORE(58, c2, q2, r2)
    CORE(59, c3, q3, r3)
    CORE(60, c4, q4, r4)
    CORE(61, c5, q5, r5)
    CORE(62, c6, q6, r6)
    CORE(63, c7, q7, r7)
    FLUSH;

#undef STEP
#undef CORE
#undef FLUSH
#undef LOADP
#undef LOADQ
#undef LOADC
#undef RL
}

// ===== final softplus =====
__global__ void __launch_bounds__(256) act_k(float* __restrict__ acc)
{
    size_t i = ((size_t)blockIdx.x * 256 + threadIdx.x) * 4;
    float4 v = *(float4*)&acc[i];
    v.x = softplus_f(v.x);
    v.y = softplus_f(v.y);
    v.z = softplus_f(v.z);
    v.w = softplus_f(v.w);
    *(float4*)&acc[i] = v;
}

// ===== Tier B fallback (round-1, known good) =====
__global__ void __launch_bounds__(128) node_mm_f32(
    const float* __restrict__ x, const float* __restrict__ Ks,
    const float* __restrict__ Kg, float* __restrict__ PQ)
{
    __shared__ float xs[8][AD];
    const int t = threadIdx.x;
    const int row0 = blockIdx.x * 8;
#pragma unroll
    for (int r = 0; r < 8; ++r) xs[r][t] = x[(size_t)(row0 + r) * AD + t];
    __syncthreads();
    float aPs[8] = {}, aQs[8] = {}, aPg[8] = {}, aQg[8] = {};
    for (int k = 0; k < AD; ++k) {
        float ks_s = Ks[k * AD + t];
        float ks_d = Ks[(AD + k) * AD + t];
        float kg_s = Kg[k * AD + t];
        float kg_d = Kg[(AD + k) * AD + t];
#pragma unroll
        for (int r = 0; r < 8; ++r) {
            float xv = xs[r][k];
            aPs[r] = fmaf(xv, ks_s, aPs[r]);
            aQs[r] = fmaf(xv, ks_d, aQs[r]);
            aPg[r] = fmaf(xv, kg_s, aPg[r]);
            aQg[r] = fmaf(xv, kg_d, aQg[r]);
        }
    }
#pragma unroll
    for (int r = 0; r < 8; ++r) {
        float* o = PQ + (size_t)(row0 + r) * 512;
        *(float2*)&o[2 * t]       = make_float2(aPs[r], aPg[r]);
        *(float2*)&o[256 + 2 * t] = make_float2(aQs[r], aQg[r]);
    }
}

__global__ void __launch_bounds__(256) edge_fused(
    const float* __restrict__ ef, const float* __restrict__ Ks,
    const float* __restrict__ Kg, const float* __restrict__ PQ,
    const int* __restrict__ pidx, const float* __restrict__ bs,
    const float* __restrict__ bg, float* __restrict__ acc)
{
    __shared__ float KB[ED][2 * AD];
    __shared__ float es[64][ED];
    const int t = threadIdx.x;
    for (int i = t; i < ED * AD; i += 256) {
        int k = i >> 7, n = i & 127;
        KB[k][2 * n]     = Ks[(2 * AD + k) * AD + n];
        KB[k][2 * n + 1] = Kg[(2 * AD + k) * AD + n];
    }
    const size_t e0 = (size_t)blockIdx.x * 64;
    for (int i = t; i < 64 * ED; i += 256) ((float*)es)[i] = ef[e0 * ED + i];
    __syncthreads();
    const int le = t >> 7, n = t & 127;
    const float bsn = bs[n], bgn = bg[n];
    for (int base = le * 8; base < 64; base += 16) {
        float accS[8] = {}, accG[8] = {};
        for (int k4 = 0; k4 < ED / 4; ++k4) {
            float2 kv0 = *(const float2*)&KB[4 * k4 + 0][2 * n];
            float2 kv1 = *(const float2*)&KB[4 * k4 + 1][2 * n];
            float2 kv2 = *(const float2*)&KB[4 * k4 + 2][2 * n];
            float2 kv3 = *(const float2*)&KB[4 * k4 + 3][2 * n];
#pragma unroll
            for (int r = 0; r < 8; ++r) {
                float4 ev = *(const float4*)&es[base + r][4 * k4];
                accS[r] = fmaf(ev.x, kv0.x, accS[r]);
                accG[r] = fmaf(ev.x, kv0.y, accG[r]);
                accS[r] = fmaf(ev.y, kv1.x, accS[r]);
                accG[r] = fmaf(ev.y, kv1.y, accG[r]);
                accS[r] = fmaf(ev.z, kv2.x, accS[r]);
                accG[r] = fmaf(ev.z, kv2.y, accG[r]);
                accS[r] = fmaf(ev.w, kv3.x, accS[r]);
                accG[r] = fmaf(ev.w, kv3.y, accG[r]);
            }
        }
#pragma unroll
        for (int r = 0; r < 8; ++r) {
            size_t e = e0 + base + r;
            int src = pidx[2 * e], dst = pidx[2 * e + 1];
            float2 pv = *(const float2*)&PQ[(size_t)src * 512 + 2 * n];
            float2 qv = *(const float2*)&PQ[(size_t)dst * 512 + 256 + 2 * n];
            float s = accS[r] + pv.x + qv.x + bsn;
            float g = accG[r] + pv.y + qv.y + bgn;
            atomicAdd(&acc[(size_t)src * AD + n], sigmoid_fast(s) * softplus_f(g));
        }
    }
}

// ===== launch =====
extern "C" void kernel_launch(void* const* d_in, const int* in_sizes, int n_in,
                              void* d_out, int out_size, void* d_ws, size_t ws_size,
                              hipStream_t stream)
{
    const float* atom = (const float*)d_in[0];
    const float* ef   = (const float*)d_in[1];
    const float* Ks   = (const float*)d_in[3];
    const float* bs   = (const float*)d_in[4];
    const float* Kg   = (const float*)d_in[5];
    const float* bg   = (const float*)d_in[6];
    const int*   pidx = (const int*)d_in[7];

    float* acc = (float*)d_out;

    char* w = (char*)d_ws;
    const size_t PQ_B   = (size_t)NN * 256 * 4;   //  51.2 MB
    const size_t C_B    = (size_t)NE * 128 * 4;   // 409.6 MB
    const size_t BN_B   = 16384 * 16;             // 256 KB
    const size_t CNT_B  = (size_t)NN * 4;
    const size_t IDX_B  = (size_t)NE * 4;
    const size_t PART_B = 256 * 4;
    unsigned* PQ32 = (unsigned*)w;  w += PQ_B;
    unsigned* C32  = (unsigned*)w;  w += C_B;
    bf16x8*   Bn   = (bf16x8*)w;    w += BN_B;
    unsigned* cnt  = (unsigned*)w;  w += CNT_B;
    unsigned* curp = (unsigned*)w;  w += CNT_B;
    int*      sid  = (int*)w;       w += IDX_B;
    int2*     sdp  = (int2*)w;      w += 2 * IDX_B;
    unsigned* part = (unsigned*)w;  w += PART_B;
    const size_t TOTAL_A = PQ_B + C_B + BN_B + 2 * CNT_B + 3 * IDX_B + PART_B;

    if (ws_size >= TOTAL_A) {
        hipMemsetAsync(cnt, 0, CNT_B, stream);
        bn_prep<<<64, 256, 0, stream>>>(Ks, Kg, Bn);
        hist_k<<<NE / 256, 256, 0, stream>>>(pidx, cnt);
        scan1_k<<<NSCAN, 256, 0, stream>>>(cnt, curp, part);
        scan2_k<<<1, 256, 0, stream>>>(part);
        scan3_k<<<NSCAN, 256, 0, stream>>>(curp, part);
        scatter_k<<<NE / 256, 256, 0, stream>>>(pidx, curp, sid, sdp);
        edge_c_mfma<<<2048, 512, 0, stream>>>(ef, Ks, Kg, sid, C32);

        for (int s = 0; s < NSTEPS; ++s) {
            node_mm_mfma<<<NROWB, 512, 0, stream>>>(atom, acc, Bn, PQ32,
                                                    s == 0 ? 0 : 1);
            edge_apply_sorted<<<NE / 256, 256, 0, stream>>>(
                (const char*)C32, (const char*)PQ32, sdp, bs, bg, acc);
        }
        act_k<<<(NN * AD) / 1024, 256, 0, stream>>>(acc);
    } else {
        float* PQ = (float*)d_ws;
        hipMemcpyAsync(acc, atom, (size_t)NN * AD * sizeof(float),
                       hipMemcpyDeviceToDevice, stream);
        for (int s = 0; s < NSTEPS; ++s) {
            node_mm_f32<<<NN / 8, 128, 0, stream>>>(acc, Ks, Kg, PQ);
            edge_fused<<<NE / 64, 256, 0, stream>>>(ef, Ks, Kg, PQ, pidx, bs, bg, acc);
            act_k<<<(NN * AD) / 1024, 256, 0, stream>>>(acc);
        }
    }
}

// Round 11
// 810.307 us; speedup vs baseline: 1.0036x; 1.0036x over previous
//
#include <hip/hip_runtime.h>
#include <hip/hip_bf16.h>
#include <math.h>

// CrystalGraphConvolution — MI355X round 11
// vs r10: (1) prep_step0 = grid-fused {edge_c tile loop | node_mm step 0} —
// independent work overlapped in one launch; (2) apply segments 64 -> 32
// edges/wave (2x wave parallelism vs latency), grid NE/128.

#define NN 50000
#define NE 800000
#define AD 128
#define ED 64
#define NSTEPS 3
#define NTILES (NE / 64)          // 12500
#define NSCAN  ((NN + 255) / 256) // 196
#define NROWB  ((NN + 63) / 64)   // 782
#define EC_BLKS 2048

#define L2E 1.4426950408889634f
#define LN2 0.6931471805599453f

typedef __attribute__((ext_vector_type(8))) __bf16 bf16x8;
typedef __attribute__((ext_vector_type(4))) float  f32x4;
typedef __attribute__((ext_vector_type(2))) unsigned u32x2;

__device__ __forceinline__ float softplus_f(float x) {      // precise (output path)
    return fmaxf(x, 0.f) + log1pf(__expf(-fabsf(x)));
}
__device__ __forceinline__ float sigmoid_fast(float x) {    // Tier B
    float e = __expf(-fabsf(x));
    float r = __builtin_amdgcn_rcpf(1.f + e);
    return (x >= 0.f) ? r : 1.f - r;
}
__device__ __forceinline__ unsigned short bf16_rne(float f) {
    unsigned u = __float_as_uint(f);
    unsigned r = u + 0x7fffu + ((u >> 16) & 1u);
    return (unsigned short)(r >> 16);
}
__device__ __forceinline__ unsigned pack_bf2(float s, float g) {
    return (unsigned)bf16_rne(s) | ((unsigned)bf16_rne(g) << 16);
}
__device__ __forceinline__ float unp_lo(unsigned v) { return __uint_as_float(v << 16); }
__device__ __forceinline__ float unp_hi(unsigned v) { return __uint_as_float(v & 0xffff0000u); }

__device__ __forceinline__ float nexp2_f(float x) {         // 2^(-x)
    float r; asm("v_exp_f32 %0, -%1" : "=v"(r) : "v"(x)); return r;
}
__device__ __forceinline__ float nexp2_abs_f(float x) {     // 2^(-|x|)
    float r; asm("v_exp_f32 %0, -abs(%1)" : "=v"(r) : "v"(x)); return r;
}
__device__ __forceinline__ float log2_f(float x) {
    float r; asm("v_log_f32 %0, %1" : "=v"(r) : "v"(x)); return r;
}

// ===== one-time B pre-pack for node GEMM =====
__global__ void __launch_bounds__(256) bn_prep(
    const float* __restrict__ Ks, const float* __restrict__ Kg,
    bf16x8* __restrict__ Bn)
{
    union U8 { short s[8]; bf16x8 v; };
    int idx = blockIdx.x * 256 + threadIdx.x;      // 64 blocks -> 16384
    int l4  = idx & 3;
    int col = (idx >> 2) & 127;
    int ki  = (idx >> 9) & 3;
    int hl  = (idx >> 11) & 1;
    int m   = (idx >> 12) & 1;
    int sel = (idx >> 13) & 1;
    const float* K = m ? Kg : Ks;
    U8 o;
#pragma unroll
    for (int j = 0; j < 8; ++j) {
        int k = sel * 128 + ki * 32 + l4 * 8 + j;
        float v = K[(size_t)k * AD + col];
        unsigned short h = bf16_rne(v);
        o.s[j] = (hl == 0) ? (short)h
                           : (short)bf16_rne(v - __uint_as_float((unsigned)h << 16));
    }
    Bn[idx] = o.v;
}

// ===== node_mm body (device fn), used by prep_step0 and node_mm_mfma =====
__device__ __forceinline__ void node_mm_body(
    const float* __restrict__ xin, float* __restrict__ acc,
    const bf16x8* __restrict__ Bn, unsigned* __restrict__ PQ32,
    int mode, int row0, int t, short* As_h, short* As_l)
{
    const int w = t >> 6, lane = t & 63;
    const int l4 = lane >> 4;

#pragma unroll
    for (int ii = 0; ii < 4; ++ii) {
        int idx = t + 512 * ii;
        int row = idx >> 5, c4 = idx & 31;
        int node = row0 + row;
        f32x4 v = {};
        if (node < NN) {
            if (mode == 0) {
                v = *(const f32x4*)&xin[(size_t)node * AD + 4 * c4];
                *(f32x4*)&acc[(size_t)node * AD + 4 * c4] = v;
            } else {
                f32x4 a = *(const f32x4*)&acc[(size_t)node * AD + 4 * c4];
                v[0] = softplus_f(a[0]); v[1] = softplus_f(a[1]);
                v[2] = softplus_f(a[2]); v[3] = softplus_f(a[3]);
                *(f32x4*)&acc[(size_t)node * AD + 4 * c4] = v;
            }
        }
        unsigned short h0 = bf16_rne(v[0]), h1 = bf16_rne(v[1]),
                       h2 = bf16_rne(v[2]), h3 = bf16_rne(v[3]);
        unsigned short l0 = bf16_rne(v[0] - __uint_as_float((unsigned)h0 << 16));
        unsigned short l1 = bf16_rne(v[1] - __uint_as_float((unsigned)h1 << 16));
        unsigned short l2 = bf16_rne(v[2] - __uint_as_float((unsigned)h2 << 16));
        unsigned short l3 = bf16_rne(v[3] - __uint_as_float((unsigned)h3 << 16));
        int sidx = (row * 128 + c4 * 4) ^ ((row & 7) << 3);
        *(short4*)&As_h[sidx] = make_short4((short)h0, (short)h1, (short)h2, (short)h3);
        *(short4*)&As_l[sidx] = make_short4((short)l0, (short)l1, (short)l2, (short)l3);
    }
    __syncthreads();

    const int col = w * 16 + (lane & 15);
#pragma unroll
    for (int sel = 0; sel < 2; ++sel) {
        bf16x8 bS[4][2], bG[4][2];
#pragma unroll
        for (int ki = 0; ki < 4; ++ki) {
#pragma unroll
            for (int hl = 0; hl < 2; ++hl) {
                bS[ki][hl] = Bn[(((sel * 2 + 0) * 2 + hl) * 4 + ki) * 512 + col * 4 + l4];
                bG[ki][hl] = Bn[(((sel * 2 + 1) * 2 + hl) * 4 + ki) * 512 + col * 4 + l4];
            }
        }
        f32x4 aS[4] = {}, aG[4] = {};
#pragma unroll
        for (int mt = 0; mt < 4; ++mt) {
            int row = mt * 16 + (lane & 15);
#pragma unroll
            for (int ki = 0; ki < 4; ++ki) {
                int idx = (row * 128 + ki * 32 + l4 * 8) ^ ((row & 7) << 3);
                bf16x8 ah = *(const bf16x8*)&As_h[idx];
                bf16x8 al = *(const bf16x8*)&As_l[idx];
                aS[mt] = __builtin_amdgcn_mfma_f32_16x16x32_bf16(ah, bS[ki][0], aS[mt], 0, 0, 0);
                aS[mt] = __builtin_amdgcn_mfma_f32_16x16x32_bf16(al, bS[ki][0], aS[mt], 0, 0, 0);
                aS[mt] = __builtin_amdgcn_mfma_f32_16x16x32_bf16(ah, bS[ki][1], aS[mt], 0, 0, 0);
                aG[mt] = __builtin_amdgcn_mfma_f32_16x16x32_bf16(ah, bG[ki][0], aG[mt], 0, 0, 0);
                aG[mt] = __builtin_amdgcn_mfma_f32_16x16x32_bf16(al, bG[ki][0], aG[mt], 0, 0, 0);
                aG[mt] = __builtin_amdgcn_mfma_f32_16x16x32_bf16(ah, bG[ki][1], aG[mt], 0, 0, 0);
            }
        }
#pragma unroll
        for (int mt = 0; mt < 4; ++mt) {
#pragma unroll
            for (int reg = 0; reg < 4; ++reg) {
                int node = row0 + mt * 16 + l4 * 4 + reg;
                if (node < NN)
                    PQ32[(size_t)node * 256 + sel * 128 + col] =
                        pack_bf2(aS[mt][reg] * L2E, aG[mt][reg] * L2E);
            }
        }
    }
}

// ===== edge_c body (device fn) =====
__device__ __forceinline__ void edge_c_body(
    const float* __restrict__ ef, const float* __restrict__ Ks,
    const float* __restrict__ Kg, const int* __restrict__ sid,
    unsigned* __restrict__ C32, int bid, int nblk, int t,
    short* As_h, short* As_l)
{
    const int w = t >> 6, lane = t & 63;

    union U8 { short s[8]; bf16x8 v; };
    bf16x8 bS[2][2], bG[2][2];
    {
        const int col = w * 16 + (lane & 15);
#pragma unroll
        for (int ki = 0; ki < 2; ++ki) {
            U8 sh_, sl_, gh_, gl_;
            const int kbase = 2 * AD + ki * 32 + (lane >> 4) * 8;
#pragma unroll
            for (int j = 0; j < 8; ++j) {
                float vs = Ks[(size_t)(kbase + j) * AD + col];
                float vg = Kg[(size_t)(kbase + j) * AD + col];
                unsigned short h = bf16_rne(vs);
                sh_.s[j] = (short)h;
                sl_.s[j] = (short)bf16_rne(vs - __uint_as_float((unsigned)h << 16));
                h = bf16_rne(vg);
                gh_.s[j] = (short)h;
                gl_.s[j] = (short)bf16_rne(vg - __uint_as_float((unsigned)h << 16));
            }
            bS[ki][0] = sh_.v; bS[ki][1] = sl_.v;
            bG[ki][0] = gh_.v; bG[ki][1] = gl_.v;
        }
    }

    const int srow = t >> 4, sc4 = t & 15;
    f32x4 pf0, pf1;
    {
        int ea = sid[(size_t)bid * 64 + srow];
        int eb = sid[(size_t)bid * 64 + srow + 32];
        pf0 = __builtin_nontemporal_load((const f32x4*)&ef[(size_t)ea * 64 + 4 * sc4]);
        pf1 = __builtin_nontemporal_load((const f32x4*)&ef[(size_t)eb * 64 + 4 * sc4]);
    }

    for (int tile = bid; tile < NTILES; tile += nblk) {
        __syncthreads();
        {
            f32x4 v[2] = {pf0, pf1};
#pragma unroll
            for (int ii = 0; ii < 2; ++ii) {
                int row = srow + 32 * ii;
                float a0 = v[ii][0], a1 = v[ii][1], a2 = v[ii][2], a3 = v[ii][3];
                unsigned short h0 = bf16_rne(a0), h1 = bf16_rne(a1),
                               h2 = bf16_rne(a2), h3 = bf16_rne(a3);
                unsigned short l0 = bf16_rne(a0 - __uint_as_float((unsigned)h0 << 16));
                unsigned short l1 = bf16_rne(a1 - __uint_as_float((unsigned)h1 << 16));
                unsigned short l2 = bf16_rne(a2 - __uint_as_float((unsigned)h2 << 16));
                unsigned short l3 = bf16_rne(a3 - __uint_as_float((unsigned)h3 << 16));
                int sidx = (row * 64 + sc4 * 4) ^ ((row & 7) << 3);
                *(short4*)&As_h[sidx] = make_short4((short)h0, (short)h1, (short)h2, (short)h3);
                *(short4*)&As_l[sidx] = make_short4((short)l0, (short)l1, (short)l2, (short)l3);
            }
        }
        {
            int nxt = tile + nblk;
            if (nxt < NTILES) {
                int ea = sid[(size_t)nxt * 64 + srow];
                int eb = sid[(size_t)nxt * 64 + srow + 32];
                pf0 = __builtin_nontemporal_load((const f32x4*)&ef[(size_t)ea * 64 + 4 * sc4]);
                pf1 = __builtin_nontemporal_load((const f32x4*)&ef[(size_t)eb * 64 + 4 * sc4]);
            }
        }
        __syncthreads();

        f32x4 accS[4] = {}, accG[4] = {};
#pragma unroll
        for (int mt = 0; mt < 4; ++mt) {
#pragma unroll
            for (int ki = 0; ki < 2; ++ki) {
                int row = mt * 16 + (lane & 15);
                int idx = (row * 64 + ki * 32 + (lane >> 4) * 8) ^ ((row & 7) << 3);
                bf16x8 ah = *(const bf16x8*)&As_h[idx];
                bf16x8 al = *(const bf16x8*)&As_l[idx];
                accS[mt] = __builtin_amdgcn_mfma_f32_16x16x32_bf16(ah, bS[ki][0], accS[mt], 0, 0, 0);
                accS[mt] = __builtin_amdgcn_mfma_f32_16x16x32_bf16(al, bS[ki][0], accS[mt], 0, 0, 0);
                accS[mt] = __builtin_amdgcn_mfma_f32_16x16x32_bf16(ah, bS[ki][1], accS[mt], 0, 0, 0);
                accG[mt] = __builtin_amdgcn_mfma_f32_16x16x32_bf16(ah, bG[ki][0], accG[mt], 0, 0, 0);
                accG[mt] = __builtin_amdgcn_mfma_f32_16x16x32_bf16(al, bG[ki][0], accG[mt], 0, 0, 0);
                accG[mt] = __builtin_amdgcn_mfma_f32_16x16x32_bf16(ah, bG[ki][1], accG[mt], 0, 0, 0);
            }
        }
        const size_t p0 = (size_t)tile * 64;
#pragma unroll
        for (int mt = 0; mt < 4; ++mt) {
#pragma unroll
            for (int reg = 0; reg < 4; ++reg) {
                int row = mt * 16 + (lane >> 4) * 4 + reg;
                unsigned val = pack_bf2(accS[mt][reg] * L2E, accG[mt][reg] * L2E);
                __builtin_nontemporal_store(val,
                    &C32[(p0 + row) * 128 + w * 16 + (lane & 15)]);
            }
        }
    }
}

// ===== fused one-time kernel: edge_c (blocks < EC_BLKS) | node_mm step0 =====
__global__ void __launch_bounds__(512) prep_step0(
    const float* __restrict__ ef, const float* __restrict__ Ks,
    const float* __restrict__ Kg, const int* __restrict__ sid,
    unsigned* __restrict__ C32, const float* __restrict__ xin,
    float* __restrict__ acc, const bf16x8* __restrict__ Bn,
    unsigned* __restrict__ PQ32)
{
    __shared__ short As_h[64 * 128];
    __shared__ short As_l[64 * 128];
    const int t = threadIdx.x;
    const int bid = blockIdx.x;
    if (bid < EC_BLKS)
        edge_c_body(ef, Ks, Kg, sid, C32, bid, EC_BLKS, t, As_h, As_l);
    else
        node_mm_body(xin, acc, Bn, PQ32, 0, (bid - EC_BLKS) * 64, t, As_h, As_l);
}

// ===== node projections (steps >= 1) =====
__global__ void __launch_bounds__(512) node_mm_mfma(
    const float* __restrict__ xin, float* __restrict__ acc,
    const bf16x8* __restrict__ Bn, unsigned* __restrict__ PQ32, int mode)
{
    __shared__ short As_h[64 * 128];
    __shared__ short As_l[64 * 128];
    node_mm_body(xin, acc, Bn, PQ32, mode, blockIdx.x * 64, threadIdx.x, As_h, As_l);
}

// ===== sort machinery =====
__global__ void __launch_bounds__(256) hist_k(const int* __restrict__ pidx,
                                              unsigned* __restrict__ cnt)
{
    int e = blockIdx.x * 256 + threadIdx.x;
    atomicAdd(&cnt[pidx[2 * e]], 1u);
}

__global__ void __launch_bounds__(256) scan1_k(const unsigned* __restrict__ cnt,
                                               unsigned* __restrict__ cur,
                                               unsigned* __restrict__ part)
{
    __shared__ unsigned tmp[256];
    const int t = threadIdx.x;
    const int bin = blockIdx.x * 256 + t;
    unsigned v = (bin < NN) ? cnt[bin] : 0u;
    tmp[t] = v;
    __syncthreads();
    for (int off = 1; off < 256; off <<= 1) {
        unsigned a = (t >= off) ? tmp[t - off] : 0u;
        __syncthreads();
        tmp[t] += a;
        __syncthreads();
    }
    if (bin < NN) cur[bin] = tmp[t] - v;
    if (t == 255) part[blockIdx.x] = tmp[255];
}

__global__ void __launch_bounds__(256) scan2_k(unsigned* __restrict__ part)
{
    __shared__ unsigned tmp[256];
    const int t = threadIdx.x;
    unsigned v = (t < NSCAN) ? part[t] : 0u;
    tmp[t] = v;
    __syncthreads();
    for (int off = 1; off < 256; off <<= 1) {
        unsigned a = (t >= off) ? tmp[t - off] : 0u;
        __syncthreads();
        tmp[t] += a;
        __syncthreads();
    }
    if (t < NSCAN) part[t] = tmp[t] - v;
}

__global__ void __launch_bounds__(256) scan3_k(unsigned* __restrict__ cur,
                                               const unsigned* __restrict__ part)
{
    const int bin = blockIdx.x * 256 + threadIdx.x;
    if (bin < NN) cur[bin] += part[blockIdx.x];
}

// scaled offsets packed: sdp[pos] = { src*1024, dst*1024+512 }
__global__ void __launch_bounds__(256) scatter_k(
    const int* __restrict__ pidx, unsigned* __restrict__ cur,
    int* __restrict__ sid, int2* __restrict__ sdp)
{
    int e = blockIdx.x * 256 + threadIdx.x;
    int s = pidx[2 * e], d = pidx[2 * e + 1];
    unsigned pos = atomicAdd(&cur[s], 1u);
    sid[pos] = e;
    sdp[pos] = make_int2(s << 10, (d << 10) + 512);
}

// ===== sorted apply v6: 32 edges/wave, log2-domain, depth-8 rings =====
__global__ void __launch_bounds__(256) edge_apply_sorted(
    const char* __restrict__ C8, const char* __restrict__ PQ8,
    const int2* __restrict__ sdp,
    const float* __restrict__ bs, const float* __restrict__ bg,
    float* __restrict__ acc)
{
    const int t = threadIdx.x & 63;
    const int w = threadIdx.x >> 6;
    const size_t p0 = ((size_t)blockIdx.x * 4 + w) * 32;
    const int2 sd = sdp[p0 + (t & 31)];   // lanes 0..31 hold the segment's edges
    const int srcv = sd.x, dstv = sd.y;

    const float2 bsv = *(const float2*)&bs[2 * t];
    const float2 bgv = *(const float2*)&bg[2 * t];
    const float bsA = bsv.x * L2E, bsB = bsv.y * L2E;
    const float bgA = bgv.x * L2E, bgB = bgv.y * L2E;

    const char* PQl = PQ8 + 8 * t;
    char* accl = (char*)acc + 8 * t;
    const char* Cl = C8 + p0 * 512 + 8 * t;

#define RL(v, i) __builtin_amdgcn_readlane((v), (i))
#define LOADC(i) __builtin_nontemporal_load((const u32x2*)(Cl + (i) * 512))
#define LOADQ(i) (*(const u32x2*)(PQl + RL(dstv, (i))))
#define LOADP(s_) (*(const u32x2*)(PQl + (s_)))

    int cur = RL(srcv, 0);
    u32x2 pv = LOADP(cur);
    float psA = unp_lo(pv.x) + bsA, pgA = unp_hi(pv.x) + bgA;
    float psB = unp_lo(pv.y) + bsB, pgB = unp_hi(pv.y) + bgB;

    u32x2 c0 = LOADC(0), c1 = LOADC(1), c2 = LOADC(2), c3 = LOADC(3),
          c4 = LOADC(4), c5 = LOADC(5), c6 = LOADC(6), c7 = LOADC(7);
    u32x2 q0 = LOADQ(0), q1 = LOADQ(1), q2 = LOADQ(2), q3 = LOADQ(3),
          q4 = LOADQ(4), q5 = LOADQ(5), q6 = LOADQ(6), q7 = LOADQ(7);
    u32x2 r0 = pv, r1 = pv, r2 = pv, r3 = pv, r4 = pv, r5 = pv, r6 = pv, r7 = pv;
    if (RL(srcv, 1) != RL(srcv, 0)) r1 = LOADP(RL(srcv, 1));
    if (RL(srcv, 2) != RL(srcv, 1)) r2 = LOADP(RL(srcv, 2));
    if (RL(srcv, 3) != RL(srcv, 2)) r3 = LOADP(RL(srcv, 3));
    if (RL(srcv, 4) != RL(srcv, 3)) r4 = LOADP(RL(srcv, 4));
    if (RL(srcv, 5) != RL(srcv, 4)) r5 = LOADP(RL(srcv, 5));
    if (RL(srcv, 6) != RL(srcv, 5)) r6 = LOADP(RL(srcv, 6));
    if (RL(srcv, 7) != RL(srcv, 6)) r7 = LOADP(RL(srcv, 7));
    float accA = 0.f, accB = 0.f;

#define FLUSH                                                              \
    atomicAdd((float*)(accl + ((unsigned)cur >> 1)),     LN2 * accA);      \
    atomicAdd((float*)(accl + ((unsigned)cur >> 1) + 4), LN2 * accB);

#define CORE(i, cc, qq, rr)                                                \
    {                                                                      \
        int src_ = RL(srcv, (i));                                          \
        if (src_ != cur) {                                                 \
            FLUSH;                                                         \
            accA = 0.f; accB = 0.f; cur = src_;                            \
            psA = unp_lo(rr.x) + bsA; pgA = unp_hi(rr.x) + bgA;            \
            psB = unp_lo(rr.y) + bsB; pgB = unp_hi(rr.y) + bgB;            \
        }                                                                  \
        float sA = unp_lo(cc.x) + unp_lo(qq.x) + psA;                      \
        float gA = unp_hi(cc.x) + unp_hi(qq.x) + pgA;                      \
        float sB = unp_lo(cc.y) + unp_lo(qq.y) + psB;                      \
        float gB = unp_hi(cc.y) + unp_hi(qq.y) + pgB;                      \
        float spA = fmaxf(gA, 0.f) + log2_f(1.f + nexp2_abs_f(gA));        \
        float spB = fmaxf(gB, 0.f) + log2_f(1.f + nexp2_abs_f(gB));       \
        accA = fmaf(__builtin_amdgcn_rcpf(1.f + nexp2_f(sA)), spA, accA);  \
        accB = fmaf(__builtin_amdgcn_rcpf(1.f + nexp2_f(sB)), spB, accB);  \
    }

#define STEP(i, cc, qq, rr)                                                \
    CORE(i, cc, qq, rr)                                                    \
    {                                                                      \
        cc = LOADC((i) + 8);                                               \
        qq = LOADQ((i) + 8);                                               \
        if (RL(srcv, (i) + 8) != RL(srcv, (i) + 7))                        \
            rr = LOADP(RL(srcv, (i) + 8));                                 \
    }

    for (int b = 0; b < 24; b += 8) {
        STEP(b + 0, c0, q0, r0)
        STEP(b + 1, c1, q1, r1)
        STEP(b + 2, c2, q2, r2)
        STEP(b + 3, c3, q3, r3)
        STEP(b + 4, c4, q4, r4)
        STEP(b + 5, c5, q5, r5)
        STEP(b + 6, c6, q6, r6)
        STEP(b + 7, c7, q7, r7)
    }
    CORE(24, c0, q0, r0)
    CORE(25, c1, q1, r1)
    CORE(26, c2, q2, r2)
    CORE(27, c3, q3, r3)
    CORE(28, c4, q4, r4)
    CORE(29, c5, q5, r5)
    CORE(30, c6, q6, r6)
    CORE(31, c7, q7, r7)
    FLUSH;

#undef STEP
#undef CORE
#undef FLUSH
#undef LOADP
#undef LOADQ
#undef LOADC
#undef RL
}

// ===== final softplus =====
__global__ void __launch_bounds__(256) act_k(float* __restrict__ acc)
{
    size_t i = ((size_t)blockIdx.x * 256 + threadIdx.x) * 4;
    float4 v = *(float4*)&acc[i];
    v.x = softplus_f(v.x);
    v.y = softplus_f(v.y);
    v.z = softplus_f(v.z);
    v.w = softplus_f(v.w);
    *(float4*)&acc[i] = v;
}

// ===== Tier B fallback (round-1, known good) =====
__global__ void __launch_bounds__(128) node_mm_f32(
    const float* __restrict__ x, const float* __restrict__ Ks,
    const float* __restrict__ Kg, float* __restrict__ PQ)
{
    __shared__ float xs[8][AD];
    const int t = threadIdx.x;
    const int row0 = blockIdx.x * 8;
#pragma unroll
    for (int r = 0; r < 8; ++r) xs[r][t] = x[(size_t)(row0 + r) * AD + t];
    __syncthreads();
    float aPs[8] = {}, aQs[8] = {}, aPg[8] = {}, aQg[8] = {};
    for (int k = 0; k < AD; ++k) {
        float ks_s = Ks[k * AD + t];
        float ks_d = Ks[(AD + k) * AD + t];
        float kg_s = Kg[k * AD + t];
        float kg_d = Kg[(AD + k) * AD + t];
#pragma unroll
        for (int r = 0; r < 8; ++r) {
            float xv = xs[r][k];
            aPs[r] = fmaf(xv, ks_s, aPs[r]);
            aQs[r] = fmaf(xv, ks_d, aQs[r]);
            aPg[r] = fmaf(xv, kg_s, aPg[r]);
            aQg[r] = fmaf(xv, kg_d, aQg[r]);
        }
    }
#pragma unroll
    for (int r = 0; r < 8; ++r) {
        float* o = PQ + (size_t)(row0 + r) * 512;
        *(float2*)&o[2 * t]       = make_float2(aPs[r], aPg[r]);
        *(float2*)&o[256 + 2 * t] = make_float2(aQs[r], aQg[r]);
    }
}

__global__ void __launch_bounds__(256) edge_fused(
    const float* __restrict__ ef, const float* __restrict__ Ks,
    const float* __restrict__ Kg, const float* __restrict__ PQ,
    const int* __restrict__ pidx, const float* __restrict__ bs,
    const float* __restrict__ bg, float* __restrict__ acc)
{
    __shared__ float KB[ED][2 * AD];
    __shared__ float es[64][ED];
    const int t = threadIdx.x;
    for (int i = t; i < ED * AD; i += 256) {
        int k = i >> 7, n = i & 127;
        KB[k][2 * n]     = Ks[(2 * AD + k) * AD + n];
        KB[k][2 * n + 1] = Kg[(2 * AD + k) * AD + n];
    }
    const size_t e0 = (size_t)blockIdx.x * 64;
    for (int i = t; i < 64 * ED; i += 256) ((float*)es)[i] = ef[e0 * ED + i];
    __syncthreads();
    const int le = t >> 7, n = t & 127;
    const float bsn = bs[n], bgn = bg[n];
    for (int base = le * 8; base < 64; base += 16) {
        float accS[8] = {}, accG[8] = {};
        for (int k4 = 0; k4 < ED / 4; ++k4) {
            float2 kv0 = *(const float2*)&KB[4 * k4 + 0][2 * n];
            float2 kv1 = *(const float2*)&KB[4 * k4 + 1][2 * n];
            float2 kv2 = *(const float2*)&KB[4 * k4 + 2][2 * n];
            float2 kv3 = *(const float2*)&KB[4 * k4 + 3][2 * n];
#pragma unroll
            for (int r = 0; r < 8; ++r) {
                float4 ev = *(const float4*)&es[base + r][4 * k4];
                accS[r] = fmaf(ev.x, kv0.x, accS[r]);
                accG[r] = fmaf(ev.x, kv0.y, accG[r]);
                accS[r] = fmaf(ev.y, kv1.x, accS[r]);
                accG[r] = fmaf(ev.y, kv1.y, accG[r]);
                accS[r] = fmaf(ev.z, kv2.x, accS[r]);
                accG[r] = fmaf(ev.z, kv2.y, accG[r]);
                accS[r] = fmaf(ev.w, kv3.x, accS[r]);
                accG[r] = fmaf(ev.w, kv3.y, accG[r]);
            }
        }
#pragma unroll
        for (int r = 0; r < 8; ++r) {
            size_t e = e0 + base + r;
            int src = pidx[2 * e], dst = pidx[2 * e + 1];
            float2 pv = *(const float2*)&PQ[(size_t)src * 512 + 2 * n];
            float2 qv = *(const float2*)&PQ[(size_t)dst * 512 + 256 + 2 * n];
            float s = accS[r] + pv.x + qv.x + bsn;
            float g = accG[r] + pv.y + qv.y + bgn;
            atomicAdd(&acc[(size_t)src * AD + n], sigmoid_fast(s) * softplus_f(g));
        }
    }
}

// ===== launch =====
extern "C" void kernel_launch(void* const* d_in, const int* in_sizes, int n_in,
                              void* d_out, int out_size, void* d_ws, size_t ws_size,
                              hipStream_t stream)
{
    const float* atom = (const float*)d_in[0];
    const float* ef   = (const float*)d_in[1];
    const float* Ks   = (const float*)d_in[3];
    const float* bs   = (const float*)d_in[4];
    const float* Kg   = (const float*)d_in[5];
    const float* bg   = (const float*)d_in[6];
    const int*   pidx = (const int*)d_in[7];

    float* acc = (float*)d_out;

    char* w = (char*)d_ws;
    const size_t PQ_B   = (size_t)NN * 256 * 4;   //  51.2 MB
    const size_t C_B    = (size_t)NE * 128 * 4;   // 409.6 MB
    const size_t BN_B   = 16384 * 16;             // 256 KB
    const size_t CNT_B  = (size_t)NN * 4;
    const size_t IDX_B  = (size_t)NE * 4;
    const size_t PART_B = 256 * 4;
    unsigned* PQ32 = (unsigned*)w;  w += PQ_B;
    unsigned* C32  = (unsigned*)w;  w += C_B;
    bf16x8*   Bn   = (bf16x8*)w;    w += BN_B;
    unsigned* cnt  = (unsigned*)w;  w += CNT_B;
    unsigned* curp = (unsigned*)w;  w += CNT_B;
    int*      sid  = (int*)w;       w += IDX_B;
    int2*     sdp  = (int2*)w;      w += 2 * IDX_B;
    unsigned* part = (unsigned*)w;  w += PART_B;
    const size_t TOTAL_A = PQ_B + C_B + BN_B + 2 * CNT_B + 3 * IDX_B + PART_B;

    if (ws_size >= TOTAL_A) {
        hipMemsetAsync(cnt, 0, CNT_B, stream);
        bn_prep<<<64, 256, 0, stream>>>(Ks, Kg, Bn);
        hist_k<<<NE / 256, 256, 0, stream>>>(pidx, cnt);
        scan1_k<<<NSCAN, 256, 0, stream>>>(cnt, curp, part);
        scan2_k<<<1, 256, 0, stream>>>(part);
        scan3_k<<<NSCAN, 256, 0, stream>>>(curp, part);
        scatter_k<<<NE / 256, 256, 0, stream>>>(pidx, curp, sid, sdp);

        // fused: edge_c (blocks 0..2047) + node_mm step0 (blocks 2048..2829)
        prep_step0<<<EC_BLKS + NROWB, 512, 0, stream>>>(ef, Ks, Kg, sid, C32,
                                                        atom, acc, Bn, PQ32);

        for (int s = 0; s < NSTEPS; ++s) {
            if (s > 0)
                node_mm_mfma<<<NROWB, 512, 0, stream>>>(atom, acc, Bn, PQ32, 1);
            edge_apply_sorted<<<NE / 128, 256, 0, stream>>>(
                (const char*)C32, (const char*)PQ32, sdp, bs, bg, acc);
        }
        act_k<<<(NN * AD) / 1024, 256, 0, stream>>>(acc);
    } else {
        float* PQ = (float*)d_ws;
        hipMemcpyAsync(acc, atom, (size_t)NN * AD * sizeof(float),
                       hipMemcpyDeviceToDevice, stream);
        for (int s = 0; s < NSTEPS; ++s) {
            node_mm_f32<<<NN / 8, 128, 0, stream>>>(acc, Ks, Kg, PQ);
            edge_fused<<<NE / 64, 256, 0, stream>>>(ef, Ks, Kg, PQ, pidx, bs, bg, acc);
            act_k<<<(NN * AD) / 1024, 256, 0, stream>>>(acc);
        }
    }
}

// Round 12
// 758.232 us; speedup vs baseline: 1.0725x; 1.0687x over previous
//
#include <hip/hip_runtime.h>
#include <hip/hip_bf16.h>
#include <math.h>

// CrystalGraphConvolution — MI355X round 12
// vs r11: revert prep_step0 fusion (r10 separate kernels). Apply v7: 32
// edges/wave + sched_barrier(0) pins prefetch issue (r10 VGPR=28 proved the
// compiler sank all ring loads -> no real MLP; barriers force true depth-8).
// node_mm mode-1 + act_k use HW exp2/log2 softplus (no libcalls).

#define NN 50000
#define NE 800000
#define AD 128
#define ED 64
#define NSTEPS 3
#define NTILES (NE / 64)          // 12500
#define NSCAN  ((NN + 255) / 256) // 196
#define NROWB  ((NN + 63) / 64)   // 782

#define L2E 1.4426950408889634f
#define LN2 0.6931471805599453f

typedef __attribute__((ext_vector_type(8))) __bf16 bf16x8;
typedef __attribute__((ext_vector_type(4))) float  f32x4;
typedef __attribute__((ext_vector_type(2))) unsigned u32x2;

__device__ __forceinline__ float softplus_f(float x) {      // Tier B only
    return fmaxf(x, 0.f) + log1pf(__expf(-fabsf(x)));
}
__device__ __forceinline__ float sigmoid_fast(float x) {    // Tier B
    float e = __expf(-fabsf(x));
    float r = __builtin_amdgcn_rcpf(1.f + e);
    return (x >= 0.f) ? r : 1.f - r;
}
__device__ __forceinline__ unsigned short bf16_rne(float f) {
    unsigned u = __float_as_uint(f);
    unsigned r = u + 0x7fffu + ((u >> 16) & 1u);
    return (unsigned short)(r >> 16);
}
__device__ __forceinline__ unsigned pack_bf2(float s, float g) {
    return (unsigned)bf16_rne(s) | ((unsigned)bf16_rne(g) << 16);
}
__device__ __forceinline__ float unp_lo(unsigned v) { return __uint_as_float(v << 16); }
__device__ __forceinline__ float unp_hi(unsigned v) { return __uint_as_float(v & 0xffff0000u); }

__device__ __forceinline__ float nexp2_f(float x) {         // 2^(-x)
    float r; asm("v_exp_f32 %0, -%1" : "=v"(r) : "v"(x)); return r;
}
__device__ __forceinline__ float nexp2_abs_f(float x) {     // 2^(-|x|)
    float r; asm("v_exp_f32 %0, -abs(%1)" : "=v"(r) : "v"(x)); return r;
}
__device__ __forceinline__ float log2_f(float x) {
    float r; asm("v_log_f32 %0, %1" : "=v"(r) : "v"(x)); return r;
}
// HW softplus: ln2 * (max(y,0) + log2(1 + 2^-|y|)), y = x*log2e. rel err ~1e-6.
__device__ __forceinline__ float softplus_hw(float x) {
    float y = x * L2E;
    return LN2 * (fmaxf(y, 0.f) + log2_f(1.f + nexp2_abs_f(y)));
}

// ===== one-time B pre-pack for node GEMM =====
__global__ void __launch_bounds__(256) bn_prep(
    const float* __restrict__ Ks, const float* __restrict__ Kg,
    bf16x8* __restrict__ Bn)
{
    union U8 { short s[8]; bf16x8 v; };
    int idx = blockIdx.x * 256 + threadIdx.x;      // 64 blocks -> 16384
    int l4  = idx & 3;
    int col = (idx >> 2) & 127;
    int ki  = (idx >> 9) & 3;
    int hl  = (idx >> 11) & 1;
    int m   = (idx >> 12) & 1;
    int sel = (idx >> 13) & 1;
    const float* K = m ? Kg : Ks;
    U8 o;
#pragma unroll
    for (int j = 0; j < 8; ++j) {
        int k = sel * 128 + ki * 32 + l4 * 8 + j;
        float v = K[(size_t)k * AD + col];
        unsigned short h = bf16_rne(v);
        o.s[j] = (hl == 0) ? (short)h
                           : (short)bf16_rne(v - __uint_as_float((unsigned)h << 16));
    }
    Bn[idx] = o.v;
}

// ===== node projections via MFMA (hi/lo), + x maintenance; outputs xL2E-scaled =====
__global__ void __launch_bounds__(512, 1) node_mm_mfma(
    const float* __restrict__ xin, float* __restrict__ acc,
    const bf16x8* __restrict__ Bn, unsigned* __restrict__ PQ32, int mode)
{
    __shared__ short As_h[64 * 128];
    __shared__ short As_l[64 * 128];
    const int t = threadIdx.x;
    const int w = t >> 6, lane = t & 63;
    const int l4 = lane >> 4;
    const int row0 = blockIdx.x * 64;

#pragma unroll
    for (int ii = 0; ii < 4; ++ii) {
        int idx = t + 512 * ii;
        int row = idx >> 5, c4 = idx & 31;
        int node = row0 + row;
        f32x4 v = {};
        if (node < NN) {
            if (mode == 0) {
                v = *(const f32x4*)&xin[(size_t)node * AD + 4 * c4];
                *(f32x4*)&acc[(size_t)node * AD + 4 * c4] = v;
            } else {
                f32x4 a = *(const f32x4*)&acc[(size_t)node * AD + 4 * c4];
                v[0] = softplus_hw(a[0]); v[1] = softplus_hw(a[1]);
                v[2] = softplus_hw(a[2]); v[3] = softplus_hw(a[3]);
                *(f32x4*)&acc[(size_t)node * AD + 4 * c4] = v;
            }
        }
        unsigned short h0 = bf16_rne(v[0]), h1 = bf16_rne(v[1]),
                       h2 = bf16_rne(v[2]), h3 = bf16_rne(v[3]);
        unsigned short l0 = bf16_rne(v[0] - __uint_as_float((unsigned)h0 << 16));
        unsigned short l1 = bf16_rne(v[1] - __uint_as_float((unsigned)h1 << 16));
        unsigned short l2 = bf16_rne(v[2] - __uint_as_float((unsigned)h2 << 16));
        unsigned short l3 = bf16_rne(v[3] - __uint_as_float((unsigned)h3 << 16));
        int sidx = (row * 128 + c4 * 4) ^ ((row & 7) << 3);
        *(short4*)&As_h[sidx] = make_short4((short)h0, (short)h1, (short)h2, (short)h3);
        *(short4*)&As_l[sidx] = make_short4((short)l0, (short)l1, (short)l2, (short)l3);
    }
    __syncthreads();

    const int col = w * 16 + (lane & 15);
#pragma unroll
    for (int sel = 0; sel < 2; ++sel) {
        bf16x8 bS[4][2], bG[4][2];
#pragma unroll
        for (int ki = 0; ki < 4; ++ki) {
#pragma unroll
            for (int hl = 0; hl < 2; ++hl) {
                bS[ki][hl] = Bn[(((sel * 2 + 0) * 2 + hl) * 4 + ki) * 512 + col * 4 + l4];
                bG[ki][hl] = Bn[(((sel * 2 + 1) * 2 + hl) * 4 + ki) * 512 + col * 4 + l4];
            }
        }
        f32x4 aS[4] = {}, aG[4] = {};
#pragma unroll
        for (int mt = 0; mt < 4; ++mt) {
            int row = mt * 16 + (lane & 15);
#pragma unroll
            for (int ki = 0; ki < 4; ++ki) {
                int idx = (row * 128 + ki * 32 + l4 * 8) ^ ((row & 7) << 3);
                bf16x8 ah = *(const bf16x8*)&As_h[idx];
                bf16x8 al = *(const bf16x8*)&As_l[idx];
                aS[mt] = __builtin_amdgcn_mfma_f32_16x16x32_bf16(ah, bS[ki][0], aS[mt], 0, 0, 0);
                aS[mt] = __builtin_amdgcn_mfma_f32_16x16x32_bf16(al, bS[ki][0], aS[mt], 0, 0, 0);
                aS[mt] = __builtin_amdgcn_mfma_f32_16x16x32_bf16(ah, bS[ki][1], aS[mt], 0, 0, 0);
                aG[mt] = __builtin_amdgcn_mfma_f32_16x16x32_bf16(ah, bG[ki][0], aG[mt], 0, 0, 0);
                aG[mt] = __builtin_amdgcn_mfma_f32_16x16x32_bf16(al, bG[ki][0], aG[mt], 0, 0, 0);
                aG[mt] = __builtin_amdgcn_mfma_f32_16x16x32_bf16(ah, bG[ki][1], aG[mt], 0, 0, 0);
            }
        }
#pragma unroll
        for (int mt = 0; mt < 4; ++mt) {
#pragma unroll
            for (int reg = 0; reg < 4; ++reg) {
                int node = row0 + mt * 16 + l4 * 4 + reg;
                if (node < NN)
                    PQ32[(size_t)node * 256 + sel * 128 + col] =
                        pack_bf2(aS[mt][reg] * L2E, aG[mt][reg] * L2E);
            }
        }
    }
}

// ===== sort machinery =====
__global__ void __launch_bounds__(256) hist_k(const int* __restrict__ pidx,
                                              unsigned* __restrict__ cnt)
{
    int e = blockIdx.x * 256 + threadIdx.x;
    atomicAdd(&cnt[pidx[2 * e]], 1u);
}

__global__ void __launch_bounds__(256) scan1_k(const unsigned* __restrict__ cnt,
                                               unsigned* __restrict__ cur,
                                               unsigned* __restrict__ part)
{
    __shared__ unsigned tmp[256];
    const int t = threadIdx.x;
    const int bin = blockIdx.x * 256 + t;
    unsigned v = (bin < NN) ? cnt[bin] : 0u;
    tmp[t] = v;
    __syncthreads();
    for (int off = 1; off < 256; off <<= 1) {
        unsigned a = (t >= off) ? tmp[t - off] : 0u;
        __syncthreads();
        tmp[t] += a;
        __syncthreads();
    }
    if (bin < NN) cur[bin] = tmp[t] - v;
    if (t == 255) part[blockIdx.x] = tmp[255];
}

__global__ void __launch_bounds__(256) scan2_k(unsigned* __restrict__ part)
{
    __shared__ unsigned tmp[256];
    const int t = threadIdx.x;
    unsigned v = (t < NSCAN) ? part[t] : 0u;
    tmp[t] = v;
    __syncthreads();
    for (int off = 1; off < 256; off <<= 1) {
        unsigned a = (t >= off) ? tmp[t - off] : 0u;
        __syncthreads();
        tmp[t] += a;
        __syncthreads();
    }
    if (t < NSCAN) part[t] = tmp[t] - v;
}

__global__ void __launch_bounds__(256) scan3_k(unsigned* __restrict__ cur,
                                               const unsigned* __restrict__ part)
{
    const int bin = blockIdx.x * 256 + threadIdx.x;
    if (bin < NN) cur[bin] += part[blockIdx.x];
}

// scaled offsets packed: sdp[pos] = { src*1024, dst*1024+512 }
__global__ void __launch_bounds__(256) scatter_k(
    const int* __restrict__ pidx, unsigned* __restrict__ cur,
    int* __restrict__ sid, int2* __restrict__ sdp)
{
    int e = blockIdx.x * 256 + threadIdx.x;
    int s = pidx[2 * e], d = pidx[2 * e + 1];
    unsigned pos = atomicAdd(&cur[s], 1u);
    sid[pos] = e;
    sdp[pos] = make_int2(s << 10, (d << 10) + 512);
}

// ===== C = ef @ K_bot via MFMA (hi/lo), gather-read / linear-write; xL2E-scaled =====
__global__ void __launch_bounds__(512) edge_c_mfma(
    const float* __restrict__ ef, const float* __restrict__ Ks,
    const float* __restrict__ Kg, const int* __restrict__ sid,
    unsigned* __restrict__ C32)
{
    __shared__ short As_h[64 * 64];
    __shared__ short As_l[64 * 64];
    const int t = threadIdx.x;
    const int w = t >> 6, lane = t & 63;

    union U8 { short s[8]; bf16x8 v; };
    bf16x8 bS[2][2], bG[2][2];
    {
        const int col = w * 16 + (lane & 15);
#pragma unroll
        for (int ki = 0; ki < 2; ++ki) {
            U8 sh_, sl_, gh_, gl_;
            const int kbase = 2 * AD + ki * 32 + (lane >> 4) * 8;
#pragma unroll
            for (int j = 0; j < 8; ++j) {
                float vs = Ks[(size_t)(kbase + j) * AD + col];
                float vg = Kg[(size_t)(kbase + j) * AD + col];
                unsigned short h = bf16_rne(vs);
                sh_.s[j] = (short)h;
                sl_.s[j] = (short)bf16_rne(vs - __uint_as_float((unsigned)h << 16));
                h = bf16_rne(vg);
                gh_.s[j] = (short)h;
                gl_.s[j] = (short)bf16_rne(vg - __uint_as_float((unsigned)h << 16));
            }
            bS[ki][0] = sh_.v; bS[ki][1] = sl_.v;
            bG[ki][0] = gh_.v; bG[ki][1] = gl_.v;
        }
    }

    const int srow = t >> 4, sc4 = t & 15;
    f32x4 pf0, pf1;
    {
        int ea = sid[(size_t)blockIdx.x * 64 + srow];
        int eb = sid[(size_t)blockIdx.x * 64 + srow + 32];
        pf0 = __builtin_nontemporal_load((const f32x4*)&ef[(size_t)ea * 64 + 4 * sc4]);
        pf1 = __builtin_nontemporal_load((const f32x4*)&ef[(size_t)eb * 64 + 4 * sc4]);
    }

    for (int tile = blockIdx.x; tile < NTILES; tile += gridDim.x) {
        __syncthreads();
        {
            f32x4 v[2] = {pf0, pf1};
#pragma unroll
            for (int ii = 0; ii < 2; ++ii) {
                int row = srow + 32 * ii;
                float a0 = v[ii][0], a1 = v[ii][1], a2 = v[ii][2], a3 = v[ii][3];
                unsigned short h0 = bf16_rne(a0), h1 = bf16_rne(a1),
                               h2 = bf16_rne(a2), h3 = bf16_rne(a3);
                unsigned short l0 = bf16_rne(a0 - __uint_as_float((unsigned)h0 << 16));
                unsigned short l1 = bf16_rne(a1 - __uint_as_float((unsigned)h1 << 16));
                unsigned short l2 = bf16_rne(a2 - __uint_as_float((unsigned)h2 << 16));
                unsigned short l3 = bf16_rne(a3 - __uint_as_float((unsigned)h3 << 16));
                int sidx = (row * 64 + sc4 * 4) ^ ((row & 7) << 3);
                *(short4*)&As_h[sidx] = make_short4((short)h0, (short)h1, (short)h2, (short)h3);
                *(short4*)&As_l[sidx] = make_short4((short)l0, (short)l1, (short)l2, (short)l3);
            }
        }
        {
            int nxt = tile + gridDim.x;
            if (nxt < NTILES) {
                int ea = sid[(size_t)nxt * 64 + srow];
                int eb = sid[(size_t)nxt * 64 + srow + 32];
                pf0 = __builtin_nontemporal_load((const f32x4*)&ef[(size_t)ea * 64 + 4 * sc4]);
                pf1 = __builtin_nontemporal_load((const f32x4*)&ef[(size_t)eb * 64 + 4 * sc4]);
            }
        }
        __syncthreads();

        f32x4 accS[4] = {}, accG[4] = {};
#pragma unroll
        for (int mt = 0; mt < 4; ++mt) {
#pragma unroll
            for (int ki = 0; ki < 2; ++ki) {
                int row = mt * 16 + (lane & 15);
                int idx = (row * 64 + ki * 32 + (lane >> 4) * 8) ^ ((row & 7) << 3);
                bf16x8 ah = *(const bf16x8*)&As_h[idx];
                bf16x8 al = *(const bf16x8*)&As_l[idx];
                accS[mt] = __builtin_amdgcn_mfma_f32_16x16x32_bf16(ah, bS[ki][0], accS[mt], 0, 0, 0);
                accS[mt] = __builtin_amdgcn_mfma_f32_16x16x32_bf16(al, bS[ki][0], accS[mt], 0, 0, 0);
                accS[mt] = __builtin_amdgcn_mfma_f32_16x16x32_bf16(ah, bS[ki][1], accS[mt], 0, 0, 0);
                accG[mt] = __builtin_amdgcn_mfma_f32_16x16x32_bf16(ah, bG[ki][0], accG[mt], 0, 0, 0);
                accG[mt] = __builtin_amdgcn_mfma_f32_16x16x32_bf16(al, bG[ki][0], accG[mt], 0, 0, 0);
                accG[mt] = __builtin_amdgcn_mfma_f32_16x16x32_bf16(ah, bG[ki][1], accG[mt], 0, 0, 0);
            }
        }
        const size_t p0 = (size_t)tile * 64;
#pragma unroll
        for (int mt = 0; mt < 4; ++mt) {
#pragma unroll
            for (int reg = 0; reg < 4; ++reg) {
                int row = mt * 16 + (lane >> 4) * 4 + reg;
                unsigned val = pack_bf2(accS[mt][reg] * L2E, accG[mt][reg] * L2E);
                __builtin_nontemporal_store(val,
                    &C32[(p0 + row) * 128 + w * 16 + (lane & 15)]);
            }
        }
    }
}

// ===== sorted apply v7: 32 edges/wave, pinned depth-8 rings =====
__global__ void __launch_bounds__(256) edge_apply_sorted(
    const char* __restrict__ C8, const char* __restrict__ PQ8,
    const int2* __restrict__ sdp,
    const float* __restrict__ bs, const float* __restrict__ bg,
    float* __restrict__ acc)
{
    const int t = threadIdx.x & 63;
    const int w = threadIdx.x >> 6;
    const size_t p0 = ((size_t)blockIdx.x * 4 + w) * 32;
    const int2 sd = sdp[p0 + (t & 31)];   // lanes 0..31 hold the segment's edges
    const int srcv = sd.x, dstv = sd.y;

    const float2 bsv = *(const float2*)&bs[2 * t];
    const float2 bgv = *(const float2*)&bg[2 * t];
    const float bsA = bsv.x * L2E, bsB = bsv.y * L2E;
    const float bgA = bgv.x * L2E, bgB = bgv.y * L2E;

    const char* PQl = PQ8 + 8 * t;
    char* accl = (char*)acc + 8 * t;
    const char* Cl = C8 + p0 * 512 + 8 * t;

#define RL(v, i) __builtin_amdgcn_readlane((v), (i))
#define LOADC(i) __builtin_nontemporal_load((const u32x2*)(Cl + (i) * 512))
#define LOADQ(i) (*(const u32x2*)(PQl + RL(dstv, (i))))
#define LOADP(s_) (*(const u32x2*)(PQl + (s_)))
#define PIN __builtin_amdgcn_sched_barrier(0)

    int cur = RL(srcv, 0);
    u32x2 pv = LOADP(cur);
    float psA = unp_lo(pv.x) + bsA, pgA = unp_hi(pv.x) + bgA;
    float psB = unp_lo(pv.y) + bsB, pgB = unp_hi(pv.y) + bgB;

    u32x2 c0 = LOADC(0), c1 = LOADC(1), c2 = LOADC(2), c3 = LOADC(3),
          c4 = LOADC(4), c5 = LOADC(5), c6 = LOADC(6), c7 = LOADC(7);
    u32x2 q0 = LOADQ(0), q1 = LOADQ(1), q2 = LOADQ(2), q3 = LOADQ(3),
          q4 = LOADQ(4), q5 = LOADQ(5), q6 = LOADQ(6), q7 = LOADQ(7);
    u32x2 r0 = pv, r1 = pv, r2 = pv, r3 = pv, r4 = pv, r5 = pv, r6 = pv, r7 = pv;
    if (RL(srcv, 1) != RL(srcv, 0)) r1 = LOADP(RL(srcv, 1));
    if (RL(srcv, 2) != RL(srcv, 1)) r2 = LOADP(RL(srcv, 2));
    if (RL(srcv, 3) != RL(srcv, 2)) r3 = LOADP(RL(srcv, 3));
    if (RL(srcv, 4) != RL(srcv, 3)) r4 = LOADP(RL(srcv, 4));
    if (RL(srcv, 5) != RL(srcv, 4)) r5 = LOADP(RL(srcv, 5));
    if (RL(srcv, 6) != RL(srcv, 5)) r6 = LOADP(RL(srcv, 6));
    if (RL(srcv, 7) != RL(srcv, 6)) r7 = LOADP(RL(srcv, 7));
    PIN;   // all prologue loads issued before any compute
    float accA = 0.f, accB = 0.f;

#define FLUSH                                                              \
    atomicAdd((float*)(accl + ((unsigned)cur >> 1)),     LN2 * accA);      \
    atomicAdd((float*)(accl + ((unsigned)cur >> 1) + 4), LN2 * accB);

#define CORE(i, cc, qq, rr)                                                \
    {                                                                      \
        int src_ = RL(srcv, (i));                                          \
        if (src_ != cur) {                                                 \
            FLUSH;                                                         \
            accA = 0.f; accB = 0.f; cur = src_;                            \
            psA = unp_lo(rr.x) + bsA; pgA = unp_hi(rr.x) + bgA;            \
            psB = unp_lo(rr.y) + bsB; pgB = unp_hi(rr.y) + bgB;            \
        }                                                                  \
        float sA = unp_lo(cc.x) + unp_lo(qq.x) + psA;                      \
        float gA = unp_hi(cc.x) + unp_hi(qq.x) + pgA;                      \
        float sB = unp_lo(cc.y) + unp_lo(qq.y) + psB;                      \
        float gB = unp_hi(cc.y) + unp_hi(qq.y) + pgB;                      \
        float spA = fmaxf(gA, 0.f) + log2_f(1.f + nexp2_abs_f(gA));        \
        float spB = fmaxf(gB, 0.f) + log2_f(1.f + nexp2_abs_f(gB));       \
        accA = fmaf(__builtin_amdgcn_rcpf(1.f + nexp2_f(sA)), spA, accA);  \
        accB = fmaf(__builtin_amdgcn_rcpf(1.f + nexp2_f(sB)), spB, accB);  \
    }

// prefetch loads for i+8, then PIN so they cannot sink into later iterations
#define STEP(i, cc, qq, rr)                                                \
    {                                                                      \
        u32x2 ncc = LOADC((i) + 8);                                        \
        u32x2 nqq = LOADQ((i) + 8);                                        \
        u32x2 nrr = rr;                                                    \
        if (RL(srcv, (i) + 8) != RL(srcv, (i) + 7))                        \
            nrr = LOADP(RL(srcv, (i) + 8));                                \
        PIN;                                                               \
        CORE(i, cc, qq, rr)                                                \
        cc = ncc; qq = nqq; rr = nrr;                                      \
    }

    for (int b = 0; b < 24; b += 8) {
        STEP(b + 0, c0, q0, r0)
        STEP(b + 1, c1, q1, r1)
        STEP(b + 2, c2, q2, r2)
        STEP(b + 3, c3, q3, r3)
        STEP(b + 4, c4, q4, r4)
        STEP(b + 5, c5, q5, r5)
        STEP(b + 6, c6, q6, r6)
        STEP(b + 7, c7, q7, r7)
    }
    CORE(24, c0, q0, r0)
    CORE(25, c1, q1, r1)
    CORE(26, c2, q2, r2)
    CORE(27, c3, q3, r3)
    CORE(28, c4, q4, r4)
    CORE(29, c5, q5, r5)
    CORE(30, c6, q6, r6)
    CORE(31, c7, q7, r7)
    FLUSH;

#undef STEP
#undef CORE
#undef FLUSH
#undef PIN
#undef LOADP
#undef LOADQ
#undef LOADC
#undef RL
}

// ===== final softplus (HW exp2/log2) =====
__global__ void __launch_bounds__(256) act_k(float* __restrict__ acc)
{
    size_t i = ((size_t)blockIdx.x * 256 + threadIdx.x) * 4;
    float4 v = *(float4*)&acc[i];
    v.x = softplus_hw(v.x);
    v.y = softplus_hw(v.y);
    v.z = softplus_hw(v.z);
    v.w = softplus_hw(v.w);
    *(float4*)&acc[i] = v;
}

// ===== Tier B fallback (round-1, known good) =====
__global__ void __launch_bounds__(128) node_mm_f32(
    const float* __restrict__ x, const float* __restrict__ Ks,
    const float* __restrict__ Kg, float* __restrict__ PQ)
{
    __shared__ float xs[8][AD];
    const int t = threadIdx.x;
    const int row0 = blockIdx.x * 8;
#pragma unroll
    for (int r = 0; r < 8; ++r) xs[r][t] = x[(size_t)(row0 + r) * AD + t];
    __syncthreads();
    float aPs[8] = {}, aQs[8] = {}, aPg[8] = {}, aQg[8] = {};
    for (int k = 0; k < AD; ++k) {
        float ks_s = Ks[k * AD + t];
        float ks_d = Ks[(AD + k) * AD + t];
        float kg_s = Kg[k * AD + t];
        float kg_d = Kg[(AD + k) * AD + t];
#pragma unroll
        for (int r = 0; r < 8; ++r) {
            float xv = xs[r][k];
            aPs[r] = fmaf(xv, ks_s, aPs[r]);
            aQs[r] = fmaf(xv, ks_d, aQs[r]);
            aPg[r] = fmaf(xv, kg_s, aPg[r]);
            aQg[r] = fmaf(xv, kg_d, aQg[r]);
        }
    }
#pragma unroll
    for (int r = 0; r < 8; ++r) {
        float* o = PQ + (size_t)(row0 + r) * 512;
        *(float2*)&o[2 * t]       = make_float2(aPs[r], aPg[r]);
        *(float2*)&o[256 + 2 * t] = make_float2(aQs[r], aQg[r]);
    }
}

__global__ void __launch_bounds__(256) edge_fused(
    const float* __restrict__ ef, const float* __restrict__ Ks,
    const float* __restrict__ Kg, const float* __restrict__ PQ,
    const int* __restrict__ pidx, const float* __restrict__ bs,
    const float* __restrict__ bg, float* __restrict__ acc)
{
    __shared__ float KB[ED][2 * AD];
    __shared__ float es[64][ED];
    const int t = threadIdx.x;
    for (int i = t; i < ED * AD; i += 256) {
        int k = i >> 7, n = i & 127;
        KB[k][2 * n]     = Ks[(2 * AD + k) * AD + n];
        KB[k][2 * n + 1] = Kg[(2 * AD + k) * AD + n];
    }
    const size_t e0 = (size_t)blockIdx.x * 64;
    for (int i = t; i < 64 * ED; i += 256) ((float*)es)[i] = ef[e0 * ED + i];
    __syncthreads();
    const int le = t >> 7, n = t & 127;
    const float bsn = bs[n], bgn = bg[n];
    for (int base = le * 8; base < 64; base += 16) {
        float accS[8] = {}, accG[8] = {};
        for (int k4 = 0; k4 < ED / 4; ++k4) {
            float2 kv0 = *(const float2*)&KB[4 * k4 + 0][2 * n];
            float2 kv1 = *(const float2*)&KB[4 * k4 + 1][2 * n];
            float2 kv2 = *(const float2*)&KB[4 * k4 + 2][2 * n];
            float2 kv3 = *(const float2*)&KB[4 * k4 + 3][2 * n];
#pragma unroll
            for (int r = 0; r < 8; ++r) {
                float4 ev = *(const float4*)&es[base + r][4 * k4];
                accS[r] = fmaf(ev.x, kv0.x, accS[r]);
                accG[r] = fmaf(ev.x, kv0.y, accG[r]);
                accS[r] = fmaf(ev.y, kv1.x, accS[r]);
                accG[r] = fmaf(ev.y, kv1.y, accG[r]);
                accS[r] = fmaf(ev.z, kv2.x, accS[r]);
                accG[r] = fmaf(ev.z, kv2.y, accG[r]);
                accS[r] = fmaf(ev.w, kv3.x, accS[r]);
                accG[r] = fmaf(ev.w, kv3.y, accG[r]);
            }
        }
#pragma unroll
        for (int r = 0; r < 8; ++r) {
            size_t e = e0 + base + r;
            int src = pidx[2 * e], dst = pidx[2 * e + 1];
            float2 pv = *(const float2*)&PQ[(size_t)src * 512 + 2 * n];
            float2 qv = *(const float2*)&PQ[(size_t)dst * 512 + 256 + 2 * n];
            float s = accS[r] + pv.x + qv.x + bsn;
            float g = accG[r] + pv.y + qv.y + bgn;
            atomicAdd(&acc[(size_t)src * AD + n], sigmoid_fast(s) * softplus_f(g));
        }
    }
}

// ===== launch =====
extern "C" void kernel_launch(void* const* d_in, const int* in_sizes, int n_in,
                              void* d_out, int out_size, void* d_ws, size_t ws_size,
                              hipStream_t stream)
{
    const float* atom = (const float*)d_in[0];
    const float* ef   = (const float*)d_in[1];
    const float* Ks   = (const float*)d_in[3];
    const float* bs   = (const float*)d_in[4];
    const float* Kg   = (const float*)d_in[5];
    const float* bg   = (const float*)d_in[6];
    const int*   pidx = (const int*)d_in[7];

    float* acc = (float*)d_out;

    char* w = (char*)d_ws;
    const size_t PQ_B   = (size_t)NN * 256 * 4;   //  51.2 MB
    const size_t C_B    = (size_t)NE * 128 * 4;   // 409.6 MB
    const size_t BN_B   = 16384 * 16;             // 256 KB
    const size_t CNT_B  = (size_t)NN * 4;
    const size_t IDX_B  = (size_t)NE * 4;
    const size_t PART_B = 256 * 4;
    unsigned* PQ32 = (unsigned*)w;  w += PQ_B;
    unsigned* C32  = (unsigned*)w;  w += C_B;
    bf16x8*   Bn   = (bf16x8*)w;    w += BN_B;
    unsigned* cnt  = (unsigned*)w;  w += CNT_B;
    unsigned* curp = (unsigned*)w;  w += CNT_B;
    int*      sid  = (int*)w;       w += IDX_B;
    int2*     sdp  = (int2*)w;      w += 2 * IDX_B;
    unsigned* part = (unsigned*)w;  w += PART_B;
    const size_t TOTAL_A = PQ_B + C_B + BN_B + 2 * CNT_B + 3 * IDX_B + PART_B;

    if (ws_size >= TOTAL_A) {
        hipMemsetAsync(cnt, 0, CNT_B, stream);
        bn_prep<<<64, 256, 0, stream>>>(Ks, Kg, Bn);
        hist_k<<<NE / 256, 256, 0, stream>>>(pidx, cnt);
        scan1_k<<<NSCAN, 256, 0, stream>>>(cnt, curp, part);
        scan2_k<<<1, 256, 0, stream>>>(part);
        scan3_k<<<NSCAN, 256, 0, stream>>>(curp, part);
        scatter_k<<<NE / 256, 256, 0, stream>>>(pidx, curp, sid, sdp);
        edge_c_mfma<<<2048, 512, 0, stream>>>(ef, Ks, Kg, sid, C32);

        for (int s = 0; s < NSTEPS; ++s) {
            node_mm_mfma<<<NROWB, 512, 0, stream>>>(atom, acc, Bn, PQ32,
                                                    s == 0 ? 0 : 1);
            edge_apply_sorted<<<NE / 128, 256, 0, stream>>>(
                (const char*)C32, (const char*)PQ32, sdp, bs, bg, acc);
        }
        act_k<<<(NN * AD) / 1024, 256, 0, stream>>>(acc);
    } else {
        float* PQ = (float*)d_ws;
        hipMemcpyAsync(acc, atom, (size_t)NN * AD * sizeof(float),
                       hipMemcpyDeviceToDevice, stream);
        for (int s = 0; s < NSTEPS; ++s) {
            node_mm_f32<<<NN / 8, 128, 0, stream>>>(acc, Ks, Kg, PQ);
            edge_fused<<<NE / 64, 256, 0, stream>>>(ef, Ks, Kg, PQ, pidx, bs, bg, acc);
            act_k<<<(NN * AD) / 1024, 256, 0, stream>>>(acc);
        }
    }
}

// Round 13
// 666.522 us; speedup vs baseline: 1.2201x; 1.1376x over previous
//
#include <hip/hip_runtime.h>
#include <hip/hip_bf16.h>
#include <math.h>

// CrystalGraphConvolution — MI355X round 13
// vs r12: C stored as OCP fp8-e4m3 (s,g) pairs — 256B/edge (was 512B bf16).
// Halves apply's HBM fetch (410->205 MB/step) and edge_c's write (437->219).
// Error analysis: C|<=3, e4m3 err <=0.03 abs — negligible vs existing +-6
// bf16 P/Q rounding at magnitude ~2k. Encode v_cvt_pk_fp8_f32 (RNE), decode
// v_cvt_pk_f32_fp8 (same HW format both ways). Everything else = r12.

#define NN 50000
#define NE 800000
#define AD 128
#define ED 64
#define NSTEPS 3
#define NTILES (NE / 64)          // 12500
#define NSCAN  ((NN + 255) / 256) // 196
#define NROWB  ((NN + 63) / 64)   // 782

#define L2E 1.4426950408889634f
#define LN2 0.6931471805599453f

typedef __attribute__((ext_vector_type(8))) __bf16 bf16x8;
typedef __attribute__((ext_vector_type(4))) float  f32x4;
typedef __attribute__((ext_vector_type(2))) float  f32x2;
typedef __attribute__((ext_vector_type(2))) unsigned u32x2;

__device__ __forceinline__ float softplus_f(float x) {      // Tier B only
    return fmaxf(x, 0.f) + log1pf(__expf(-fabsf(x)));
}
__device__ __forceinline__ float sigmoid_fast(float x) {    // Tier B
    float e = __expf(-fabsf(x));
    float r = __builtin_amdgcn_rcpf(1.f + e);
    return (x >= 0.f) ? r : 1.f - r;
}
__device__ __forceinline__ unsigned short bf16_rne(float f) {
    unsigned u = __float_as_uint(f);
    unsigned r = u + 0x7fffu + ((u >> 16) & 1u);
    return (unsigned short)(r >> 16);
}
__device__ __forceinline__ unsigned pack_bf2(float s, float g) {
    return (unsigned)bf16_rne(s) | ((unsigned)bf16_rne(g) << 16);
}
__device__ __forceinline__ float unp_lo(unsigned v) { return __uint_as_float(v << 16); }
__device__ __forceinline__ float unp_hi(unsigned v) { return __uint_as_float(v & 0xffff0000u); }

__device__ __forceinline__ float nexp2_f(float x) {         // 2^(-x)
    float r; asm("v_exp_f32 %0, -%1" : "=v"(r) : "v"(x)); return r;
}
__device__ __forceinline__ float nexp2_abs_f(float x) {     // 2^(-|x|)
    float r; asm("v_exp_f32 %0, -abs(%1)" : "=v"(r) : "v"(x)); return r;
}
__device__ __forceinline__ float log2_f(float x) {
    float r; asm("v_log_f32 %0, %1" : "=v"(r) : "v"(x)); return r;
}
// HW softplus: ln2 * (max(y,0) + log2(1 + 2^-|y|)), y = x*log2e. rel err ~1e-6.
__device__ __forceinline__ float softplus_hw(float x) {
    float y = x * L2E;
    return LN2 * (fmaxf(y, 0.f) + log2_f(1.f + nexp2_abs_f(y)));
}
// fp8 e4m3 pack/unpack (gfx950 OCP; round-trips through same HW format)
__device__ __forceinline__ unsigned short pack_fp8_pair(float s, float g) {
    int v = __builtin_amdgcn_cvt_pk_fp8_f32(s, g, 0, false);  // bytes 0,1
    return (unsigned short)(v & 0xffff);
}

// ===== one-time B pre-pack for node GEMM =====
__global__ void __launch_bounds__(256) bn_prep(
    const float* __restrict__ Ks, const float* __restrict__ Kg,
    bf16x8* __restrict__ Bn)
{
    union U8 { short s[8]; bf16x8 v; };
    int idx = blockIdx.x * 256 + threadIdx.x;      // 64 blocks -> 16384
    int l4  = idx & 3;
    int col = (idx >> 2) & 127;
    int ki  = (idx >> 9) & 3;
    int hl  = (idx >> 11) & 1;
    int m   = (idx >> 12) & 1;
    int sel = (idx >> 13) & 1;
    const float* K = m ? Kg : Ks;
    U8 o;
#pragma unroll
    for (int j = 0; j < 8; ++j) {
        int k = sel * 128 + ki * 32 + l4 * 8 + j;
        float v = K[(size_t)k * AD + col];
        unsigned short h = bf16_rne(v);
        o.s[j] = (hl == 0) ? (short)h
                           : (short)bf16_rne(v - __uint_as_float((unsigned)h << 16));
    }
    Bn[idx] = o.v;
}

// ===== node projections via MFMA (hi/lo), + x maintenance; outputs xL2E-scaled =====
__global__ void __launch_bounds__(512, 1) node_mm_mfma(
    const float* __restrict__ xin, float* __restrict__ acc,
    const bf16x8* __restrict__ Bn, unsigned* __restrict__ PQ32, int mode)
{
    __shared__ short As_h[64 * 128];
    __shared__ short As_l[64 * 128];
    const int t = threadIdx.x;
    const int w = t >> 6, lane = t & 63;
    const int l4 = lane >> 4;
    const int row0 = blockIdx.x * 64;

#pragma unroll
    for (int ii = 0; ii < 4; ++ii) {
        int idx = t + 512 * ii;
        int row = idx >> 5, c4 = idx & 31;
        int node = row0 + row;
        f32x4 v = {};
        if (node < NN) {
            if (mode == 0) {
                v = *(const f32x4*)&xin[(size_t)node * AD + 4 * c4];
                *(f32x4*)&acc[(size_t)node * AD + 4 * c4] = v;
            } else {
                f32x4 a = *(const f32x4*)&acc[(size_t)node * AD + 4 * c4];
                v[0] = softplus_hw(a[0]); v[1] = softplus_hw(a[1]);
                v[2] = softplus_hw(a[2]); v[3] = softplus_hw(a[3]);
                *(f32x4*)&acc[(size_t)node * AD + 4 * c4] = v;
            }
        }
        unsigned short h0 = bf16_rne(v[0]), h1 = bf16_rne(v[1]),
                       h2 = bf16_rne(v[2]), h3 = bf16_rne(v[3]);
        unsigned short l0 = bf16_rne(v[0] - __uint_as_float((unsigned)h0 << 16));
        unsigned short l1 = bf16_rne(v[1] - __uint_as_float((unsigned)h1 << 16));
        unsigned short l2 = bf16_rne(v[2] - __uint_as_float((unsigned)h2 << 16));
        unsigned short l3 = bf16_rne(v[3] - __uint_as_float((unsigned)h3 << 16));
        int sidx = (row * 128 + c4 * 4) ^ ((row & 7) << 3);
        *(short4*)&As_h[sidx] = make_short4((short)h0, (short)h1, (short)h2, (short)h3);
        *(short4*)&As_l[sidx] = make_short4((short)l0, (short)l1, (short)l2, (short)l3);
    }
    __syncthreads();

    const int col = w * 16 + (lane & 15);
#pragma unroll
    for (int sel = 0; sel < 2; ++sel) {
        bf16x8 bS[4][2], bG[4][2];
#pragma unroll
        for (int ki = 0; ki < 4; ++ki) {
#pragma unroll
            for (int hl = 0; hl < 2; ++hl) {
                bS[ki][hl] = Bn[(((sel * 2 + 0) * 2 + hl) * 4 + ki) * 512 + col * 4 + l4];
                bG[ki][hl] = Bn[(((sel * 2 + 1) * 2 + hl) * 4 + ki) * 512 + col * 4 + l4];
            }
        }
        f32x4 aS[4] = {}, aG[4] = {};
#pragma unroll
        for (int mt = 0; mt < 4; ++mt) {
            int row = mt * 16 + (lane & 15);
#pragma unroll
            for (int ki = 0; ki < 4; ++ki) {
                int idx = (row * 128 + ki * 32 + l4 * 8) ^ ((row & 7) << 3);
                bf16x8 ah = *(const bf16x8*)&As_h[idx];
                bf16x8 al = *(const bf16x8*)&As_l[idx];
                aS[mt] = __builtin_amdgcn_mfma_f32_16x16x32_bf16(ah, bS[ki][0], aS[mt], 0, 0, 0);
                aS[mt] = __builtin_amdgcn_mfma_f32_16x16x32_bf16(al, bS[ki][0], aS[mt], 0, 0, 0);
                aS[mt] = __builtin_amdgcn_mfma_f32_16x16x32_bf16(ah, bS[ki][1], aS[mt], 0, 0, 0);
                aG[mt] = __builtin_amdgcn_mfma_f32_16x16x32_bf16(ah, bG[ki][0], aG[mt], 0, 0, 0);
                aG[mt] = __builtin_amdgcn_mfma_f32_16x16x32_bf16(al, bG[ki][0], aG[mt], 0, 0, 0);
                aG[mt] = __builtin_amdgcn_mfma_f32_16x16x32_bf16(ah, bG[ki][1], aG[mt], 0, 0, 0);
            }
        }
#pragma unroll
        for (int mt = 0; mt < 4; ++mt) {
#pragma unroll
            for (int reg = 0; reg < 4; ++reg) {
                int node = row0 + mt * 16 + l4 * 4 + reg;
                if (node < NN)
                    PQ32[(size_t)node * 256 + sel * 128 + col] =
                        pack_bf2(aS[mt][reg] * L2E, aG[mt][reg] * L2E);
            }
        }
    }
}

// ===== sort machinery =====
__global__ void __launch_bounds__(256) hist_k(const int* __restrict__ pidx,
                                              unsigned* __restrict__ cnt)
{
    int e = blockIdx.x * 256 + threadIdx.x;
    atomicAdd(&cnt[pidx[2 * e]], 1u);
}

__global__ void __launch_bounds__(256) scan1_k(const unsigned* __restrict__ cnt,
                                               unsigned* __restrict__ cur,
                                               unsigned* __restrict__ part)
{
    __shared__ unsigned tmp[256];
    const int t = threadIdx.x;
    const int bin = blockIdx.x * 256 + t;
    unsigned v = (bin < NN) ? cnt[bin] : 0u;
    tmp[t] = v;
    __syncthreads();
    for (int off = 1; off < 256; off <<= 1) {
        unsigned a = (t >= off) ? tmp[t - off] : 0u;
        __syncthreads();
        tmp[t] += a;
        __syncthreads();
    }
    if (bin < NN) cur[bin] = tmp[t] - v;
    if (t == 255) part[blockIdx.x] = tmp[255];
}

__global__ void __launch_bounds__(256) scan2_k(unsigned* __restrict__ part)
{
    __shared__ unsigned tmp[256];
    const int t = threadIdx.x;
    unsigned v = (t < NSCAN) ? part[t] : 0u;
    tmp[t] = v;
    __syncthreads();
    for (int off = 1; off < 256; off <<= 1) {
        unsigned a = (t >= off) ? tmp[t - off] : 0u;
        __syncthreads();
        tmp[t] += a;
        __syncthreads();
    }
    if (t < NSCAN) part[t] = tmp[t] - v;
}

__global__ void __launch_bounds__(256) scan3_k(unsigned* __restrict__ cur,
                                               const unsigned* __restrict__ part)
{
    const int bin = blockIdx.x * 256 + threadIdx.x;
    if (bin < NN) cur[bin] += part[blockIdx.x];
}

// scaled offsets packed: sdp[pos] = { src*1024, dst*1024+512 }
__global__ void __launch_bounds__(256) scatter_k(
    const int* __restrict__ pidx, unsigned* __restrict__ cur,
    int* __restrict__ sid, int2* __restrict__ sdp)
{
    int e = blockIdx.x * 256 + threadIdx.x;
    int s = pidx[2 * e], d = pidx[2 * e + 1];
    unsigned pos = atomicAdd(&cur[s], 1u);
    sid[pos] = e;
    sdp[pos] = make_int2(s << 10, (d << 10) + 512);
}

// ===== C = ef @ K_bot via MFMA (hi/lo); fp8 (s,g) output, xL2E-scaled =====
__global__ void __launch_bounds__(512) edge_c_mfma(
    const float* __restrict__ ef, const float* __restrict__ Ks,
    const float* __restrict__ Kg, const int* __restrict__ sid,
    unsigned short* __restrict__ C16)
{
    __shared__ short As_h[64 * 64];
    __shared__ short As_l[64 * 64];
    const int t = threadIdx.x;
    const int w = t >> 6, lane = t & 63;

    union U8 { short s[8]; bf16x8 v; };
    bf16x8 bS[2][2], bG[2][2];
    {
        const int col = w * 16 + (lane & 15);
#pragma unroll
        for (int ki = 0; ki < 2; ++ki) {
            U8 sh_, sl_, gh_, gl_;
            const int kbase = 2 * AD + ki * 32 + (lane >> 4) * 8;
#pragma unroll
            for (int j = 0; j < 8; ++j) {
                float vs = Ks[(size_t)(kbase + j) * AD + col];
                float vg = Kg[(size_t)(kbase + j) * AD + col];
                unsigned short h = bf16_rne(vs);
                sh_.s[j] = (short)h;
                sl_.s[j] = (short)bf16_rne(vs - __uint_as_float((unsigned)h << 16));
                h = bf16_rne(vg);
                gh_.s[j] = (short)h;
                gl_.s[j] = (short)bf16_rne(vg - __uint_as_float((unsigned)h << 16));
            }
            bS[ki][0] = sh_.v; bS[ki][1] = sl_.v;
            bG[ki][0] = gh_.v; bG[ki][1] = gl_.v;
        }
    }

    const int srow = t >> 4, sc4 = t & 15;
    f32x4 pf0, pf1;
    {
        int ea = sid[(size_t)blockIdx.x * 64 + srow];
        int eb = sid[(size_t)blockIdx.x * 64 + srow + 32];
        pf0 = __builtin_nontemporal_load((const f32x4*)&ef[(size_t)ea * 64 + 4 * sc4]);
        pf1 = __builtin_nontemporal_load((const f32x4*)&ef[(size_t)eb * 64 + 4 * sc4]);
    }

    for (int tile = blockIdx.x; tile < NTILES; tile += gridDim.x) {
        __syncthreads();
        {
            f32x4 v[2] = {pf0, pf1};
#pragma unroll
            for (int ii = 0; ii < 2; ++ii) {
                int row = srow + 32 * ii;
                float a0 = v[ii][0], a1 = v[ii][1], a2 = v[ii][2], a3 = v[ii][3];
                unsigned short h0 = bf16_rne(a0), h1 = bf16_rne(a1),
                               h2 = bf16_rne(a2), h3 = bf16_rne(a3);
                unsigned short l0 = bf16_rne(a0 - __uint_as_float((unsigned)h0 << 16));
                unsigned short l1 = bf16_rne(a1 - __uint_as_float((unsigned)h1 << 16));
                unsigned short l2 = bf16_rne(a2 - __uint_as_float((unsigned)h2 << 16));
                unsigned short l3 = bf16_rne(a3 - __uint_as_float((unsigned)h3 << 16));
                int sidx = (row * 64 + sc4 * 4) ^ ((row & 7) << 3);
                *(short4*)&As_h[sidx] = make_short4((short)h0, (short)h1, (short)h2, (short)h3);
                *(short4*)&As_l[sidx] = make_short4((short)l0, (short)l1, (short)l2, (short)l3);
            }
        }
        {
            int nxt = tile + gridDim.x;
            if (nxt < NTILES) {
                int ea = sid[(size_t)nxt * 64 + srow];
                int eb = sid[(size_t)nxt * 64 + srow + 32];
                pf0 = __builtin_nontemporal_load((const f32x4*)&ef[(size_t)ea * 64 + 4 * sc4]);
                pf1 = __builtin_nontemporal_load((const f32x4*)&ef[(size_t)eb * 64 + 4 * sc4]);
            }
        }
        __syncthreads();

        f32x4 accS[4] = {}, accG[4] = {};
#pragma unroll
        for (int mt = 0; mt < 4; ++mt) {
#pragma unroll
            for (int ki = 0; ki < 2; ++ki) {
                int row = mt * 16 + (lane & 15);
                int idx = (row * 64 + ki * 32 + (lane >> 4) * 8) ^ ((row & 7) << 3);
                bf16x8 ah = *(const bf16x8*)&As_h[idx];
                bf16x8 al = *(const bf16x8*)&As_l[idx];
                accS[mt] = __builtin_amdgcn_mfma_f32_16x16x32_bf16(ah, bS[ki][0], accS[mt], 0, 0, 0);
                accS[mt] = __builtin_amdgcn_mfma_f32_16x16x32_bf16(al, bS[ki][0], accS[mt], 0, 0, 0);
                accS[mt] = __builtin_amdgcn_mfma_f32_16x16x32_bf16(ah, bS[ki][1], accS[mt], 0, 0, 0);
                accG[mt] = __builtin_amdgcn_mfma_f32_16x16x32_bf16(ah, bG[ki][0], accG[mt], 0, 0, 0);
                accG[mt] = __builtin_amdgcn_mfma_f32_16x16x32_bf16(al, bG[ki][0], accG[mt], 0, 0, 0);
                accG[mt] = __builtin_amdgcn_mfma_f32_16x16x32_bf16(ah, bG[ki][1], accG[mt], 0, 0, 0);
            }
        }
        const size_t p0 = (size_t)tile * 64;
#pragma unroll
        for (int mt = 0; mt < 4; ++mt) {
#pragma unroll
            for (int reg = 0; reg < 4; ++reg) {
                int row = mt * 16 + (lane >> 4) * 4 + reg;
                unsigned short val =
                    pack_fp8_pair(accS[mt][reg] * L2E, accG[mt][reg] * L2E);
                __builtin_nontemporal_store(val,
                    &C16[(p0 + row) * 128 + w * 16 + (lane & 15)]);
            }
        }
    }
}

// ===== sorted apply v8: fp8 C stream, 32 edges/wave, pinned depth-8 rings =====
__global__ void __launch_bounds__(256) edge_apply_sorted(
    const char* __restrict__ C8, const char* __restrict__ PQ8,
    const int2* __restrict__ sdp,
    const float* __restrict__ bs, const float* __restrict__ bg,
    float* __restrict__ acc)
{
    const int t = threadIdx.x & 63;
    const int w = threadIdx.x >> 6;
    const size_t p0 = ((size_t)blockIdx.x * 4 + w) * 32;
    const int2 sd = sdp[p0 + (t & 31)];   // lanes 0..31 hold the segment's edges
    const int srcv = sd.x, dstv = sd.y;

    const float2 bsv = *(const float2*)&bs[2 * t];
    const float2 bgv = *(const float2*)&bg[2 * t];
    const float bsA = bsv.x * L2E, bsB = bsv.y * L2E;
    const float bgA = bgv.x * L2E, bgB = bgv.y * L2E;

    const char* PQl = PQ8 + 8 * t;
    char* accl = (char*)acc + 8 * t;
    const char* Cl = C8 + p0 * 256 + 4 * t;   // fp8 row = 256 B

#define RL(v, i) __builtin_amdgcn_readlane((v), (i))
#define LOADC(i) __builtin_nontemporal_load((const unsigned*)(Cl + (i) * 256))
#define LOADQ(i) (*(const u32x2*)(PQl + RL(dstv, (i))))
#define LOADP(s_) (*(const u32x2*)(PQl + (s_)))
#define PIN __builtin_amdgcn_sched_barrier(0)

    int cur = RL(srcv, 0);
    u32x2 pv = LOADP(cur);
    float psA = unp_lo(pv.x) + bsA, pgA = unp_hi(pv.x) + bgA;
    float psB = unp_lo(pv.y) + bsB, pgB = unp_hi(pv.y) + bgB;

    unsigned c0 = LOADC(0), c1 = LOADC(1), c2 = LOADC(2), c3 = LOADC(3),
             c4 = LOADC(4), c5 = LOADC(5), c6 = LOADC(6), c7 = LOADC(7);
    u32x2 q0 = LOADQ(0), q1 = LOADQ(1), q2 = LOADQ(2), q3 = LOADQ(3),
          q4 = LOADQ(4), q5 = LOADQ(5), q6 = LOADQ(6), q7 = LOADQ(7);
    u32x2 r0 = pv, r1 = pv, r2 = pv, r3 = pv, r4 = pv, r5 = pv, r6 = pv, r7 = pv;
    if (RL(srcv, 1) != RL(srcv, 0)) r1 = LOADP(RL(srcv, 1));
    if (RL(srcv, 2) != RL(srcv, 1)) r2 = LOADP(RL(srcv, 2));
    if (RL(srcv, 3) != RL(srcv, 2)) r3 = LOADP(RL(srcv, 3));
    if (RL(srcv, 4) != RL(srcv, 3)) r4 = LOADP(RL(srcv, 4));
    if (RL(srcv, 5) != RL(srcv, 4)) r5 = LOADP(RL(srcv, 5));
    if (RL(srcv, 6) != RL(srcv, 5)) r6 = LOADP(RL(srcv, 6));
    if (RL(srcv, 7) != RL(srcv, 6)) r7 = LOADP(RL(srcv, 7));
    PIN;   // all prologue loads issued before any compute
    float accA = 0.f, accB = 0.f;

#define FLUSH                                                              \
    atomicAdd((float*)(accl + ((unsigned)cur >> 1)),     LN2 * accA);      \
    atomicAdd((float*)(accl + ((unsigned)cur >> 1) + 4), LN2 * accB);

#define CORE(i, cc, qq, rr)                                                \
    {                                                                      \
        int src_ = RL(srcv, (i));                                          \
        if (src_ != cur) {                                                 \
            FLUSH;                                                         \
            accA = 0.f; accB = 0.f; cur = src_;                            \
            psA = unp_lo(rr.x) + bsA; pgA = unp_hi(rr.x) + bgA;            \
            psB = unp_lo(rr.y) + bsB; pgB = unp_hi(rr.y) + bgB;            \
        }                                                                  \
        f32x2 sgA = __builtin_amdgcn_cvt_pk_f32_fp8((int)cc, false);       \
        f32x2 sgB = __builtin_amdgcn_cvt_pk_f32_fp8((int)cc, true);        \
        float sA = sgA[0] + unp_lo(qq.x) + psA;                            \
        float gA = sgA[1] + unp_hi(qq.x) + pgA;                            \
        float sB = sgB[0] + unp_lo(qq.y) + psB;                            \
        float gB = sgB[1] + unp_hi(qq.y) + pgB;                            \
        float spA = fmaxf(gA, 0.f) + log2_f(1.f + nexp2_abs_f(gA));        \
        float spB = fmaxf(gB, 0.f) + log2_f(1.f + nexp2_abs_f(gB));       \
        accA = fmaf(__builtin_amdgcn_rcpf(1.f + nexp2_f(sA)), spA, accA);  \
        accB = fmaf(__builtin_amdgcn_rcpf(1.f + nexp2_f(sB)), spB, accB);  \
    }

// prefetch loads for i+8, then PIN so they cannot sink into later iterations
#define STEP(i, cc, qq, rr)                                                \
    {                                                                      \
        unsigned ncc = LOADC((i) + 8);                                     \
        u32x2 nqq = LOADQ((i) + 8);                                        \
        u32x2 nrr = rr;                                                    \
        if (RL(srcv, (i) + 8) != RL(srcv, (i) + 7))                        \
            nrr = LOADP(RL(srcv, (i) + 8));                                \
        PIN;                                                               \
        CORE(i, cc, qq, rr)                                                \
        cc = ncc; qq = nqq; rr = nrr;                                      \
    }

    for (int b = 0; b < 24; b += 8) {
        STEP(b + 0, c0, q0, r0)
        STEP(b + 1, c1, q1, r1)
        STEP(b + 2, c2, q2, r2)
        STEP(b + 3, c3, q3, r3)
        STEP(b + 4, c4, q4, r4)
        STEP(b + 5, c5, q5, r5)
        STEP(b + 6, c6, q6, r6)
        STEP(b + 7, c7, q7, r7)
    }
    CORE(24, c0, q0, r0)
    CORE(25, c1, q1, r1)
    CORE(26, c2, q2, r2)
    CORE(27, c3, q3, r3)
    CORE(28, c4, q4, r4)
    CORE(29, c5, q5, r5)
    CORE(30, c6, q6, r6)
    CORE(31, c7, q7, r7)
    FLUSH;

#undef STEP
#undef CORE
#undef FLUSH
#undef PIN
#undef LOADP
#undef LOADQ
#undef LOADC
#undef RL
}

// ===== final softplus (HW exp2/log2) =====
__global__ void __launch_bounds__(256) act_k(float* __restrict__ acc)
{
    size_t i = ((size_t)blockIdx.x * 256 + threadIdx.x) * 4;
    float4 v = *(float4*)&acc[i];
    v.x = softplus_hw(v.x);
    v.y = softplus_hw(v.y);
    v.z = softplus_hw(v.z);
    v.w = softplus_hw(v.w);
    *(float4*)&acc[i] = v;
}

// ===== Tier B fallback (round-1, known good) =====
__global__ void __launch_bounds__(128) node_mm_f32(
    const float* __restrict__ x, const float* __restrict__ Ks,
    const float* __restrict__ Kg, float* __restrict__ PQ)
{
    __shared__ float xs[8][AD];
    const int t = threadIdx.x;
    const int row0 = blockIdx.x * 8;
#pragma unroll
    for (int r = 0; r < 8; ++r) xs[r][t] = x[(size_t)(row0 + r) * AD + t];
    __syncthreads();
    float aPs[8] = {}, aQs[8] = {}, aPg[8] = {}, aQg[8] = {};
    for (int k = 0; k < AD; ++k) {
        float ks_s = Ks[k * AD + t];
        float ks_d = Ks[(AD + k) * AD + t];
        float kg_s = Kg[k * AD + t];
        float kg_d = Kg[(AD + k) * AD + t];
#pragma unroll
        for (int r = 0; r < 8; ++r) {
            float xv = xs[r][k];
            aPs[r] = fmaf(xv, ks_s, aPs[r]);
            aQs[r] = fmaf(xv, ks_d, aQs[r]);
            aPg[r] = fmaf(xv, kg_s, aPg[r]);
            aQg[r] = fmaf(xv, kg_d, aQg[r]);
        }
    }
#pragma unroll
    for (int r = 0; r < 8; ++r) {
        float* o = PQ + (size_t)(row0 + r) * 512;
        *(float2*)&o[2 * t]       = make_float2(aPs[r], aPg[r]);
        *(float2*)&o[256 + 2 * t] = make_float2(aQs[r], aQg[r]);
    }
}

__global__ void __launch_bounds__(256) edge_fused(
    const float* __restrict__ ef, const float* __restrict__ Ks,
    const float* __restrict__ Kg, const float* __restrict__ PQ,
    const int* __restrict__ pidx, const float* __restrict__ bs,
    const float* __restrict__ bg, float* __restrict__ acc)
{
    __shared__ float KB[ED][2 * AD];
    __shared__ float es[64][ED];
    const int t = threadIdx.x;
    for (int i = t; i < ED * AD; i += 256) {
        int k = i >> 7, n = i & 127;
        KB[k][2 * n]     = Ks[(2 * AD + k) * AD + n];
        KB[k][2 * n + 1] = Kg[(2 * AD + k) * AD + n];
    }
    const size_t e0 = (size_t)blockIdx.x * 64;
    for (int i = t; i < 64 * ED; i += 256) ((float*)es)[i] = ef[e0 * ED + i];
    __syncthreads();
    const int le = t >> 7, n = t & 127;
    const float bsn = bs[n], bgn = bg[n];
    for (int base = le * 8; base < 64; base += 16) {
        float accS[8] = {}, accG[8] = {};
        for (int k4 = 0; k4 < ED / 4; ++k4) {
            float2 kv0 = *(const float2*)&KB[4 * k4 + 0][2 * n];
            float2 kv1 = *(const float2*)&KB[4 * k4 + 1][2 * n];
            float2 kv2 = *(const float2*)&KB[4 * k4 + 2][2 * n];
            float2 kv3 = *(const float2*)&KB[4 * k4 + 3][2 * n];
#pragma unroll
            for (int r = 0; r < 8; ++r) {
                float4 ev = *(const float4*)&es[base + r][4 * k4];
                accS[r] = fmaf(ev.x, kv0.x, accS[r]);
                accG[r] = fmaf(ev.x, kv0.y, accG[r]);
                accS[r] = fmaf(ev.y, kv1.x, accS[r]);
                accG[r] = fmaf(ev.y, kv1.y, accG[r]);
                accS[r] = fmaf(ev.z, kv2.x, accS[r]);
                accG[r] = fmaf(ev.z, kv2.y, accG[r]);
                accS[r] = fmaf(ev.w, kv3.x, accS[r]);
                accG[r] = fmaf(ev.w, kv3.y, accG[r]);
            }
        }
#pragma unroll
        for (int r = 0; r < 8; ++r) {
            size_t e = e0 + base + r;
            int src = pidx[2 * e], dst = pidx[2 * e + 1];
            float2 pv = *(const float2*)&PQ[(size_t)src * 512 + 2 * n];
            float2 qv = *(const float2*)&PQ[(size_t)dst * 512 + 256 + 2 * n];
            float s = accS[r] + pv.x + qv.x + bsn;
            float g = accG[r] + pv.y + qv.y + bgn;
            atomicAdd(&acc[(size_t)src * AD + n], sigmoid_fast(s) * softplus_f(g));
        }
    }
}

// ===== launch =====
extern "C" void kernel_launch(void* const* d_in, const int* in_sizes, int n_in,
                              void* d_out, int out_size, void* d_ws, size_t ws_size,
                              hipStream_t stream)
{
    const float* atom = (const float*)d_in[0];
    const float* ef   = (const float*)d_in[1];
    const float* Ks   = (const float*)d_in[3];
    const float* bs   = (const float*)d_in[4];
    const float* Kg   = (const float*)d_in[5];
    const float* bg   = (const float*)d_in[6];
    const int*   pidx = (const int*)d_in[7];

    float* acc = (float*)d_out;

    char* w = (char*)d_ws;
    const size_t PQ_B   = (size_t)NN * 256 * 4;   //  51.2 MB
    const size_t C_B    = (size_t)NE * 128 * 2;   // 204.8 MB (fp8 pairs)
    const size_t BN_B   = 16384 * 16;             // 256 KB
    const size_t CNT_B  = (size_t)NN * 4;
    const size_t IDX_B  = (size_t)NE * 4;
    const size_t PART_B = 256 * 4;
    unsigned* PQ32      = (unsigned*)w;       w += PQ_B;
    unsigned short* C16 = (unsigned short*)w; w += C_B;
    bf16x8*   Bn   = (bf16x8*)w;    w += BN_B;
    unsigned* cnt  = (unsigned*)w;  w += CNT_B;
    unsigned* curp = (unsigned*)w;  w += CNT_B;
    int*      sid  = (int*)w;       w += IDX_B;
    int2*     sdp  = (int2*)w;      w += 2 * IDX_B;
    unsigned* part = (unsigned*)w;  w += PART_B;
    const size_t TOTAL_A = PQ_B + C_B + BN_B + 2 * CNT_B + 3 * IDX_B + PART_B;

    if (ws_size >= TOTAL_A) {
        hipMemsetAsync(cnt, 0, CNT_B, stream);
        bn_prep<<<64, 256, 0, stream>>>(Ks, Kg, Bn);
        hist_k<<<NE / 256, 256, 0, stream>>>(pidx, cnt);
        scan1_k<<<NSCAN, 256, 0, stream>>>(cnt, curp, part);
        scan2_k<<<1, 256, 0, stream>>>(part);
        scan3_k<<<NSCAN, 256, 0, stream>>>(curp, part);
        scatter_k<<<NE / 256, 256, 0, stream>>>(pidx, curp, sid, sdp);
        edge_c_mfma<<<2048, 512, 0, stream>>>(ef, Ks, Kg, sid, C16);

        for (int s = 0; s < NSTEPS; ++s) {
            node_mm_mfma<<<NROWB, 512, 0, stream>>>(atom, acc, Bn, PQ32,
                                                    s == 0 ? 0 : 1);
            edge_apply_sorted<<<NE / 128, 256, 0, stream>>>(
                (const char*)C16, (const char*)PQ32, sdp, bs, bg, acc);
        }
        act_k<<<(NN * AD) / 1024, 256, 0, stream>>>(acc);
    } else {
        float* PQ = (float*)d_ws;
        hipMemcpyAsync(acc, atom, (size_t)NN * AD * sizeof(float),
                       hipMemcpyDeviceToDevice, stream);
        for (int s = 0; s < NSTEPS; ++s) {
            node_mm_f32<<<NN / 8, 128, 0, stream>>>(acc, Ks, Kg, PQ);
            edge_fused<<<NE / 64, 256, 0, stream>>>(ef, Ks, Kg, PQ, pidx, bs, bg, acc);
            act_k<<<(NN * AD) / 1024, 256, 0, stream>>>(acc);
        }
    }
}

// Round 14
// 660.418 us; speedup vs baseline: 1.2314x; 1.0092x over previous
//
#include <hip/hip_runtime.h>
#include <hip/hip_bf16.h>
#include <math.h>

// CrystalGraphConvolution — MI355X round 14
// vs r13: edge_c drops the lo-plane (bf16-hi only GEMM). Output is fp8-e4m3
// (3 mantissa bits, 3-6% rel err) so hi/lo's extra precision (0.4% -> 0.002%)
// was invisible after quantization. 48 -> 16 MFMA/tile, half the staging
// VALU, 8 KB LDS. node_mm keeps hi/lo (its bf16 P/Q output dominates error).

#define NN 50000
#define NE 800000
#define AD 128
#define ED 64
#define NSTEPS 3
#define NTILES (NE / 64)          // 12500
#define NSCAN  ((NN + 255) / 256) // 196
#define NROWB  ((NN + 63) / 64)   // 782

#define L2E 1.4426950408889634f
#define LN2 0.6931471805599453f

typedef __attribute__((ext_vector_type(8))) __bf16 bf16x8;
typedef __attribute__((ext_vector_type(4))) float  f32x4;
typedef __attribute__((ext_vector_type(2))) float  f32x2;
typedef __attribute__((ext_vector_type(2))) unsigned u32x2;

__device__ __forceinline__ float softplus_f(float x) {      // Tier B only
    return fmaxf(x, 0.f) + log1pf(__expf(-fabsf(x)));
}
__device__ __forceinline__ float sigmoid_fast(float x) {    // Tier B
    float e = __expf(-fabsf(x));
    float r = __builtin_amdgcn_rcpf(1.f + e);
    return (x >= 0.f) ? r : 1.f - r;
}
__device__ __forceinline__ unsigned short bf16_rne(float f) {
    unsigned u = __float_as_uint(f);
    unsigned r = u + 0x7fffu + ((u >> 16) & 1u);
    return (unsigned short)(r >> 16);
}
__device__ __forceinline__ unsigned pack_bf2(float s, float g) {
    return (unsigned)bf16_rne(s) | ((unsigned)bf16_rne(g) << 16);
}
__device__ __forceinline__ float unp_lo(unsigned v) { return __uint_as_float(v << 16); }
__device__ __forceinline__ float unp_hi(unsigned v) { return __uint_as_float(v & 0xffff0000u); }

__device__ __forceinline__ float nexp2_f(float x) {         // 2^(-x)
    float r; asm("v_exp_f32 %0, -%1" : "=v"(r) : "v"(x)); return r;
}
__device__ __forceinline__ float nexp2_abs_f(float x) {     // 2^(-|x|)
    float r; asm("v_exp_f32 %0, -abs(%1)" : "=v"(r) : "v"(x)); return r;
}
__device__ __forceinline__ float log2_f(float x) {
    float r; asm("v_log_f32 %0, %1" : "=v"(r) : "v"(x)); return r;
}
// HW softplus: ln2 * (max(y,0) + log2(1 + 2^-|y|)), y = x*log2e. rel err ~1e-6.
__device__ __forceinline__ float softplus_hw(float x) {
    float y = x * L2E;
    return LN2 * (fmaxf(y, 0.f) + log2_f(1.f + nexp2_abs_f(y)));
}
// fp8 e4m3 pack (gfx950 OCP; round-trips through same HW format)
__device__ __forceinline__ unsigned short pack_fp8_pair(float s, float g) {
    int v = __builtin_amdgcn_cvt_pk_fp8_f32(s, g, 0, false);  // bytes 0,1
    return (unsigned short)(v & 0xffff);
}

// ===== one-time B pre-pack for node GEMM =====
__global__ void __launch_bounds__(256) bn_prep(
    const float* __restrict__ Ks, const float* __restrict__ Kg,
    bf16x8* __restrict__ Bn)
{
    union U8 { short s[8]; bf16x8 v; };
    int idx = blockIdx.x * 256 + threadIdx.x;      // 64 blocks -> 16384
    int l4  = idx & 3;
    int col = (idx >> 2) & 127;
    int ki  = (idx >> 9) & 3;
    int hl  = (idx >> 11) & 1;
    int m   = (idx >> 12) & 1;
    int sel = (idx >> 13) & 1;
    const float* K = m ? Kg : Ks;
    U8 o;
#pragma unroll
    for (int j = 0; j < 8; ++j) {
        int k = sel * 128 + ki * 32 + l4 * 8 + j;
        float v = K[(size_t)k * AD + col];
        unsigned short h = bf16_rne(v);
        o.s[j] = (hl == 0) ? (short)h
                           : (short)bf16_rne(v - __uint_as_float((unsigned)h << 16));
    }
    Bn[idx] = o.v;
}

// ===== node projections via MFMA (hi/lo), + x maintenance; outputs xL2E-scaled =====
__global__ void __launch_bounds__(512, 1) node_mm_mfma(
    const float* __restrict__ xin, float* __restrict__ acc,
    const bf16x8* __restrict__ Bn, unsigned* __restrict__ PQ32, int mode)
{
    __shared__ short As_h[64 * 128];
    __shared__ short As_l[64 * 128];
    const int t = threadIdx.x;
    const int w = t >> 6, lane = t & 63;
    const int l4 = lane >> 4;
    const int row0 = blockIdx.x * 64;

#pragma unroll
    for (int ii = 0; ii < 4; ++ii) {
        int idx = t + 512 * ii;
        int row = idx >> 5, c4 = idx & 31;
        int node = row0 + row;
        f32x4 v = {};
        if (node < NN) {
            if (mode == 0) {
                v = *(const f32x4*)&xin[(size_t)node * AD + 4 * c4];
                *(f32x4*)&acc[(size_t)node * AD + 4 * c4] = v;
            } else {
                f32x4 a = *(const f32x4*)&acc[(size_t)node * AD + 4 * c4];
                v[0] = softplus_hw(a[0]); v[1] = softplus_hw(a[1]);
                v[2] = softplus_hw(a[2]); v[3] = softplus_hw(a[3]);
                *(f32x4*)&acc[(size_t)node * AD + 4 * c4] = v;
            }
        }
        unsigned short h0 = bf16_rne(v[0]), h1 = bf16_rne(v[1]),
                       h2 = bf16_rne(v[2]), h3 = bf16_rne(v[3]);
        unsigned short l0 = bf16_rne(v[0] - __uint_as_float((unsigned)h0 << 16));
        unsigned short l1 = bf16_rne(v[1] - __uint_as_float((unsigned)h1 << 16));
        unsigned short l2 = bf16_rne(v[2] - __uint_as_float((unsigned)h2 << 16));
        unsigned short l3 = bf16_rne(v[3] - __uint_as_float((unsigned)h3 << 16));
        int sidx = (row * 128 + c4 * 4) ^ ((row & 7) << 3);
        *(short4*)&As_h[sidx] = make_short4((short)h0, (short)h1, (short)h2, (short)h3);
        *(short4*)&As_l[sidx] = make_short4((short)l0, (short)l1, (short)l2, (short)l3);
    }
    __syncthreads();

    const int col = w * 16 + (lane & 15);
#pragma unroll
    for (int sel = 0; sel < 2; ++sel) {
        bf16x8 bS[4][2], bG[4][2];
#pragma unroll
        for (int ki = 0; ki < 4; ++ki) {
#pragma unroll
            for (int hl = 0; hl < 2; ++hl) {
                bS[ki][hl] = Bn[(((sel * 2 + 0) * 2 + hl) * 4 + ki) * 512 + col * 4 + l4];
                bG[ki][hl] = Bn[(((sel * 2 + 1) * 2 + hl) * 4 + ki) * 512 + col * 4 + l4];
            }
        }
        f32x4 aS[4] = {}, aG[4] = {};
#pragma unroll
        for (int mt = 0; mt < 4; ++mt) {
            int row = mt * 16 + (lane & 15);
#pragma unroll
            for (int ki = 0; ki < 4; ++ki) {
                int idx = (row * 128 + ki * 32 + l4 * 8) ^ ((row & 7) << 3);
                bf16x8 ah = *(const bf16x8*)&As_h[idx];
                bf16x8 al = *(const bf16x8*)&As_l[idx];
                aS[mt] = __builtin_amdgcn_mfma_f32_16x16x32_bf16(ah, bS[ki][0], aS[mt], 0, 0, 0);
                aS[mt] = __builtin_amdgcn_mfma_f32_16x16x32_bf16(al, bS[ki][0], aS[mt], 0, 0, 0);
                aS[mt] = __builtin_amdgcn_mfma_f32_16x16x32_bf16(ah, bS[ki][1], aS[mt], 0, 0, 0);
                aG[mt] = __builtin_amdgcn_mfma_f32_16x16x32_bf16(ah, bG[ki][0], aG[mt], 0, 0, 0);
                aG[mt] = __builtin_amdgcn_mfma_f32_16x16x32_bf16(al, bG[ki][0], aG[mt], 0, 0, 0);
                aG[mt] = __builtin_amdgcn_mfma_f32_16x16x32_bf16(ah, bG[ki][1], aG[mt], 0, 0, 0);
            }
        }
#pragma unroll
        for (int mt = 0; mt < 4; ++mt) {
#pragma unroll
            for (int reg = 0; reg < 4; ++reg) {
                int node = row0 + mt * 16 + l4 * 4 + reg;
                if (node < NN)
                    PQ32[(size_t)node * 256 + sel * 128 + col] =
                        pack_bf2(aS[mt][reg] * L2E, aG[mt][reg] * L2E);
            }
        }
    }
}

// ===== sort machinery =====
__global__ void __launch_bounds__(256) hist_k(const int* __restrict__ pidx,
                                              unsigned* __restrict__ cnt)
{
    int e = blockIdx.x * 256 + threadIdx.x;
    atomicAdd(&cnt[pidx[2 * e]], 1u);
}

__global__ void __launch_bounds__(256) scan1_k(const unsigned* __restrict__ cnt,
                                               unsigned* __restrict__ cur,
                                               unsigned* __restrict__ part)
{
    __shared__ unsigned tmp[256];
    const int t = threadIdx.x;
    const int bin = blockIdx.x * 256 + t;
    unsigned v = (bin < NN) ? cnt[bin] : 0u;
    tmp[t] = v;
    __syncthreads();
    for (int off = 1; off < 256; off <<= 1) {
        unsigned a = (t >= off) ? tmp[t - off] : 0u;
        __syncthreads();
        tmp[t] += a;
        __syncthreads();
    }
    if (bin < NN) cur[bin] = tmp[t] - v;
    if (t == 255) part[blockIdx.x] = tmp[255];
}

__global__ void __launch_bounds__(256) scan2_k(unsigned* __restrict__ part)
{
    __shared__ unsigned tmp[256];
    const int t = threadIdx.x;
    unsigned v = (t < NSCAN) ? part[t] : 0u;
    tmp[t] = v;
    __syncthreads();
    for (int off = 1; off < 256; off <<= 1) {
        unsigned a = (t >= off) ? tmp[t - off] : 0u;
        __syncthreads();
        tmp[t] += a;
        __syncthreads();
    }
    if (t < NSCAN) part[t] = tmp[t] - v;
}

__global__ void __launch_bounds__(256) scan3_k(unsigned* __restrict__ cur,
                                               const unsigned* __restrict__ part)
{
    const int bin = blockIdx.x * 256 + threadIdx.x;
    if (bin < NN) cur[bin] += part[blockIdx.x];
}

// scaled offsets packed: sdp[pos] = { src*1024, dst*1024+512 }
__global__ void __launch_bounds__(256) scatter_k(
    const int* __restrict__ pidx, unsigned* __restrict__ cur,
    int* __restrict__ sid, int2* __restrict__ sdp)
{
    int e = blockIdx.x * 256 + threadIdx.x;
    int s = pidx[2 * e], d = pidx[2 * e + 1];
    unsigned pos = atomicAdd(&cur[s], 1u);
    sid[pos] = e;
    sdp[pos] = make_int2(s << 10, (d << 10) + 512);
}

// ===== C = ef @ K_bot via MFMA (bf16-hi only); fp8 (s,g) output, xL2E-scaled =====
__global__ void __launch_bounds__(512) edge_c_mfma(
    const float* __restrict__ ef, const float* __restrict__ Ks,
    const float* __restrict__ Kg, const int* __restrict__ sid,
    unsigned short* __restrict__ C16)
{
    __shared__ short As_h[64 * 64];   // 8 KB
    const int t = threadIdx.x;
    const int w = t >> 6, lane = t & 63;

    union U8 { short s[8]; bf16x8 v; };
    bf16x8 bS[2], bG[2];   // hi plane only
    {
        const int col = w * 16 + (lane & 15);
#pragma unroll
        for (int ki = 0; ki < 2; ++ki) {
            U8 sh_, gh_;
            const int kbase = 2 * AD + ki * 32 + (lane >> 4) * 8;
#pragma unroll
            for (int j = 0; j < 8; ++j) {
                sh_.s[j] = (short)bf16_rne(Ks[(size_t)(kbase + j) * AD + col]);
                gh_.s[j] = (short)bf16_rne(Kg[(size_t)(kbase + j) * AD + col]);
            }
            bS[ki] = sh_.v;
            bG[ki] = gh_.v;
        }
    }

    const int srow = t >> 4, sc4 = t & 15;
    f32x4 pf0, pf1;
    {
        int ea = sid[(size_t)blockIdx.x * 64 + srow];
        int eb = sid[(size_t)blockIdx.x * 64 + srow + 32];
        pf0 = __builtin_nontemporal_load((const f32x4*)&ef[(size_t)ea * 64 + 4 * sc4]);
        pf1 = __builtin_nontemporal_load((const f32x4*)&ef[(size_t)eb * 64 + 4 * sc4]);
    }

    for (int tile = blockIdx.x; tile < NTILES; tile += gridDim.x) {
        __syncthreads();
        {
            f32x4 v[2] = {pf0, pf1};
#pragma unroll
            for (int ii = 0; ii < 2; ++ii) {
                int row = srow + 32 * ii;
                unsigned short h0 = bf16_rne(v[ii][0]), h1 = bf16_rne(v[ii][1]),
                               h2 = bf16_rne(v[ii][2]), h3 = bf16_rne(v[ii][3]);
                int sidx = (row * 64 + sc4 * 4) ^ ((row & 7) << 3);
                *(short4*)&As_h[sidx] = make_short4((short)h0, (short)h1, (short)h2, (short)h3);
            }
        }
        {
            int nxt = tile + gridDim.x;
            if (nxt < NTILES) {
                int ea = sid[(size_t)nxt * 64 + srow];
                int eb = sid[(size_t)nxt * 64 + srow + 32];
                pf0 = __builtin_nontemporal_load((const f32x4*)&ef[(size_t)ea * 64 + 4 * sc4]);
                pf1 = __builtin_nontemporal_load((const f32x4*)&ef[(size_t)eb * 64 + 4 * sc4]);
            }
        }
        __syncthreads();

        f32x4 accS[4] = {}, accG[4] = {};
#pragma unroll
        for (int mt = 0; mt < 4; ++mt) {
#pragma unroll
            for (int ki = 0; ki < 2; ++ki) {
                int row = mt * 16 + (lane & 15);
                int idx = (row * 64 + ki * 32 + (lane >> 4) * 8) ^ ((row & 7) << 3);
                bf16x8 ah = *(const bf16x8*)&As_h[idx];
                accS[mt] = __builtin_amdgcn_mfma_f32_16x16x32_bf16(ah, bS[ki], accS[mt], 0, 0, 0);
                accG[mt] = __builtin_amdgcn_mfma_f32_16x16x32_bf16(ah, bG[ki], accG[mt], 0, 0, 0);
            }
        }
        const size_t p0 = (size_t)tile * 64;
#pragma unroll
        for (int mt = 0; mt < 4; ++mt) {
#pragma unroll
            for (int reg = 0; reg < 4; ++reg) {
                int row = mt * 16 + (lane >> 4) * 4 + reg;
                unsigned short val =
                    pack_fp8_pair(accS[mt][reg] * L2E, accG[mt][reg] * L2E);
                __builtin_nontemporal_store(val,
                    &C16[(p0 + row) * 128 + w * 16 + (lane & 15)]);
            }
        }
    }
}

// ===== sorted apply v8: fp8 C stream, 32 edges/wave, pinned depth-8 rings =====
__global__ void __launch_bounds__(256) edge_apply_sorted(
    const char* __restrict__ C8, const char* __restrict__ PQ8,
    const int2* __restrict__ sdp,
    const float* __restrict__ bs, const float* __restrict__ bg,
    float* __restrict__ acc)
{
    const int t = threadIdx.x & 63;
    const int w = threadIdx.x >> 6;
    const size_t p0 = ((size_t)blockIdx.x * 4 + w) * 32;
    const int2 sd = sdp[p0 + (t & 31)];   // lanes 0..31 hold the segment's edges
    const int srcv = sd.x, dstv = sd.y;

    const float2 bsv = *(const float2*)&bs[2 * t];
    const float2 bgv = *(const float2*)&bg[2 * t];
    const float bsA = bsv.x * L2E, bsB = bsv.y * L2E;
    const float bgA = bgv.x * L2E, bgB = bgv.y * L2E;

    const char* PQl = PQ8 + 8 * t;
    char* accl = (char*)acc + 8 * t;
    const char* Cl = C8 + p0 * 256 + 4 * t;   // fp8 row = 256 B

#define RL(v, i) __builtin_amdgcn_readlane((v), (i))
#define LOADC(i) __builtin_nontemporal_load((const unsigned*)(Cl + (i) * 256))
#define LOADQ(i) (*(const u32x2*)(PQl + RL(dstv, (i))))
#define LOADP(s_) (*(const u32x2*)(PQl + (s_)))
#define PIN __builtin_amdgcn_sched_barrier(0)

    int cur = RL(srcv, 0);
    u32x2 pv = LOADP(cur);
    float psA = unp_lo(pv.x) + bsA, pgA = unp_hi(pv.x) + bgA;
    float psB = unp_lo(pv.y) + bsB, pgB = unp_hi(pv.y) + bgB;

    unsigned c0 = LOADC(0), c1 = LOADC(1), c2 = LOADC(2), c3 = LOADC(3),
             c4 = LOADC(4), c5 = LOADC(5), c6 = LOADC(6), c7 = LOADC(7);
    u32x2 q0 = LOADQ(0), q1 = LOADQ(1), q2 = LOADQ(2), q3 = LOADQ(3),
          q4 = LOADQ(4), q5 = LOADQ(5), q6 = LOADQ(6), q7 = LOADQ(7);
    u32x2 r0 = pv, r1 = pv, r2 = pv, r3 = pv, r4 = pv, r5 = pv, r6 = pv, r7 = pv;
    if (RL(srcv, 1) != RL(srcv, 0)) r1 = LOADP(RL(srcv, 1));
    if (RL(srcv, 2) != RL(srcv, 1)) r2 = LOADP(RL(srcv, 2));
    if (RL(srcv, 3) != RL(srcv, 2)) r3 = LOADP(RL(srcv, 3));
    if (RL(srcv, 4) != RL(srcv, 3)) r4 = LOADP(RL(srcv, 4));
    if (RL(srcv, 5) != RL(srcv, 4)) r5 = LOADP(RL(srcv, 5));
    if (RL(srcv, 6) != RL(srcv, 5)) r6 = LOADP(RL(srcv, 6));
    if (RL(srcv, 7) != RL(srcv, 6)) r7 = LOADP(RL(srcv, 7));
    PIN;   // all prologue loads issued before any compute
    float accA = 0.f, accB = 0.f;

#define FLUSH                                                              \
    atomicAdd((float*)(accl + ((unsigned)cur >> 1)),     LN2 * accA);      \
    atomicAdd((float*)(accl + ((unsigned)cur >> 1) + 4), LN2 * accB);

#define CORE(i, cc, qq, rr)                                                \
    {                                                                      \
        int src_ = RL(srcv, (i));                                          \
        if (src_ != cur) {                                                 \
            FLUSH;                                                         \
            accA = 0.f; accB = 0.f; cur = src_;                            \
            psA = unp_lo(rr.x) + bsA; pgA = unp_hi(rr.x) + bgA;            \
            psB = unp_lo(rr.y) + bsB; pgB = unp_hi(rr.y) + bgB;            \
        }                                                                  \
        f32x2 sgA = __builtin_amdgcn_cvt_pk_f32_fp8((int)cc, false);       \
        f32x2 sgB = __builtin_amdgcn_cvt_pk_f32_fp8((int)cc, true);        \
        float sA = sgA[0] + unp_lo(qq.x) + psA;                            \
        float gA = sgA[1] + unp_hi(qq.x) + pgA;                            \
        float sB = sgB[0] + unp_lo(qq.y) + psB;                            \
        float gB = sgB[1] + unp_hi(qq.y) + pgB;                            \
        float spA = fmaxf(gA, 0.f) + log2_f(1.f + nexp2_abs_f(gA));        \
        float spB = fmaxf(gB, 0.f) + log2_f(1.f + nexp2_abs_f(gB));       \
        accA = fmaf(__builtin_amdgcn_rcpf(1.f + nexp2_f(sA)), spA, accA);  \
        accB = fmaf(__builtin_amdgcn_rcpf(1.f + nexp2_f(sB)), spB, accB);  \
    }

// prefetch loads for i+8, then PIN so they cannot sink into later iterations
#define STEP(i, cc, qq, rr)                                                \
    {                                                                      \
        unsigned ncc = LOADC((i) + 8);                                     \
        u32x2 nqq = LOADQ((i) + 8);                                        \
        u32x2 nrr = rr;                                                    \
        if (RL(srcv, (i) + 8) != RL(srcv, (i) + 7))                        \
            nrr = LOADP(RL(srcv, (i) + 8));                                \
        PIN;                                                               \
        CORE(i, cc, qq, rr)                                                \
        cc = ncc; qq = nqq; rr = nrr;                                      \
    }

    for (int b = 0; b < 24; b += 8) {
        STEP(b + 0, c0, q0, r0)
        STEP(b + 1, c1, q1, r1)
        STEP(b + 2, c2, q2, r2)
        STEP(b + 3, c3, q3, r3)
        STEP(b + 4, c4, q4, r4)
        STEP(b + 5, c5, q5, r5)
        STEP(b + 6, c6, q6, r6)
        STEP(b + 7, c7, q7, r7)
    }
    CORE(24, c0, q0, r0)
    CORE(25, c1, q1, r1)
    CORE(26, c2, q2, r2)
    CORE(27, c3, q3, r3)
    CORE(28, c4, q4, r4)
    CORE(29, c5, q5, r5)
    CORE(30, c6, q6, r6)
    CORE(31, c7, q7, r7)
    FLUSH;

#undef STEP
#undef CORE
#undef FLUSH
#undef PIN
#undef LOADP
#undef LOADQ
#undef LOADC
#undef RL
}

// ===== final softplus (HW exp2/log2) =====
__global__ void __launch_bounds__(256) act_k(float* __restrict__ acc)
{
    size_t i = ((size_t)blockIdx.x * 256 + threadIdx.x) * 4;
    float4 v = *(float4*)&acc[i];
    v.x = softplus_hw(v.x);
    v.y = softplus_hw(v.y);
    v.z = softplus_hw(v.z);
    v.w = softplus_hw(v.w);
    *(float4*)&acc[i] = v;
}

// ===== Tier B fallback (round-1, known good) =====
__global__ void __launch_bounds__(128) node_mm_f32(
    const float* __restrict__ x, const float* __restrict__ Ks,
    const float* __restrict__ Kg, float* __restrict__ PQ)
{
    __shared__ float xs[8][AD];
    const int t = threadIdx.x;
    const int row0 = blockIdx.x * 8;
#pragma unroll
    for (int r = 0; r < 8; ++r) xs[r][t] = x[(size_t)(row0 + r) * AD + t];
    __syncthreads();
    float aPs[8] = {}, aQs[8] = {}, aPg[8] = {}, aQg[8] = {};
    for (int k = 0; k < AD; ++k) {
        float ks_s = Ks[k * AD + t];
        float ks_d = Ks[(AD + k) * AD + t];
        float kg_s = Kg[k * AD + t];
        float kg_d = Kg[(AD + k) * AD + t];
#pragma unroll
        for (int r = 0; r < 8; ++r) {
            float xv = xs[r][k];
            aPs[r] = fmaf(xv, ks_s, aPs[r]);
            aQs[r] = fmaf(xv, ks_d, aQs[r]);
            aPg[r] = fmaf(xv, kg_s, aPg[r]);
            aQg[r] = fmaf(xv, kg_d, aQg[r]);
        }
    }
#pragma unroll
    for (int r = 0; r < 8; ++r) {
        float* o = PQ + (size_t)(row0 + r) * 512;
        *(float2*)&o[2 * t]       = make_float2(aPs[r], aPg[r]);
        *(float2*)&o[256 + 2 * t] = make_float2(aQs[r], aQg[r]);
    }
}

__global__ void __launch_bounds__(256) edge_fused(
    const float* __restrict__ ef, const float* __restrict__ Ks,
    const float* __restrict__ Kg, const float* __restrict__ PQ,
    const int* __restrict__ pidx, const float* __restrict__ bs,
    const float* __restrict__ bg, float* __restrict__ acc)
{
    __shared__ float KB[ED][2 * AD];
    __shared__ float es[64][ED];
    const int t = threadIdx.x;
    for (int i = t; i < ED * AD; i += 256) {
        int k = i >> 7, n = i & 127;
        KB[k][2 * n]     = Ks[(2 * AD + k) * AD + n];
        KB[k][2 * n + 1] = Kg[(2 * AD + k) * AD + n];
    }
    const size_t e0 = (size_t)blockIdx.x * 64;
    for (int i = t; i < 64 * ED; i += 256) ((float*)es)[i] = ef[e0 * ED + i];
    __syncthreads();
    const int le = t >> 7, n = t & 127;
    const float bsn = bs[n], bgn = bg[n];
    for (int base = le * 8; base < 64; base += 16) {
        float accS[8] = {}, accG[8] = {};
        for (int k4 = 0; k4 < ED / 4; ++k4) {
            float2 kv0 = *(const float2*)&KB[4 * k4 + 0][2 * n];
            float2 kv1 = *(const float2*)&KB[4 * k4 + 1][2 * n];
            float2 kv2 = *(const float2*)&KB[4 * k4 + 2][2 * n];
            float2 kv3 = *(const float2*)&KB[4 * k4 + 3][2 * n];
#pragma unroll
            for (int r = 0; r < 8; ++r) {
                float4 ev = *(const float4*)&es[base + r][4 * k4];
                accS[r] = fmaf(ev.x, kv0.x, accS[r]);
                accG[r] = fmaf(ev.x, kv0.y, accG[r]);
                accS[r] = fmaf(ev.y, kv1.x, accS[r]);
                accG[r] = fmaf(ev.y, kv1.y, accG[r]);
                accS[r] = fmaf(ev.z, kv2.x, accS[r]);
                accG[r] = fmaf(ev.z, kv2.y, accG[r]);
                accS[r] = fmaf(ev.w, kv3.x, accS[r]);
                accG[r] = fmaf(ev.w, kv3.y, accG[r]);
            }
        }
#pragma unroll
        for (int r = 0; r < 8; ++r) {
            size_t e = e0 + base + r;
            int src = pidx[2 * e], dst = pidx[2 * e + 1];
            float2 pv = *(const float2*)&PQ[(size_t)src * 512 + 2 * n];
            float2 qv = *(const float2*)&PQ[(size_t)dst * 512 + 256 + 2 * n];
            float s = accS[r] + pv.x + qv.x + bsn;
            float g = accG[r] + pv.y + qv.y + bgn;
            atomicAdd(&acc[(size_t)src * AD + n], sigmoid_fast(s) * softplus_f(g));
        }
    }
}

// ===== launch =====
extern "C" void kernel_launch(void* const* d_in, const int* in_sizes, int n_in,
                              void* d_out, int out_size, void* d_ws, size_t ws_size,
                              hipStream_t stream)
{
    const float* atom = (const float*)d_in[0];
    const float* ef   = (const float*)d_in[1];
    const float* Ks   = (const float*)d_in[3];
    const float* bs   = (const float*)d_in[4];
    const float* Kg   = (const float*)d_in[5];
    const float* bg   = (const float*)d_in[6];
    const int*   pidx = (const int*)d_in[7];

    float* acc = (float*)d_out;

    char* w = (char*)d_ws;
    const size_t PQ_B   = (size_t)NN * 256 * 4;   //  51.2 MB
    const size_t C_B    = (size_t)NE * 128 * 2;   // 204.8 MB (fp8 pairs)
    const size_t BN_B   = 16384 * 16;             // 256 KB
    const size_t CNT_B  = (size_t)NN * 4;
    const size_t IDX_B  = (size_t)NE * 4;
    const size_t PART_B = 256 * 4;
    unsigned* PQ32      = (unsigned*)w;       w += PQ_B;
    unsigned short* C16 = (unsigned short*)w; w += C_B;
    bf16x8*   Bn   = (bf16x8*)w;    w += BN_B;
    unsigned* cnt  = (unsigned*)w;  w += CNT_B;
    unsigned* curp = (unsigned*)w;  w += CNT_B;
    int*      sid  = (int*)w;       w += IDX_B;
    int2*     sdp  = (int2*)w;      w += 2 * IDX_B;
    unsigned* part = (unsigned*)w;  w += PART_B;
    const size_t TOTAL_A = PQ_B + C_B + BN_B + 2 * CNT_B + 3 * IDX_B + PART_B;

    if (ws_size >= TOTAL_A) {
        hipMemsetAsync(cnt, 0, CNT_B, stream);
        bn_prep<<<64, 256, 0, stream>>>(Ks, Kg, Bn);
        hist_k<<<NE / 256, 256, 0, stream>>>(pidx, cnt);
        scan1_k<<<NSCAN, 256, 0, stream>>>(cnt, curp, part);
        scan2_k<<<1, 256, 0, stream>>>(part);
        scan3_k<<<NSCAN, 256, 0, stream>>>(curp, part);
        scatter_k<<<NE / 256, 256, 0, stream>>>(pidx, curp, sid, sdp);
        edge_c_mfma<<<2048, 512, 0, stream>>>(ef, Ks, Kg, sid, C16);

        for (int s = 0; s < NSTEPS; ++s) {
            node_mm_mfma<<<NROWB, 512, 0, stream>>>(atom, acc, Bn, PQ32,
                                                    s == 0 ? 0 : 1);
            edge_apply_sorted<<<NE / 128, 256, 0, stream>>>(
                (const char*)C16, (const char*)PQ32, sdp, bs, bg, acc);
        }
        act_k<<<(NN * AD) / 1024, 256, 0, stream>>>(acc);
    } else {
        float* PQ = (float*)d_ws;
        hipMemcpyAsync(acc, atom, (size_t)NN * AD * sizeof(float),
                       hipMemcpyDeviceToDevice, stream);
        for (int s = 0; s < NSTEPS; ++s) {
            node_mm_f32<<<NN / 8, 128, 0, stream>>>(acc, Ks, Kg, PQ);
            edge_fused<<<NE / 64, 256, 0, stream>>>(ef, Ks, Kg, PQ, pidx, bs, bg, acc);
            act_k<<<(NN * AD) / 1024, 256, 0, stream>>>(acc);
        }
    }
}

// Round 15
// 649.671 us; speedup vs baseline: 1.2518x; 1.0165x over previous
//
#include <hip/hip_runtime.h>
#include <hip/hip_bf16.h>
#include <math.h>

// CrystalGraphConvolution — MI355X round 15
// vs r14: C (204.8 MB fp8) now FITS the 256 MB Infinity Cache and is read 3x
// — drop the nontemporal hints on the C path (edge_c store, apply load) so
// applies 2-3 hit L3 instead of HBM. ef gather keeps nt (single-use).

#define NN 50000
#define NE 800000
#define AD 128
#define ED 64
#define NSTEPS 3
#define NTILES (NE / 64)          // 12500
#define NSCAN  ((NN + 255) / 256) // 196
#define NROWB  ((NN + 63) / 64)   // 782

#define L2E 1.4426950408889634f
#define LN2 0.6931471805599453f

typedef __attribute__((ext_vector_type(8))) __bf16 bf16x8;
typedef __attribute__((ext_vector_type(4))) float  f32x4;
typedef __attribute__((ext_vector_type(2))) float  f32x2;
typedef __attribute__((ext_vector_type(2))) unsigned u32x2;

__device__ __forceinline__ float softplus_f(float x) {      // Tier B only
    return fmaxf(x, 0.f) + log1pf(__expf(-fabsf(x)));
}
__device__ __forceinline__ float sigmoid_fast(float x) {    // Tier B
    float e = __expf(-fabsf(x));
    float r = __builtin_amdgcn_rcpf(1.f + e);
    return (x >= 0.f) ? r : 1.f - r;
}
__device__ __forceinline__ unsigned short bf16_rne(float f) {
    unsigned u = __float_as_uint(f);
    unsigned r = u + 0x7fffu + ((u >> 16) & 1u);
    return (unsigned short)(r >> 16);
}
__device__ __forceinline__ unsigned pack_bf2(float s, float g) {
    return (unsigned)bf16_rne(s) | ((unsigned)bf16_rne(g) << 16);
}
__device__ __forceinline__ float unp_lo(unsigned v) { return __uint_as_float(v << 16); }
__device__ __forceinline__ float unp_hi(unsigned v) { return __uint_as_float(v & 0xffff0000u); }

__device__ __forceinline__ float nexp2_f(float x) {         // 2^(-x)
    float r; asm("v_exp_f32 %0, -%1" : "=v"(r) : "v"(x)); return r;
}
__device__ __forceinline__ float nexp2_abs_f(float x) {     // 2^(-|x|)
    float r; asm("v_exp_f32 %0, -abs(%1)" : "=v"(r) : "v"(x)); return r;
}
__device__ __forceinline__ float log2_f(float x) {
    float r; asm("v_log_f32 %0, %1" : "=v"(r) : "v"(x)); return r;
}
// HW softplus: ln2 * (max(y,0) + log2(1 + 2^-|y|)), y = x*log2e. rel err ~1e-6.
__device__ __forceinline__ float softplus_hw(float x) {
    float y = x * L2E;
    return LN2 * (fmaxf(y, 0.f) + log2_f(1.f + nexp2_abs_f(y)));
}
// fp8 e4m3 pack (gfx950 OCP; round-trips through same HW format)
__device__ __forceinline__ unsigned short pack_fp8_pair(float s, float g) {
    int v = __builtin_amdgcn_cvt_pk_fp8_f32(s, g, 0, false);  // bytes 0,1
    return (unsigned short)(v & 0xffff);
}

// ===== one-time B pre-pack for node GEMM =====
__global__ void __launch_bounds__(256) bn_prep(
    const float* __restrict__ Ks, const float* __restrict__ Kg,
    bf16x8* __restrict__ Bn)
{
    union U8 { short s[8]; bf16x8 v; };
    int idx = blockIdx.x * 256 + threadIdx.x;      // 64 blocks -> 16384
    int l4  = idx & 3;
    int col = (idx >> 2) & 127;
    int ki  = (idx >> 9) & 3;
    int hl  = (idx >> 11) & 1;
    int m   = (idx >> 12) & 1;
    int sel = (idx >> 13) & 1;
    const float* K = m ? Kg : Ks;
    U8 o;
#pragma unroll
    for (int j = 0; j < 8; ++j) {
        int k = sel * 128 + ki * 32 + l4 * 8 + j;
        float v = K[(size_t)k * AD + col];
        unsigned short h = bf16_rne(v);
        o.s[j] = (hl == 0) ? (short)h
                           : (short)bf16_rne(v - __uint_as_float((unsigned)h << 16));
    }
    Bn[idx] = o.v;
}

// ===== node projections via MFMA (hi/lo), + x maintenance; outputs xL2E-scaled =====
__global__ void __launch_bounds__(512, 1) node_mm_mfma(
    const float* __restrict__ xin, float* __restrict__ acc,
    const bf16x8* __restrict__ Bn, unsigned* __restrict__ PQ32, int mode)
{
    __shared__ short As_h[64 * 128];
    __shared__ short As_l[64 * 128];
    const int t = threadIdx.x;
    const int w = t >> 6, lane = t & 63;
    const int l4 = lane >> 4;
    const int row0 = blockIdx.x * 64;

#pragma unroll
    for (int ii = 0; ii < 4; ++ii) {
        int idx = t + 512 * ii;
        int row = idx >> 5, c4 = idx & 31;
        int node = row0 + row;
        f32x4 v = {};
        if (node < NN) {
            if (mode == 0) {
                v = *(const f32x4*)&xin[(size_t)node * AD + 4 * c4];
                *(f32x4*)&acc[(size_t)node * AD + 4 * c4] = v;
            } else {
                f32x4 a = *(const f32x4*)&acc[(size_t)node * AD + 4 * c4];
                v[0] = softplus_hw(a[0]); v[1] = softplus_hw(a[1]);
                v[2] = softplus_hw(a[2]); v[3] = softplus_hw(a[3]);
                *(f32x4*)&acc[(size_t)node * AD + 4 * c4] = v;
            }
        }
        unsigned short h0 = bf16_rne(v[0]), h1 = bf16_rne(v[1]),
                       h2 = bf16_rne(v[2]), h3 = bf16_rne(v[3]);
        unsigned short l0 = bf16_rne(v[0] - __uint_as_float((unsigned)h0 << 16));
        unsigned short l1 = bf16_rne(v[1] - __uint_as_float((unsigned)h1 << 16));
        unsigned short l2 = bf16_rne(v[2] - __uint_as_float((unsigned)h2 << 16));
        unsigned short l3 = bf16_rne(v[3] - __uint_as_float((unsigned)h3 << 16));
        int sidx = (row * 128 + c4 * 4) ^ ((row & 7) << 3);
        *(short4*)&As_h[sidx] = make_short4((short)h0, (short)h1, (short)h2, (short)h3);
        *(short4*)&As_l[sidx] = make_short4((short)l0, (short)l1, (short)l2, (short)l3);
    }
    __syncthreads();

    const int col = w * 16 + (lane & 15);
#pragma unroll
    for (int sel = 0; sel < 2; ++sel) {
        bf16x8 bS[4][2], bG[4][2];
#pragma unroll
        for (int ki = 0; ki < 4; ++ki) {
#pragma unroll
            for (int hl = 0; hl < 2; ++hl) {
                bS[ki][hl] = Bn[(((sel * 2 + 0) * 2 + hl) * 4 + ki) * 512 + col * 4 + l4];
                bG[ki][hl] = Bn[(((sel * 2 + 1) * 2 + hl) * 4 + ki) * 512 + col * 4 + l4];
            }
        }
        f32x4 aS[4] = {}, aG[4] = {};
#pragma unroll
        for (int mt = 0; mt < 4; ++mt) {
            int row = mt * 16 + (lane & 15);
#pragma unroll
            for (int ki = 0; ki < 4; ++ki) {
                int idx = (row * 128 + ki * 32 + l4 * 8) ^ ((row & 7) << 3);
                bf16x8 ah = *(const bf16x8*)&As_h[idx];
                bf16x8 al = *(const bf16x8*)&As_l[idx];
                aS[mt] = __builtin_amdgcn_mfma_f32_16x16x32_bf16(ah, bS[ki][0], aS[mt], 0, 0, 0);
                aS[mt] = __builtin_amdgcn_mfma_f32_16x16x32_bf16(al, bS[ki][0], aS[mt], 0, 0, 0);
                aS[mt] = __builtin_amdgcn_mfma_f32_16x16x32_bf16(ah, bS[ki][1], aS[mt], 0, 0, 0);
                aG[mt] = __builtin_amdgcn_mfma_f32_16x16x32_bf16(ah, bG[ki][0], aG[mt], 0, 0, 0);
                aG[mt] = __builtin_amdgcn_mfma_f32_16x16x32_bf16(al, bG[ki][0], aG[mt], 0, 0, 0);
                aG[mt] = __builtin_amdgcn_mfma_f32_16x16x32_bf16(ah, bG[ki][1], aG[mt], 0, 0, 0);
            }
        }
#pragma unroll
        for (int mt = 0; mt < 4; ++mt) {
#pragma unroll
            for (int reg = 0; reg < 4; ++reg) {
                int node = row0 + mt * 16 + l4 * 4 + reg;
                if (node < NN)
                    PQ32[(size_t)node * 256 + sel * 128 + col] =
                        pack_bf2(aS[mt][reg] * L2E, aG[mt][reg] * L2E);
            }
        }
    }
}

// ===== sort machinery =====
__global__ void __launch_bounds__(256) hist_k(const int* __restrict__ pidx,
                                              unsigned* __restrict__ cnt)
{
    int e = blockIdx.x * 256 + threadIdx.x;
    atomicAdd(&cnt[pidx[2 * e]], 1u);
}

__global__ void __launch_bounds__(256) scan1_k(const unsigned* __restrict__ cnt,
                                               unsigned* __restrict__ cur,
                                               unsigned* __restrict__ part)
{
    __shared__ unsigned tmp[256];
    const int t = threadIdx.x;
    const int bin = blockIdx.x * 256 + t;
    unsigned v = (bin < NN) ? cnt[bin] : 0u;
    tmp[t] = v;
    __syncthreads();
    for (int off = 1; off < 256; off <<= 1) {
        unsigned a = (t >= off) ? tmp[t - off] : 0u;
        __syncthreads();
        tmp[t] += a;
        __syncthreads();
    }
    if (bin < NN) cur[bin] = tmp[t] - v;
    if (t == 255) part[blockIdx.x] = tmp[255];
}

__global__ void __launch_bounds__(256) scan2_k(unsigned* __restrict__ part)
{
    __shared__ unsigned tmp[256];
    const int t = threadIdx.x;
    unsigned v = (t < NSCAN) ? part[t] : 0u;
    tmp[t] = v;
    __syncthreads();
    for (int off = 1; off < 256; off <<= 1) {
        unsigned a = (t >= off) ? tmp[t - off] : 0u;
        __syncthreads();
        tmp[t] += a;
        __syncthreads();
    }
    if (t < NSCAN) part[t] = tmp[t] - v;
}

__global__ void __launch_bounds__(256) scan3_k(unsigned* __restrict__ cur,
                                               const unsigned* __restrict__ part)
{
    const int bin = blockIdx.x * 256 + threadIdx.x;
    if (bin < NN) cur[bin] += part[blockIdx.x];
}

// scaled offsets packed: sdp[pos] = { src*1024, dst*1024+512 }
__global__ void __launch_bounds__(256) scatter_k(
    const int* __restrict__ pidx, unsigned* __restrict__ cur,
    int* __restrict__ sid, int2* __restrict__ sdp)
{
    int e = blockIdx.x * 256 + threadIdx.x;
    int s = pidx[2 * e], d = pidx[2 * e + 1];
    unsigned pos = atomicAdd(&cur[s], 1u);
    sid[pos] = e;
    sdp[pos] = make_int2(s << 10, (d << 10) + 512);
}

// ===== C = ef @ K_bot via MFMA (bf16-hi only); fp8 (s,g) output, xL2E-scaled =====
__global__ void __launch_bounds__(512) edge_c_mfma(
    const float* __restrict__ ef, const float* __restrict__ Ks,
    const float* __restrict__ Kg, const int* __restrict__ sid,
    unsigned short* __restrict__ C16)
{
    __shared__ short As_h[64 * 64];   // 8 KB
    const int t = threadIdx.x;
    const int w = t >> 6, lane = t & 63;

    union U8 { short s[8]; bf16x8 v; };
    bf16x8 bS[2], bG[2];   // hi plane only
    {
        const int col = w * 16 + (lane & 15);
#pragma unroll
        for (int ki = 0; ki < 2; ++ki) {
            U8 sh_, gh_;
            const int kbase = 2 * AD + ki * 32 + (lane >> 4) * 8;
#pragma unroll
            for (int j = 0; j < 8; ++j) {
                sh_.s[j] = (short)bf16_rne(Ks[(size_t)(kbase + j) * AD + col]);
                gh_.s[j] = (short)bf16_rne(Kg[(size_t)(kbase + j) * AD + col]);
            }
            bS[ki] = sh_.v;
            bG[ki] = gh_.v;
        }
    }

    const int srow = t >> 4, sc4 = t & 15;
    f32x4 pf0, pf1;
    {
        int ea = sid[(size_t)blockIdx.x * 64 + srow];
        int eb = sid[(size_t)blockIdx.x * 64 + srow + 32];
        pf0 = __builtin_nontemporal_load((const f32x4*)&ef[(size_t)ea * 64 + 4 * sc4]);
        pf1 = __builtin_nontemporal_load((const f32x4*)&ef[(size_t)eb * 64 + 4 * sc4]);
    }

    for (int tile = blockIdx.x; tile < NTILES; tile += gridDim.x) {
        __syncthreads();
        {
            f32x4 v[2] = {pf0, pf1};
#pragma unroll
            for (int ii = 0; ii < 2; ++ii) {
                int row = srow + 32 * ii;
                unsigned short h0 = bf16_rne(v[ii][0]), h1 = bf16_rne(v[ii][1]),
                               h2 = bf16_rne(v[ii][2]), h3 = bf16_rne(v[ii][3]);
                int sidx = (row * 64 + sc4 * 4) ^ ((row & 7) << 3);
                *(short4*)&As_h[sidx] = make_short4((short)h0, (short)h1, (short)h2, (short)h3);
            }
        }
        {
            int nxt = tile + gridDim.x;
            if (nxt < NTILES) {
                int ea = sid[(size_t)nxt * 64 + srow];
                int eb = sid[(size_t)nxt * 64 + srow + 32];
                pf0 = __builtin_nontemporal_load((const f32x4*)&ef[(size_t)ea * 64 + 4 * sc4]);
                pf1 = __builtin_nontemporal_load((const f32x4*)&ef[(size_t)eb * 64 + 4 * sc4]);
            }
        }
        __syncthreads();

        f32x4 accS[4] = {}, accG[4] = {};
#pragma unroll
        for (int mt = 0; mt < 4; ++mt) {
#pragma unroll
            for (int ki = 0; ki < 2; ++ki) {
                int row = mt * 16 + (lane & 15);
                int idx = (row * 64 + ki * 32 + (lane >> 4) * 8) ^ ((row & 7) << 3);
                bf16x8 ah = *(const bf16x8*)&As_h[idx];
                accS[mt] = __builtin_amdgcn_mfma_f32_16x16x32_bf16(ah, bS[ki], accS[mt], 0, 0, 0);
                accG[mt] = __builtin_amdgcn_mfma_f32_16x16x32_bf16(ah, bG[ki], accG[mt], 0, 0, 0);
            }
        }
        const size_t p0 = (size_t)tile * 64;
#pragma unroll
        for (int mt = 0; mt < 4; ++mt) {
#pragma unroll
            for (int reg = 0; reg < 4; ++reg) {
                int row = mt * 16 + (lane >> 4) * 4 + reg;
                C16[(p0 + row) * 128 + w * 16 + (lane & 15)] =
                    pack_fp8_pair(accS[mt][reg] * L2E, accG[mt][reg] * L2E);
            }
        }
    }
}

// ===== sorted apply v9: cacheable fp8 C stream, 32 edges/wave, pinned rings =====
__global__ void __launch_bounds__(256) edge_apply_sorted(
    const char* __restrict__ C8, const char* __restrict__ PQ8,
    const int2* __restrict__ sdp,
    const float* __restrict__ bs, const float* __restrict__ bg,
    float* __restrict__ acc)
{
    const int t = threadIdx.x & 63;
    const int w = threadIdx.x >> 6;
    const size_t p0 = ((size_t)blockIdx.x * 4 + w) * 32;
    const int2 sd = sdp[p0 + (t & 31)];   // lanes 0..31 hold the segment's edges
    const int srcv = sd.x, dstv = sd.y;

    const float2 bsv = *(const float2*)&bs[2 * t];
    const float2 bgv = *(const float2*)&bg[2 * t];
    const float bsA = bsv.x * L2E, bsB = bsv.y * L2E;
    const float bgA = bgv.x * L2E, bgB = bgv.y * L2E;

    const char* PQl = PQ8 + 8 * t;
    char* accl = (char*)acc + 8 * t;
    const char* Cl = C8 + p0 * 256 + 4 * t;   // fp8 row = 256 B

#define RL(v, i) __builtin_amdgcn_readlane((v), (i))
#define LOADC(i) (*(const unsigned*)(Cl + (i) * 256))
#define LOADQ(i) (*(const u32x2*)(PQl + RL(dstv, (i))))
#define LOADP(s_) (*(const u32x2*)(PQl + (s_)))
#define PIN __builtin_amdgcn_sched_barrier(0)

    int cur = RL(srcv, 0);
    u32x2 pv = LOADP(cur);
    float psA = unp_lo(pv.x) + bsA, pgA = unp_hi(pv.x) + bgA;
    float psB = unp_lo(pv.y) + bsB, pgB = unp_hi(pv.y) + bgB;

    unsigned c0 = LOADC(0), c1 = LOADC(1), c2 = LOADC(2), c3 = LOADC(3),
             c4 = LOADC(4), c5 = LOADC(5), c6 = LOADC(6), c7 = LOADC(7);
    u32x2 q0 = LOADQ(0), q1 = LOADQ(1), q2 = LOADQ(2), q3 = LOADQ(3),
          q4 = LOADQ(4), q5 = LOADQ(5), q6 = LOADQ(6), q7 = LOADQ(7);
    u32x2 r0 = pv, r1 = pv, r2 = pv, r3 = pv, r4 = pv, r5 = pv, r6 = pv, r7 = pv;
    if (RL(srcv, 1) != RL(srcv, 0)) r1 = LOADP(RL(srcv, 1));
    if (RL(srcv, 2) != RL(srcv, 1)) r2 = LOADP(RL(srcv, 2));
    if (RL(srcv, 3) != RL(srcv, 2)) r3 = LOADP(RL(srcv, 3));
    if (RL(srcv, 4) != RL(srcv, 3)) r4 = LOADP(RL(srcv, 4));
    if (RL(srcv, 5) != RL(srcv, 4)) r5 = LOADP(RL(srcv, 5));
    if (RL(srcv, 6) != RL(srcv, 5)) r6 = LOADP(RL(srcv, 6));
    if (RL(srcv, 7) != RL(srcv, 6)) r7 = LOADP(RL(srcv, 7));
    PIN;   // all prologue loads issued before any compute
    float accA = 0.f, accB = 0.f;

#define FLUSH                                                              \
    atomicAdd((float*)(accl + ((unsigned)cur >> 1)),     LN2 * accA);      \
    atomicAdd((float*)(accl + ((unsigned)cur >> 1) + 4), LN2 * accB);

#define CORE(i, cc, qq, rr)                                                \
    {                                                                      \
        int src_ = RL(srcv, (i));                                          \
        if (src_ != cur) {                                                 \
            FLUSH;                                                         \
            accA = 0.f; accB = 0.f; cur = src_;                            \
            psA = unp_lo(rr.x) + bsA; pgA = unp_hi(rr.x) + bgA;            \
            psB = unp_lo(rr.y) + bsB; pgB = unp_hi(rr.y) + bgB;            \
        }                                                                  \
        f32x2 sgA = __builtin_amdgcn_cvt_pk_f32_fp8((int)cc, false);       \
        f32x2 sgB = __builtin_amdgcn_cvt_pk_f32_fp8((int)cc, true);        \
        float sA = sgA[0] + unp_lo(qq.x) + psA;                            \
        float gA = sgA[1] + unp_hi(qq.x) + pgA;                            \
        float sB = sgB[0] + unp_lo(qq.y) + psB;                            \
        float gB = sgB[1] + unp_hi(qq.y) + pgB;                            \
        float spA = fmaxf(gA, 0.f) + log2_f(1.f + nexp2_abs_f(gA));        \
        float spB = fmaxf(gB, 0.f) + log2_f(1.f + nexp2_abs_f(gB));       \
        accA = fmaf(__builtin_amdgcn_rcpf(1.f + nexp2_f(sA)), spA, accA);  \
        accB = fmaf(__builtin_amdgcn_rcpf(1.f + nexp2_f(sB)), spB, accB);  \
    }

// prefetch loads for i+8, then PIN so they cannot sink into later iterations
#define STEP(i, cc, qq, rr)                                                \
    {                                                                      \
        unsigned ncc = LOADC((i) + 8);                                     \
        u32x2 nqq = LOADQ((i) + 8);                                        \
        u32x2 nrr = rr;                                                    \
        if (RL(srcv, (i) + 8) != RL(srcv, (i) + 7))                        \
            nrr = LOADP(RL(srcv, (i) + 8));                                \
        PIN;                                                               \
        CORE(i, cc, qq, rr)                                                \
        cc = ncc; qq = nqq; rr = nrr;                                      \
    }

    for (int b = 0; b < 24; b += 8) {
        STEP(b + 0, c0, q0, r0)
        STEP(b + 1, c1, q1, r1)
        STEP(b + 2, c2, q2, r2)
        STEP(b + 3, c3, q3, r3)
        STEP(b + 4, c4, q4, r4)
        STEP(b + 5, c5, q5, r5)
        STEP(b + 6, c6, q6, r6)
        STEP(b + 7, c7, q7, r7)
    }
    CORE(24, c0, q0, r0)
    CORE(25, c1, q1, r1)
    CORE(26, c2, q2, r2)
    CORE(27, c3, q3, r3)
    CORE(28, c4, q4, r4)
    CORE(29, c5, q5, r5)
    CORE(30, c6, q6, r6)
    CORE(31, c7, q7, r7)
    FLUSH;

#undef STEP
#undef CORE
#undef FLUSH
#undef PIN
#undef LOADP
#undef LOADQ
#undef LOADC
#undef RL
}

// ===== final softplus (HW exp2/log2) =====
__global__ void __launch_bounds__(256) act_k(float* __restrict__ acc)
{
    size_t i = ((size_t)blockIdx.x * 256 + threadIdx.x) * 4;
    float4 v = *(float4*)&acc[i];
    v.x = softplus_hw(v.x);
    v.y = softplus_hw(v.y);
    v.z = softplus_hw(v.z);
    v.w = softplus_hw(v.w);
    *(float4*)&acc[i] = v;
}

// ===== Tier B fallback (round-1, known good) =====
__global__ void __launch_bounds__(128) node_mm_f32(
    const float* __restrict__ x, const float* __restrict__ Ks,
    const float* __restrict__ Kg, float* __restrict__ PQ)
{
    __shared__ float xs[8][AD];
    const int t = threadIdx.x;
    const int row0 = blockIdx.x * 8;
#pragma unroll
    for (int r = 0; r < 8; ++r) xs[r][t] = x[(size_t)(row0 + r) * AD + t];
    __syncthreads();
    float aPs[8] = {}, aQs[8] = {}, aPg[8] = {}, aQg[8] = {};
    for (int k = 0; k < AD; ++k) {
        float ks_s = Ks[k * AD + t];
        float ks_d = Ks[(AD + k) * AD + t];
        float kg_s = Kg[k * AD + t];
        float kg_d = Kg[(AD + k) * AD + t];
#pragma unroll
        for (int r = 0; r < 8; ++r) {
            float xv = xs[r][k];
            aPs[r] = fmaf(xv, ks_s, aPs[r]);
            aQs[r] = fmaf(xv, ks_d, aQs[r]);
            aPg[r] = fmaf(xv, kg_s, aPg[r]);
            aQg[r] = fmaf(xv, kg_d, aQg[r]);
        }
    }
#pragma unroll
    for (int r = 0; r < 8; ++r) {
        float* o = PQ + (size_t)(row0 + r) * 512;
        *(float2*)&o[2 * t]       = make_float2(aPs[r], aPg[r]);
        *(float2*)&o[256 + 2 * t] = make_float2(aQs[r], aQg[r]);
    }
}

__global__ void __launch_bounds__(256) edge_fused(
    const float* __restrict__ ef, const float* __restrict__ Ks,
    const float* __restrict__ Kg, const float* __restrict__ PQ,
    const int* __restrict__ pidx, const float* __restrict__ bs,
    const float* __restrict__ bg, float* __restrict__ acc)
{
    __shared__ float KB[ED][2 * AD];
    __shared__ float es[64][ED];
    const int t = threadIdx.x;
    for (int i = t; i < ED * AD; i += 256) {
        int k = i >> 7, n = i & 127;
        KB[k][2 * n]     = Ks[(2 * AD + k) * AD + n];
        KB[k][2 * n + 1] = Kg[(2 * AD + k) * AD + n];
    }
    const size_t e0 = (size_t)blockIdx.x * 64;
    for (int i = t; i < 64 * ED; i += 256) ((float*)es)[i] = ef[e0 * ED + i];
    __syncthreads();
    const int le = t >> 7, n = t & 127;
    const float bsn = bs[n], bgn = bg[n];
    for (int base = le * 8; base < 64; base += 16) {
        float accS[8] = {}, accG[8] = {};
        for (int k4 = 0; k4 < ED / 4; ++k4) {
            float2 kv0 = *(const float2*)&KB[4 * k4 + 0][2 * n];
            float2 kv1 = *(const float2*)&KB[4 * k4 + 1][2 * n];
            float2 kv2 = *(const float2*)&KB[4 * k4 + 2][2 * n];
            float2 kv3 = *(const float2*)&KB[4 * k4 + 3][2 * n];
#pragma unroll
            for (int r = 0; r < 8; ++r) {
                float4 ev = *(const float4*)&es[base + r][4 * k4];
                accS[r] = fmaf(ev.x, kv0.x, accS[r]);
                accG[r] = fmaf(ev.x, kv0.y, accG[r]);
                accS[r] = fmaf(ev.y, kv1.x, accS[r]);
                accG[r] = fmaf(ev.y, kv1.y, accG[r]);
                accS[r] = fmaf(ev.z, kv2.x, accS[r]);
                accG[r] = fmaf(ev.z, kv2.y, accG[r]);
                accS[r] = fmaf(ev.w, kv3.x, accS[r]);
                accG[r] = fmaf(ev.w, kv3.y, accG[r]);
            }
        }
#pragma unroll
        for (int r = 0; r < 8; ++r) {
            size_t e = e0 + base + r;
            int src = pidx[2 * e], dst = pidx[2 * e + 1];
            float2 pv = *(const float2*)&PQ[(size_t)src * 512 + 2 * n];
            float2 qv = *(const float2*)&PQ[(size_t)dst * 512 + 256 + 2 * n];
            float s = accS[r] + pv.x + qv.x + bsn;
            float g = accG[r] + pv.y + qv.y + bgn;
            atomicAdd(&acc[(size_t)src * AD + n], sigmoid_fast(s) * softplus_f(g));
        }
    }
}

// ===== launch =====
extern "C" void kernel_launch(void* const* d_in, const int* in_sizes, int n_in,
                              void* d_out, int out_size, void* d_ws, size_t ws_size,
                              hipStream_t stream)
{
    const float* atom = (const float*)d_in[0];
    const float* ef   = (const float*)d_in[1];
    const float* Ks   = (const float*)d_in[3];
    const float* bs   = (const float*)d_in[4];
    const float* Kg   = (const float*)d_in[5];
    const float* bg   = (const float*)d_in[6];
    const int*   pidx = (const int*)d_in[7];

    float* acc = (float*)d_out;

    char* w = (char*)d_ws;
    const size_t PQ_B   = (size_t)NN * 256 * 4;   //  51.2 MB
    const size_t C_B    = (size_t)NE * 128 * 2;   // 204.8 MB (fp8 pairs)
    const size_t BN_B   = 16384 * 16;             // 256 KB
    const size_t CNT_B  = (size_t)NN * 4;
    const size_t IDX_B  = (size_t)NE * 4;
    const size_t PART_B = 256 * 4;
    unsigned* PQ32      = (unsigned*)w;       w += PQ_B;
    unsigned short* C16 = (unsigned short*)w; w += C_B;
    bf16x8*   Bn   = (bf16x8*)w;    w += BN_B;
    unsigned* cnt  = (unsigned*)w;  w += CNT_B;
    unsigned* curp = (unsigned*)w;  w += CNT_B;
    int*      sid  = (int*)w;       w += IDX_B;
    int2*     sdp  = (int2*)w;      w += 2 * IDX_B;
    unsigned* part = (unsigned*)w;  w += PART_B;
    const size_t TOTAL_A = PQ_B + C_B + BN_B + 2 * CNT_B + 3 * IDX_B + PART_B;

    if (ws_size >= TOTAL_A) {
        hipMemsetAsync(cnt, 0, CNT_B, stream);
        bn_prep<<<64, 256, 0, stream>>>(Ks, Kg, Bn);
        hist_k<<<NE / 256, 256, 0, stream>>>(pidx, cnt);
        scan1_k<<<NSCAN, 256, 0, stream>>>(cnt, curp, part);
        scan2_k<<<1, 256, 0, stream>>>(part);
        scan3_k<<<NSCAN, 256, 0, stream>>>(curp, part);
        scatter_k<<<NE / 256, 256, 0, stream>>>(pidx, curp, sid, sdp);
        edge_c_mfma<<<2048, 512, 0, stream>>>(ef, Ks, Kg, sid, C16);

        for (int s = 0; s < NSTEPS; ++s) {
            node_mm_mfma<<<NROWB, 512, 0, stream>>>(atom, acc, Bn, PQ32,
                                                    s == 0 ? 0 : 1);
            edge_apply_sorted<<<NE / 128, 256, 0, stream>>>(
                (const char*)C16, (const char*)PQ32, sdp, bs, bg, acc);
        }
        act_k<<<(NN * AD) / 1024, 256, 0, stream>>>(acc);
    } else {
        float* PQ = (float*)d_ws;
        hipMemcpyAsync(acc, atom, (size_t)NN * AD * sizeof(float),
                       hipMemcpyDeviceToDevice, stream);
        for (int s = 0; s < NSTEPS; ++s) {
            node_mm_f32<<<NN / 8, 128, 0, stream>>>(acc, Ks, Kg, PQ);
            edge_fused<<<NE / 64, 256, 0, stream>>>(ef, Ks, Kg, PQ, pidx, bs, bg, acc);
            act_k<<<(NN * AD) / 1024, 256, 0, stream>>>(acc);
        }
    }
}

// Round 16
// 648.392 us; speedup vs baseline: 1.2542x; 1.0020x over previous
//
#include <hip/hip_runtime.h>
#include <hip/hip_bf16.h>
#include <math.h>

// CrystalGraphConvolution — MI355X round 16
// vs r15: (1) edge_c gather prefetch depth 1 -> 2 (ef-row HBM latency ~900cyc
// > tile loop body; depth-2 keeps two tiles of gathers in flight); (2) scan3
// folded into scatter (pos = local prefix + part[s>>8]) — one less launch.

#define NN 50000
#define NE 800000
#define AD 128
#define ED 64
#define NSTEPS 3
#define NTILES (NE / 64)          // 12500
#define NSCAN  ((NN + 255) / 256) // 196
#define NROWB  ((NN + 63) / 64)   // 782

#define L2E 1.4426950408889634f
#define LN2 0.6931471805599453f

typedef __attribute__((ext_vector_type(8))) __bf16 bf16x8;
typedef __attribute__((ext_vector_type(4))) float  f32x4;
typedef __attribute__((ext_vector_type(2))) float  f32x2;
typedef __attribute__((ext_vector_type(2))) unsigned u32x2;

__device__ __forceinline__ float softplus_f(float x) {      // Tier B only
    return fmaxf(x, 0.f) + log1pf(__expf(-fabsf(x)));
}
__device__ __forceinline__ float sigmoid_fast(float x) {    // Tier B
    float e = __expf(-fabsf(x));
    float r = __builtin_amdgcn_rcpf(1.f + e);
    return (x >= 0.f) ? r : 1.f - r;
}
__device__ __forceinline__ unsigned short bf16_rne(float f) {
    unsigned u = __float_as_uint(f);
    unsigned r = u + 0x7fffu + ((u >> 16) & 1u);
    return (unsigned short)(r >> 16);
}
__device__ __forceinline__ unsigned pack_bf2(float s, float g) {
    return (unsigned)bf16_rne(s) | ((unsigned)bf16_rne(g) << 16);
}
__device__ __forceinline__ float unp_lo(unsigned v) { return __uint_as_float(v << 16); }
__device__ __forceinline__ float unp_hi(unsigned v) { return __uint_as_float(v & 0xffff0000u); }

__device__ __forceinline__ float nexp2_f(float x) {         // 2^(-x)
    float r; asm("v_exp_f32 %0, -%1" : "=v"(r) : "v"(x)); return r;
}
__device__ __forceinline__ float nexp2_abs_f(float x) {     // 2^(-|x|)
    float r; asm("v_exp_f32 %0, -abs(%1)" : "=v"(r) : "v"(x)); return r;
}
__device__ __forceinline__ float log2_f(float x) {
    float r; asm("v_log_f32 %0, %1" : "=v"(r) : "v"(x)); return r;
}
// HW softplus: ln2 * (max(y,0) + log2(1 + 2^-|y|)), y = x*log2e. rel err ~1e-6.
__device__ __forceinline__ float softplus_hw(float x) {
    float y = x * L2E;
    return LN2 * (fmaxf(y, 0.f) + log2_f(1.f + nexp2_abs_f(y)));
}
// fp8 e4m3 pack (gfx950 OCP; round-trips through same HW format)
__device__ __forceinline__ unsigned short pack_fp8_pair(float s, float g) {
    int v = __builtin_amdgcn_cvt_pk_fp8_f32(s, g, 0, false);  // bytes 0,1
    return (unsigned short)(v & 0xffff);
}

// ===== one-time B pre-pack for node GEMM =====
__global__ void __launch_bounds__(256) bn_prep(
    const float* __restrict__ Ks, const float* __restrict__ Kg,
    bf16x8* __restrict__ Bn)
{
    union U8 { short s[8]; bf16x8 v; };
    int idx = blockIdx.x * 256 + threadIdx.x;      // 64 blocks -> 16384
    int l4  = idx & 3;
    int col = (idx >> 2) & 127;
    int ki  = (idx >> 9) & 3;
    int hl  = (idx >> 11) & 1;
    int m   = (idx >> 12) & 1;
    int sel = (idx >> 13) & 1;
    const float* K = m ? Kg : Ks;
    U8 o;
#pragma unroll
    for (int j = 0; j < 8; ++j) {
        int k = sel * 128 + ki * 32 + l4 * 8 + j;
        float v = K[(size_t)k * AD + col];
        unsigned short h = bf16_rne(v);
        o.s[j] = (hl == 0) ? (short)h
                           : (short)bf16_rne(v - __uint_as_float((unsigned)h << 16));
    }
    Bn[idx] = o.v;
}

// ===== node projections via MFMA (hi/lo), + x maintenance; outputs xL2E-scaled =====
__global__ void __launch_bounds__(512, 1) node_mm_mfma(
    const float* __restrict__ xin, float* __restrict__ acc,
    const bf16x8* __restrict__ Bn, unsigned* __restrict__ PQ32, int mode)
{
    __shared__ short As_h[64 * 128];
    __shared__ short As_l[64 * 128];
    const int t = threadIdx.x;
    const int w = t >> 6, lane = t & 63;
    const int l4 = lane >> 4;
    const int row0 = blockIdx.x * 64;

#pragma unroll
    for (int ii = 0; ii < 4; ++ii) {
        int idx = t + 512 * ii;
        int row = idx >> 5, c4 = idx & 31;
        int node = row0 + row;
        f32x4 v = {};
        if (node < NN) {
            if (mode == 0) {
                v = *(const f32x4*)&xin[(size_t)node * AD + 4 * c4];
                *(f32x4*)&acc[(size_t)node * AD + 4 * c4] = v;
            } else {
                f32x4 a = *(const f32x4*)&acc[(size_t)node * AD + 4 * c4];
                v[0] = softplus_hw(a[0]); v[1] = softplus_hw(a[1]);
                v[2] = softplus_hw(a[2]); v[3] = softplus_hw(a[3]);
                *(f32x4*)&acc[(size_t)node * AD + 4 * c4] = v;
            }
        }
        unsigned short h0 = bf16_rne(v[0]), h1 = bf16_rne(v[1]),
                       h2 = bf16_rne(v[2]), h3 = bf16_rne(v[3]);
        unsigned short l0 = bf16_rne(v[0] - __uint_as_float((unsigned)h0 << 16));
        unsigned short l1 = bf16_rne(v[1] - __uint_as_float((unsigned)h1 << 16));
        unsigned short l2 = bf16_rne(v[2] - __uint_as_float((unsigned)h2 << 16));
        unsigned short l3 = bf16_rne(v[3] - __uint_as_float((unsigned)h3 << 16));
        int sidx = (row * 128 + c4 * 4) ^ ((row & 7) << 3);
        *(short4*)&As_h[sidx] = make_short4((short)h0, (short)h1, (short)h2, (short)h3);
        *(short4*)&As_l[sidx] = make_short4((short)l0, (short)l1, (short)l2, (short)l3);
    }
    __syncthreads();

    const int col = w * 16 + (lane & 15);
#pragma unroll
    for (int sel = 0; sel < 2; ++sel) {
        bf16x8 bS[4][2], bG[4][2];
#pragma unroll
        for (int ki = 0; ki < 4; ++ki) {
#pragma unroll
            for (int hl = 0; hl < 2; ++hl) {
                bS[ki][hl] = Bn[(((sel * 2 + 0) * 2 + hl) * 4 + ki) * 512 + col * 4 + l4];
                bG[ki][hl] = Bn[(((sel * 2 + 1) * 2 + hl) * 4 + ki) * 512 + col * 4 + l4];
            }
        }
        f32x4 aS[4] = {}, aG[4] = {};
#pragma unroll
        for (int mt = 0; mt < 4; ++mt) {
            int row = mt * 16 + (lane & 15);
#pragma unroll
            for (int ki = 0; ki < 4; ++ki) {
                int idx = (row * 128 + ki * 32 + l4 * 8) ^ ((row & 7) << 3);
                bf16x8 ah = *(const bf16x8*)&As_h[idx];
                bf16x8 al = *(const bf16x8*)&As_l[idx];
                aS[mt] = __builtin_amdgcn_mfma_f32_16x16x32_bf16(ah, bS[ki][0], aS[mt], 0, 0, 0);
                aS[mt] = __builtin_amdgcn_mfma_f32_16x16x32_bf16(al, bS[ki][0], aS[mt], 0, 0, 0);
                aS[mt] = __builtin_amdgcn_mfma_f32_16x16x32_bf16(ah, bS[ki][1], aS[mt], 0, 0, 0);
                aG[mt] = __builtin_amdgcn_mfma_f32_16x16x32_bf16(ah, bG[ki][0], aG[mt], 0, 0, 0);
                aG[mt] = __builtin_amdgcn_mfma_f32_16x16x32_bf16(al, bG[ki][0], aG[mt], 0, 0, 0);
                aG[mt] = __builtin_amdgcn_mfma_f32_16x16x32_bf16(ah, bG[ki][1], aG[mt], 0, 0, 0);
            }
        }
#pragma unroll
        for (int mt = 0; mt < 4; ++mt) {
#pragma unroll
            for (int reg = 0; reg < 4; ++reg) {
                int node = row0 + mt * 16 + l4 * 4 + reg;
                if (node < NN)
                    PQ32[(size_t)node * 256 + sel * 128 + col] =
                        pack_bf2(aS[mt][reg] * L2E, aG[mt][reg] * L2E);
            }
        }
    }
}

// ===== sort machinery =====
__global__ void __launch_bounds__(256) hist_k(const int* __restrict__ pidx,
                                              unsigned* __restrict__ cnt)
{
    int e = blockIdx.x * 256 + threadIdx.x;
    atomicAdd(&cnt[pidx[2 * e]], 1u);
}

__global__ void __launch_bounds__(256) scan1_k(const unsigned* __restrict__ cnt,
                                               unsigned* __restrict__ cur,
                                               unsigned* __restrict__ part)
{
    __shared__ unsigned tmp[256];
    const int t = threadIdx.x;
    const int bin = blockIdx.x * 256 + t;
    unsigned v = (bin < NN) ? cnt[bin] : 0u;
    tmp[t] = v;
    __syncthreads();
    for (int off = 1; off < 256; off <<= 1) {
        unsigned a = (t >= off) ? tmp[t - off] : 0u;
        __syncthreads();
        tmp[t] += a;
        __syncthreads();
    }
    if (bin < NN) cur[bin] = tmp[t] - v;
    if (t == 255) part[blockIdx.x] = tmp[255];
}

__global__ void __launch_bounds__(256) scan2_k(unsigned* __restrict__ part)
{
    __shared__ unsigned tmp[256];
    const int t = threadIdx.x;
    unsigned v = (t < NSCAN) ? part[t] : 0u;
    tmp[t] = v;
    __syncthreads();
    for (int off = 1; off < 256; off <<= 1) {
        unsigned a = (t >= off) ? tmp[t - off] : 0u;
        __syncthreads();
        tmp[t] += a;
        __syncthreads();
    }
    if (t < NSCAN) part[t] = tmp[t] - v;
}

// scatter with fused global-offset add: pos = local-prefix + part[s>>8]
// scaled offsets packed: sdp[pos] = { src*1024, dst*1024+512 }
__global__ void __launch_bounds__(256) scatter_k(
    const int* __restrict__ pidx, unsigned* __restrict__ cur,
    const unsigned* __restrict__ part,
    int* __restrict__ sid, int2* __restrict__ sdp)
{
    int e = blockIdx.x * 256 + threadIdx.x;
    int s = pidx[2 * e], d = pidx[2 * e + 1];
    unsigned pos = atomicAdd(&cur[s], 1u) + part[s >> 8];
    sid[pos] = e;
    sdp[pos] = make_int2(s << 10, (d << 10) + 512);
}

// ===== C = ef @ K_bot via MFMA (bf16-hi); fp8 out; depth-2 gather prefetch =====
__global__ void __launch_bounds__(512) edge_c_mfma(
    const float* __restrict__ ef, const float* __restrict__ Ks,
    const float* __restrict__ Kg, const int* __restrict__ sid,
    unsigned short* __restrict__ C16)
{
    __shared__ short As_h[64 * 64];   // 8 KB
    const int t = threadIdx.x;
    const int w = t >> 6, lane = t & 63;

    union U8 { short s[8]; bf16x8 v; };
    bf16x8 bS[2], bG[2];   // hi plane only
    {
        const int col = w * 16 + (lane & 15);
#pragma unroll
        for (int ki = 0; ki < 2; ++ki) {
            U8 sh_, gh_;
            const int kbase = 2 * AD + ki * 32 + (lane >> 4) * 8;
#pragma unroll
            for (int j = 0; j < 8; ++j) {
                sh_.s[j] = (short)bf16_rne(Ks[(size_t)(kbase + j) * AD + col]);
                gh_.s[j] = (short)bf16_rne(Kg[(size_t)(kbase + j) * AD + col]);
            }
            bS[ki] = sh_.v;
            bG[ki] = gh_.v;
        }
    }

    const int srow = t >> 4, sc4 = t & 15;
    const int G = gridDim.x;
    // depth-2 prefetch ring: A = data for current tile, B = next tile
    f32x4 pa0, pa1, pb0, pb1;
    {
        int ea = sid[(size_t)blockIdx.x * 64 + srow];
        int eb = sid[(size_t)blockIdx.x * 64 + srow + 32];
        pa0 = __builtin_nontemporal_load((const f32x4*)&ef[(size_t)ea * 64 + 4 * sc4]);
        pa1 = __builtin_nontemporal_load((const f32x4*)&ef[(size_t)eb * 64 + 4 * sc4]);
        int n1 = blockIdx.x + G;
        if (n1 < NTILES) {
            int ec = sid[(size_t)n1 * 64 + srow];
            int ed = sid[(size_t)n1 * 64 + srow + 32];
            pb0 = __builtin_nontemporal_load((const f32x4*)&ef[(size_t)ec * 64 + 4 * sc4]);
            pb1 = __builtin_nontemporal_load((const f32x4*)&ef[(size_t)ed * 64 + 4 * sc4]);
        }
    }

    for (int tile = blockIdx.x; tile < NTILES; tile += G) {
        __syncthreads();   // prior tile's MFMA reads of As done
        {
#pragma unroll
            for (int ii = 0; ii < 2; ++ii) {
                f32x4 v = ii ? pa1 : pa0;
                int row = srow + 32 * ii;
                unsigned short h0 = bf16_rne(v[0]), h1 = bf16_rne(v[1]),
                               h2 = bf16_rne(v[2]), h3 = bf16_rne(v[3]);
                int sidx = (row * 64 + sc4 * 4) ^ ((row & 7) << 3);
                *(short4*)&As_h[sidx] = make_short4((short)h0, (short)h1, (short)h2, (short)h3);
            }
        }
        // shift ring; issue loads for tile + 2G
        pa0 = pb0; pa1 = pb1;
        {
            int n2 = tile + 2 * G;
            if (n2 < NTILES) {
                int ec = sid[(size_t)n2 * 64 + srow];
                int ed = sid[(size_t)n2 * 64 + srow + 32];
                pb0 = __builtin_nontemporal_load((const f32x4*)&ef[(size_t)ec * 64 + 4 * sc4]);
                pb1 = __builtin_nontemporal_load((const f32x4*)&ef[(size_t)ed * 64 + 4 * sc4]);
            }
        }
        __syncthreads();

        f32x4 accS[4] = {}, accG[4] = {};
#pragma unroll
        for (int mt = 0; mt < 4; ++mt) {
#pragma unroll
            for (int ki = 0; ki < 2; ++ki) {
                int row = mt * 16 + (lane & 15);
                int idx = (row * 64 + ki * 32 + (lane >> 4) * 8) ^ ((row & 7) << 3);
                bf16x8 ah = *(const bf16x8*)&As_h[idx];
                accS[mt] = __builtin_amdgcn_mfma_f32_16x16x32_bf16(ah, bS[ki], accS[mt], 0, 0, 0);
                accG[mt] = __builtin_amdgcn_mfma_f32_16x16x32_bf16(ah, bG[ki], accG[mt], 0, 0, 0);
            }
        }
        const size_t p0 = (size_t)tile * 64;
#pragma unroll
        for (int mt = 0; mt < 4; ++mt) {
#pragma unroll
            for (int reg = 0; reg < 4; ++reg) {
                int row = mt * 16 + (lane >> 4) * 4 + reg;
                C16[(p0 + row) * 128 + w * 16 + (lane & 15)] =
                    pack_fp8_pair(accS[mt][reg] * L2E, accG[mt][reg] * L2E);
            }
        }
    }
}

// ===== sorted apply v9: cacheable fp8 C stream, 32 edges/wave, pinned rings =====
__global__ void __launch_bounds__(256) edge_apply_sorted(
    const char* __restrict__ C8, const char* __restrict__ PQ8,
    const int2* __restrict__ sdp,
    const float* __restrict__ bs, const float* __restrict__ bg,
    float* __restrict__ acc)
{
    const int t = threadIdx.x & 63;
    const int w = threadIdx.x >> 6;
    const size_t p0 = ((size_t)blockIdx.x * 4 + w) * 32;
    const int2 sd = sdp[p0 + (t & 31)];   // lanes 0..31 hold the segment's edges
    const int srcv = sd.x, dstv = sd.y;

    const float2 bsv = *(const float2*)&bs[2 * t];
    const float2 bgv = *(const float2*)&bg[2 * t];
    const float bsA = bsv.x * L2E, bsB = bsv.y * L2E;
    const float bgA = bgv.x * L2E, bgB = bgv.y * L2E;

    const char* PQl = PQ8 + 8 * t;
    char* accl = (char*)acc + 8 * t;
    const char* Cl = C8 + p0 * 256 + 4 * t;   // fp8 row = 256 B

#define RL(v, i) __builtin_amdgcn_readlane((v), (i))
#define LOADC(i) (*(const unsigned*)(Cl + (i) * 256))
#define LOADQ(i) (*(const u32x2*)(PQl + RL(dstv, (i))))
#define LOADP(s_) (*(const u32x2*)(PQl + (s_)))
#define PIN __builtin_amdgcn_sched_barrier(0)

    int cur = RL(srcv, 0);
    u32x2 pv = LOADP(cur);
    float psA = unp_lo(pv.x) + bsA, pgA = unp_hi(pv.x) + bgA;
    float psB = unp_lo(pv.y) + bsB, pgB = unp_hi(pv.y) + bgB;

    unsigned c0 = LOADC(0), c1 = LOADC(1), c2 = LOADC(2), c3 = LOADC(3),
             c4 = LOADC(4), c5 = LOADC(5), c6 = LOADC(6), c7 = LOADC(7);
    u32x2 q0 = LOADQ(0), q1 = LOADQ(1), q2 = LOADQ(2), q3 = LOADQ(3),
          q4 = LOADQ(4), q5 = LOADQ(5), q6 = LOADQ(6), q7 = LOADQ(7);
    u32x2 r0 = pv, r1 = pv, r2 = pv, r3 = pv, r4 = pv, r5 = pv, r6 = pv, r7 = pv;
    if (RL(srcv, 1) != RL(srcv, 0)) r1 = LOADP(RL(srcv, 1));
    if (RL(srcv, 2) != RL(srcv, 1)) r2 = LOADP(RL(srcv, 2));
    if (RL(srcv, 3) != RL(srcv, 2)) r3 = LOADP(RL(srcv, 3));
    if (RL(srcv, 4) != RL(srcv, 3)) r4 = LOADP(RL(srcv, 4));
    if (RL(srcv, 5) != RL(srcv, 4)) r5 = LOADP(RL(srcv, 5));
    if (RL(srcv, 6) != RL(srcv, 5)) r6 = LOADP(RL(srcv, 6));
    if (RL(srcv, 7) != RL(srcv, 6)) r7 = LOADP(RL(srcv, 7));
    PIN;   // all prologue loads issued before any compute
    float accA = 0.f, accB = 0.f;

#define FLUSH                                                              \
    atomicAdd((float*)(accl + ((unsigned)cur >> 1)),     LN2 * accA);      \
    atomicAdd((float*)(accl + ((unsigned)cur >> 1) + 4), LN2 * accB);

#define CORE(i, cc, qq, rr)                                                \
    {                                                                      \
        int src_ = RL(srcv, (i));                                          \
        if (src_ != cur) {                                                 \
            FLUSH;                                                         \
            accA = 0.f; accB = 0.f; cur = src_;                            \
            psA = unp_lo(rr.x) + bsA; pgA = unp_hi(rr.x) + bgA;            \
            psB = unp_lo(rr.y) + bsB; pgB = unp_hi(rr.y) + bgB;            \
        }                                                                  \
        f32x2 sgA = __builtin_amdgcn_cvt_pk_f32_fp8((int)cc, false);       \
        f32x2 sgB = __builtin_amdgcn_cvt_pk_f32_fp8((int)cc, true);        \
        float sA = sgA[0] + unp_lo(qq.x) + psA;                            \
        float gA = sgA[1] + unp_hi(qq.x) + pgA;                            \
        float sB = sgB[0] + unp_lo(qq.y) + psB;                            \
        float gB = sgB[1] + unp_hi(qq.y) + pgB;                            \
        float spA = fmaxf(gA, 0.f) + log2_f(1.f + nexp2_abs_f(gA));        \
        float spB = fmaxf(gB, 0.f) + log2_f(1.f + nexp2_abs_f(gB));       \
        accA = fmaf(__builtin_amdgcn_rcpf(1.f + nexp2_f(sA)), spA, accA);  \
        accB = fmaf(__builtin_amdgcn_rcpf(1.f + nexp2_f(sB)), spB, accB);  \
    }

// prefetch loads for i+8, then PIN so they cannot sink into later iterations
#define STEP(i, cc, qq, rr)                                                \
    {                                                                      \
        unsigned ncc = LOADC((i) + 8);                                     \
        u32x2 nqq = LOADQ((i) + 8);                                        \
        u32x2 nrr = rr;                                                    \
        if (RL(srcv, (i) + 8) != RL(srcv, (i) + 7))                        \
            nrr = LOADP(RL(srcv, (i) + 8));                                \
        PIN;                                                               \
        CORE(i, cc, qq, rr)                                                \
        cc = ncc; qq = nqq; rr = nrr;                                      \
    }

    for (int b = 0; b < 24; b += 8) {
        STEP(b + 0, c0, q0, r0)
        STEP(b + 1, c1, q1, r1)
        STEP(b + 2, c2, q2, r2)
        STEP(b + 3, c3, q3, r3)
        STEP(b + 4, c4, q4, r4)
        STEP(b + 5, c5, q5, r5)
        STEP(b + 6, c6, q6, r6)
        STEP(b + 7, c7, q7, r7)
    }
    CORE(24, c0, q0, r0)
    CORE(25, c1, q1, r1)
    CORE(26, c2, q2, r2)
    CORE(27, c3, q3, r3)
    CORE(28, c4, q4, r4)
    CORE(29, c5, q5, r5)
    CORE(30, c6, q6, r6)
    CORE(31, c7, q7, r7)
    FLUSH;

#undef STEP
#undef CORE
#undef FLUSH
#undef PIN
#undef LOADP
#undef LOADQ
#undef LOADC
#undef RL
}

// ===== final softplus (HW exp2/log2) =====
__global__ void __launch_bounds__(256) act_k(float* __restrict__ acc)
{
    size_t i = ((size_t)blockIdx.x * 256 + threadIdx.x) * 4;
    float4 v = *(float4*)&acc[i];
    v.x = softplus_hw(v.x);
    v.y = softplus_hw(v.y);
    v.z = softplus_hw(v.z);
    v.w = softplus_hw(v.w);
    *(float4*)&acc[i] = v;
}

// ===== Tier B fallback (round-1, known good) =====
__global__ void __launch_bounds__(128) node_mm_f32(
    const float* __restrict__ x, const float* __restrict__ Ks,
    const float* __restrict__ Kg, float* __restrict__ PQ)
{
    __shared__ float xs[8][AD];
    const int t = threadIdx.x;
    const int row0 = blockIdx.x * 8;
#pragma unroll
    for (int r = 0; r < 8; ++r) xs[r][t] = x[(size_t)(row0 + r) * AD + t];
    __syncthreads();
    float aPs[8] = {}, aQs[8] = {}, aPg[8] = {}, aQg[8] = {};
    for (int k = 0; k < AD; ++k) {
        float ks_s = Ks[k * AD + t];
        float ks_d = Ks[(AD + k) * AD + t];
        float kg_s = Kg[k * AD + t];
        float kg_d = Kg[(AD + k) * AD + t];
#pragma unroll
        for (int r = 0; r < 8; ++r) {
            float xv = xs[r][k];
            aPs[r] = fmaf(xv, ks_s, aPs[r]);
            aQs[r] = fmaf(xv, ks_d, aQs[r]);
            aPg[r] = fmaf(xv, kg_s, aPg[r]);
            aQg[r] = fmaf(xv, kg_d, aQg[r]);
        }
    }
#pragma unroll
    for (int r = 0; r < 8; ++r) {
        float* o = PQ + (size_t)(row0 + r) * 512;
        *(float2*)&o[2 * t]       = make_float2(aPs[r], aPg[r]);
        *(float2*)&o[256 + 2 * t] = make_float2(aQs[r], aQg[r]);
    }
}

__global__ void __launch_bounds__(256) edge_fused(
    const float* __restrict__ ef, const float* __restrict__ Ks,
    const float* __restrict__ Kg, const float* __restrict__ PQ,
    const int* __restrict__ pidx, const float* __restrict__ bs,
    const float* __restrict__ bg, float* __restrict__ acc)
{
    __shared__ float KB[ED][2 * AD];
    __shared__ float es[64][ED];
    const int t = threadIdx.x;
    for (int i = t; i < ED * AD; i += 256) {
        int k = i >> 7, n = i & 127;
        KB[k][2 * n]     = Ks[(2 * AD + k) * AD + n];
        KB[k][2 * n + 1] = Kg[(2 * AD + k) * AD + n];
    }
    const size_t e0 = (size_t)blockIdx.x * 64;
    for (int i = t; i < 64 * ED; i += 256) ((float*)es)[i] = ef[e0 * ED + i];
    __syncthreads();
    const int le = t >> 7, n = t & 127;
    const float bsn = bs[n], bgn = bg[n];
    for (int base = le * 8; base < 64; base += 16) {
        float accS[8] = {}, accG[8] = {};
        for (int k4 = 0; k4 < ED / 4; ++k4) {
            float2 kv0 = *(const float2*)&KB[4 * k4 + 0][2 * n];
            float2 kv1 = *(const float2*)&KB[4 * k4 + 1][2 * n];
            float2 kv2 = *(const float2*)&KB[4 * k4 + 2][2 * n];
            float2 kv3 = *(const float2*)&KB[4 * k4 + 3][2 * n];
#pragma unroll
            for (int r = 0; r < 8; ++r) {
                float4 ev = *(const float4*)&es[base + r][4 * k4];
                accS[r] = fmaf(ev.x, kv0.x, accS[r]);
                accG[r] = fmaf(ev.x, kv0.y, accG[r]);
                accS[r] = fmaf(ev.y, kv1.x, accS[r]);
                accG[r] = fmaf(ev.y, kv1.y, accG[r]);
                accS[r] = fmaf(ev.z, kv2.x, accS[r]);
                accG[r] = fmaf(ev.z, kv2.y, accG[r]);
                accS[r] = fmaf(ev.w, kv3.x, accS[r]);
                accG[r] = fmaf(ev.w, kv3.y, accG[r]);
            }
        }
#pragma unroll
        for (int r = 0; r < 8; ++r) {
            size_t e = e0 + base + r;
            int src = pidx[2 * e], dst = pidx[2 * e + 1];
            float2 pv = *(const float2*)&PQ[(size_t)src * 512 + 2 * n];
            float2 qv = *(const float2*)&PQ[(size_t)dst * 512 + 256 + 2 * n];
            float s = accS[r] + pv.x + qv.x + bsn;
            float g = accG[r] + pv.y + qv.y + bgn;
            atomicAdd(&acc[(size_t)src * AD + n], sigmoid_fast(s) * softplus_f(g));
        }
    }
}

// ===== launch =====
extern "C" void kernel_launch(void* const* d_in, const int* in_sizes, int n_in,
                              void* d_out, int out_size, void* d_ws, size_t ws_size,
                              hipStream_t stream)
{
    const float* atom = (const float*)d_in[0];
    const float* ef   = (const float*)d_in[1];
    const float* Ks   = (const float*)d_in[3];
    const float* bs   = (const float*)d_in[4];
    const float* Kg   = (const float*)d_in[5];
    const float* bg   = (const float*)d_in[6];
    const int*   pidx = (const int*)d_in[7];

    float* acc = (float*)d_out;

    char* w = (char*)d_ws;
    const size_t PQ_B   = (size_t)NN * 256 * 4;   //  51.2 MB
    const size_t C_B    = (size_t)NE * 128 * 2;   // 204.8 MB (fp8 pairs)
    const size_t BN_B   = 16384 * 16;             // 256 KB
    const size_t CNT_B  = (size_t)NN * 4;
    const size_t IDX_B  = (size_t)NE * 4;
    const size_t PART_B = 256 * 4;
    unsigned* PQ32      = (unsigned*)w;       w += PQ_B;
    unsigned short* C16 = (unsigned short*)w; w += C_B;
    bf16x8*   Bn   = (bf16x8*)w;    w += BN_B;
    unsigned* cnt  = (unsigned*)w;  w += CNT_B;
    unsigned* curp = (unsigned*)w;  w += CNT_B;
    int*      sid  = (int*)w;       w += IDX_B;
    int2*     sdp  = (int2*)w;      w += 2 * IDX_B;
    unsigned* part = (unsigned*)w;  w += PART_B;
    const size_t TOTAL_A = PQ_B + C_B + BN_B + 2 * CNT_B + 3 * IDX_B + PART_B;

    if (ws_size >= TOTAL_A) {
        hipMemsetAsync(cnt, 0, CNT_B, stream);
        bn_prep<<<64, 256, 0, stream>>>(Ks, Kg, Bn);
        hist_k<<<NE / 256, 256, 0, stream>>>(pidx, cnt);
        scan1_k<<<NSCAN, 256, 0, stream>>>(cnt, curp, part);
        scan2_k<<<1, 256, 0, stream>>>(part);
        scatter_k<<<NE / 256, 256, 0, stream>>>(pidx, curp, part, sid, sdp);
        edge_c_mfma<<<2048, 512, 0, stream>>>(ef, Ks, Kg, sid, C16);

        for (int s = 0; s < NSTEPS; ++s) {
            node_mm_mfma<<<NROWB, 512, 0, stream>>>(atom, acc, Bn, PQ32,
                                                    s == 0 ? 0 : 1);
            edge_apply_sorted<<<NE / 128, 256, 0, stream>>>(
                (const char*)C16, (const char*)PQ32, sdp, bs, bg, acc);
        }
        act_k<<<(NN * AD) / 1024, 256, 0, stream>>>(acc);
    } else {
        float* PQ = (float*)d_ws;
        hipMemcpyAsync(acc, atom, (size_t)NN * AD * sizeof(float),
                       hipMemcpyDeviceToDevice, stream);
        for (int s = 0; s < NSTEPS; ++s) {
            node_mm_f32<<<NN / 8, 128, 0, stream>>>(acc, Ks, Kg, PQ);
            edge_fused<<<NE / 64, 256, 0, stream>>>(ef, Ks, Kg, PQ, pidx, bs, bg, acc);
            act_k<<<(NN * AD) / 1024, 256, 0, stream>>>(acc);
        }
    }
}